// Round 1
// baseline (986.731 us; speedup 1.0000x reference)
//
#include <hip/hip_runtime.h>

typedef __bf16 bf16;
typedef __bf16 bf16x8 __attribute__((ext_vector_type(8)));
typedef __bf16 bf16x4 __attribute__((ext_vector_type(4)));
typedef float f32x4 __attribute__((ext_vector_type(4)));

constexpr int D = 2048, H = 16, DPH = 128, DR = 64, DC_KV = 16, DC_Q = 512;
constexpr int QHD = 192, MEG = 256, B = 2, S = 2048;
constexpr int T = B * S;
constexpr float EPS = 1e-7f;
constexpr float SCALE = 0.07216878364870323f; // 1/sqrt(192)

static __device__ __forceinline__ bf16x8 zero8() {
  bf16x8 v;
#pragma unroll
  for (int j = 0; j < 8; j++) v[j] = (bf16)0.f;
  return v;
}

// ---------------- rope table (f64 precision, once) ----------------
__global__ void rope_table_kernel(float* __restrict__ cos_t, float* __restrict__ sin_t) {
  int i = blockIdx.x * 64 + threadIdx.x;  // over S*32
  int pos = i >> 5, j = i & 31;
  double invf = pow(10000.0, -(double)(2 * j) / 64.0);
  double a = (double)pos * invf;
  cos_t[i] = (float)cos(a);
  sin_t[i] = (float)sin(a);
}

// ---------------- f32 -> bf16 cast ----------------
__global__ void cast_bf16_kernel(const float* __restrict__ in, bf16* __restrict__ out, int n) {
  int i = (blockIdx.x * blockDim.x + threadIdx.x) * 4;
  if (i < n) {
    float4 v = *reinterpret_cast<const float4*>(in + i);
    bf16x4 o;
    o[0] = (bf16)v.x; o[1] = (bf16)v.y; o[2] = (bf16)v.z; o[3] = (bf16)v.w;
    *reinterpret_cast<bf16x4*>(out + i) = o;
  }
}

// ---------------- transpose + cast: out[n][k] = (bf16) in[k][n], in is K x N f32 ----------------
__global__ __launch_bounds__(256) void transpose_cast_kernel(
    const float* __restrict__ in, bf16* __restrict__ out, int K, int N) {
  __shared__ float tile[32][33];
  int k0 = blockIdx.y * 32, n0 = blockIdx.x * 32;
  int tid = threadIdx.x;
#pragma unroll
  for (int e = tid; e < 1024; e += 256) {
    int i = e >> 5, j = e & 31;
    int k = k0 + i, n = n0 + j;
    tile[i][j] = (k < K && n < N) ? in[(size_t)k * N + n] : 0.f;
  }
  __syncthreads();
#pragma unroll
  for (int e = tid; e < 1024; e += 256) {
    int jj = e >> 5, ii = e & 31;
    int n = n0 + jj, k = k0 + ii;
    if (k < K && n < N) out[(size_t)n * K + k] = (bf16)tile[ii][jj];
  }
}

// ---------------- RMSNorm over 512 dims (q path) ----------------
__global__ __launch_bounds__(256) void rmsnorm_q_kernel(
    const float* __restrict__ cq, const float* __restrict__ w, bf16* __restrict__ outp) {
  int wid = threadIdx.x >> 6, lane = threadIdx.x & 63;
  int t = blockIdx.x * 4 + wid;
  const float* x = cq + (size_t)t * DC_Q;
  float4 v0 = *reinterpret_cast<const float4*>(x + lane * 8);
  float4 v1 = *reinterpret_cast<const float4*>(x + lane * 8 + 4);
  float ss = v0.x * v0.x + v0.y * v0.y + v0.z * v0.z + v0.w * v0.w +
             v1.x * v1.x + v1.y * v1.y + v1.z * v1.z + v1.w * v1.w;
#pragma unroll
  for (int off = 32; off; off >>= 1) ss += __shfl_xor(ss, off);
  float r = rsqrtf(ss / (float)DC_Q + EPS);
  const float* wp = w + lane * 8;
  float vv[8] = {v0.x, v0.y, v0.z, v0.w, v1.x, v1.y, v1.z, v1.w};
  bf16x8 o;
#pragma unroll
  for (int j = 0; j < 8; j++) o[j] = (bf16)(vv[j] * r * wp[j]);
  *reinterpret_cast<bf16x8*>(outp + (size_t)t * DC_Q + lane * 8) = o;
}

// ---------------- kv path: rmsnorm(16) + tiny GEMM (K=16) + k_rope RoPE ----------------
__global__ __launch_bounds__(256) void kv_fused_kernel(
    const float* __restrict__ ckv, const float* __restrict__ kvw,
    const float* __restrict__ Wkv_up, const int* __restrict__ pos_ids,
    const float* __restrict__ cos_t, const float* __restrict__ sin_t,
    bf16* __restrict__ kvb, bf16* __restrict__ kemb) {
  int t = blockIdx.x;
  const float* x = ckv + (size_t)t * 80;
  float c[16];
  float ss = 0.f;
#pragma unroll
  for (int k = 0; k < 16; k++) { float v = x[k]; c[k] = v; ss += v * v; }
  float r = rsqrtf(ss / 16.f + EPS);
#pragma unroll
  for (int k = 0; k < 16; k++) c[k] = c[k] * r * kvw[k];
  int n = threadIdx.x;
#pragma unroll
  for (int rep = 0; rep < 16; rep++, n += 256) {
    float acc = 0.f;
#pragma unroll
    for (int k = 0; k < 16; k++) acc += c[k] * Wkv_up[k * (H * MEG) + n];
    kvb[(size_t)t * (H * MEG) + n] = (bf16)acc;
  }
  if (threadIdx.x < 32) {
    int j = threadIdx.x;
    int pos = pos_ids[t];
    float cf = cos_t[pos * 32 + j], sf = sin_t[pos * 32 + j];
    float x0 = x[16 + 2 * j], x1 = x[16 + 2 * j + 1];
    kemb[(size_t)t * DR + j]      = (bf16)(x0 * cf - x1 * sf);
    kemb[(size_t)t * DR + 32 + j] = (bf16)(x1 * cf + x0 * sf);
  }
}

// ---------------- build Q (B*H, S, 192) with RoPE on last 64 ----------------
__global__ __launch_bounds__(192) void build_q_kernel(
    const bf16* __restrict__ qbf, const int* __restrict__ pos_ids,
    const float* __restrict__ cos_t, const float* __restrict__ sin_t,
    bf16* __restrict__ Q) {
  int blk = blockIdx.x;           // bh * S + s
  int s = blk & (S - 1);
  int bh = blk >> 11;
  int b = bh >> 4, h = bh & 15;
  int t = b * S + s;
  const bf16* src = qbf + (size_t)t * (H * QHD) + h * QHD;
  bf16* dst = Q + (size_t)blk * QHD;
  int tid = threadIdx.x;
  if (tid < 128) {
    dst[tid] = src[tid];
  } else if (tid < 160) {
    int j = tid - 128;
    int pos = pos_ids[t];
    float cf = cos_t[pos * 32 + j], sf = sin_t[pos * 32 + j];
    float x0 = (float)src[128 + 2 * j], x1 = (float)src[128 + 2 * j + 1];
    dst[128 + j] = (bf16)(x0 * cf - x1 * sf);
    dst[160 + j] = (bf16)(x1 * cf + x0 * sf);
  }
}

// ---------------- build K (B*H, S, 192) ----------------
__global__ __launch_bounds__(192) void build_k_kernel(
    const bf16* __restrict__ kvb, const bf16* __restrict__ kemb, bf16* __restrict__ Kt) {
  int blk = blockIdx.x;
  int s = blk & (S - 1);
  int bh = blk >> 11;
  int b = bh >> 4, h = bh & 15;
  int t = b * S + s;
  int tid = threadIdx.x;
  bf16* dst = Kt + (size_t)blk * QHD;
  dst[tid] = (tid < 128) ? kvb[(size_t)t * (H * MEG) + h * MEG + tid]
                         : kemb[(size_t)t * DR + (tid - 128)];
}

// ---------------- build V^T (B*H, 128, S) ----------------
__global__ __launch_bounds__(256) void build_vt_kernel(
    const bf16* __restrict__ kvb, bf16* __restrict__ Vt) {
  __shared__ bf16 tile[128][72];
  int bh = blockIdx.y;
  int b = bh >> 4, h = bh & 15;
  int s0 = blockIdx.x * 64;
  int tid = threadIdx.x;
#pragma unroll
  for (int e = tid; e < 8192; e += 256) {
    int si = e >> 7, v = e & 127;
    tile[v][si] = kvb[(size_t)(b * S + s0 + si) * (H * MEG) + h * MEG + 128 + v];
  }
  __syncthreads();
#pragma unroll
  for (int e = tid; e < 8192; e += 256) {
    int v = e >> 6, si = e & 63;
    Vt[((size_t)bh * 128 + v) * S + s0 + si] = tile[v][si];
  }
}

// ---------------- bf16 MFMA GEMM: C(MxN) = A(MxK) * Bt(NxK)^T ----------------
template <typename OutT>
__global__ __launch_bounds__(256) void gemm_bt_kernel(
    const bf16* __restrict__ A, const bf16* __restrict__ Bt,
    OutT* __restrict__ C, int M, int N, int K) {
  __shared__ bf16 As[128 * 64];
  __shared__ bf16 Bs[128 * 64];
  int tid = threadIdx.x;
  int wid = tid >> 6, lane = tid & 63;
  int g = lane >> 4, c = lane & 15;
  int wr = wid >> 1, wc = wid & 1;
  int m0 = blockIdx.y * 128, n0 = blockIdx.x * 128;

  f32x4 acc[4][4] = {};
  int nk = K >> 6;
  for (int kt = 0; kt < nk; kt++) {
    int k0 = kt << 6;
    __syncthreads();
#pragma unroll
    for (int r = 0; r < 4; r++) {
      int gg = tid + r * 256;
      int row = gg >> 3, slot = gg & 7;
      int sw = slot ^ (row & 7);
      {
        int gr = m0 + row;
        bf16x8 v = zero8();
        if (gr < M) v = *reinterpret_cast<const bf16x8*>(A + (size_t)gr * K + k0 + slot * 8);
        *reinterpret_cast<bf16x8*>(As + row * 64 + sw * 8) = v;
      }
      {
        int gr = n0 + row;
        bf16x8 v = zero8();
        if (gr < N) v = *reinterpret_cast<const bf16x8*>(Bt + (size_t)gr * K + k0 + slot * 8);
        *reinterpret_cast<bf16x8*>(Bs + row * 64 + sw * 8) = v;
      }
    }
    __syncthreads();
#pragma unroll
    for (int kk = 0; kk < 2; kk++) {
      bf16x8 af[4], bfr[4];
#pragma unroll
      for (int mi = 0; mi < 4; mi++) {
        int row = wr * 64 + mi * 16 + c;
        int sl = (kk * 4 + g) ^ (row & 7);
        af[mi] = *reinterpret_cast<const bf16x8*>(As + row * 64 + sl * 8);
      }
#pragma unroll
      for (int ni = 0; ni < 4; ni++) {
        int row = wc * 64 + ni * 16 + c;
        int sl = (kk * 4 + g) ^ (row & 7);
        bfr[ni] = *reinterpret_cast<const bf16x8*>(Bs + row * 64 + sl * 8);
      }
#pragma unroll
      for (int mi = 0; mi < 4; mi++)
#pragma unroll
        for (int ni = 0; ni < 4; ni++)
          acc[mi][ni] = __builtin_amdgcn_mfma_f32_16x16x32_bf16(af[mi], bfr[ni], acc[mi][ni], 0, 0, 0);
    }
  }
#pragma unroll
  for (int mi = 0; mi < 4; mi++)
#pragma unroll
    for (int ni = 0; ni < 4; ni++)
#pragma unroll
      for (int r = 0; r < 4; r++) {
        int row = m0 + wr * 64 + mi * 16 + g * 4 + r;
        int col = n0 + wc * 64 + ni * 16 + c;
        if (row < M && col < N) C[(size_t)row * N + col] = (OutT)acc[mi][ni][r];
      }
}

// ---------------- flash attention: 1 wave per (bh, 16 q-rows) ----------------
__global__ __launch_bounds__(64) void attn_kernel(
    const bf16* __restrict__ Q, const bf16* __restrict__ Kt,
    const bf16* __restrict__ Vt, bf16* __restrict__ O) {
  __shared__ bf16 pls[16 * 64];
  int bh = blockIdx.y;
  int qb = blockIdx.x;
  int q0 = qb * 16;
  int lane = threadIdx.x;
  int g = lane >> 4, cc = lane & 15;
  int b = bh >> 4, h = bh & 15;

  const bf16* Qp = Q + ((size_t)bh * S + q0 + cc) * QHD + g * 8;
  bf16x8 aq[6];
#pragma unroll
  for (int kk = 0; kk < 6; kk++) aq[kk] = *reinterpret_cast<const bf16x8*>(Qp + kk * 32);

  float mrow[4], lrow[4];
  f32x4 acc[8] = {};
#pragma unroll
  for (int r = 0; r < 4; r++) { mrow[r] = -INFINITY; lrow[r] = 0.f; }

  int nkt = (q0 + 15) / 64 + 1;
  for (int kt = 0; kt < nkt; kt++) {
    int k0 = kt * 64;
    f32x4 sacc[4] = {};
    const bf16* Kp = Kt + ((size_t)bh * S + k0 + cc) * QHD + g * 8;
#pragma unroll
    for (int kk = 0; kk < 6; kk++) {
#pragma unroll
      for (int nt = 0; nt < 4; nt++) {
        bf16x8 bk = *reinterpret_cast<const bf16x8*>(Kp + (size_t)nt * 16 * QHD + kk * 32);
        sacc[nt] = __builtin_amdgcn_mfma_f32_16x16x32_bf16(aq[kk], bk, sacc[nt], 0, 0, 0);
      }
    }
    float sv[4][4];
#pragma unroll
    for (int nt = 0; nt < 4; nt++)
#pragma unroll
      for (int r = 0; r < 4; r++) {
        int qrow = q0 + g * 4 + r, kcol = k0 + nt * 16 + cc;
        sv[nt][r] = (kcol <= qrow) ? sacc[nt][r] * SCALE : -INFINITY;
      }
    float scale_r[4];
#pragma unroll
    for (int r = 0; r < 4; r++) {
      float tm = fmaxf(fmaxf(sv[0][r], sv[1][r]), fmaxf(sv[2][r], sv[3][r]));
#pragma unroll
      for (int off = 1; off < 16; off <<= 1) tm = fmaxf(tm, __shfl_xor(tm, off));
      float mnew = fmaxf(mrow[r], tm);
      float sc = __expf(mrow[r] - mnew);
      float rs = 0.f;
#pragma unroll
      for (int nt = 0; nt < 4; nt++) {
        float p = __expf(sv[nt][r] - mnew);
        sv[nt][r] = p;
        rs += p;
      }
#pragma unroll
      for (int off = 1; off < 16; off <<= 1) rs += __shfl_xor(rs, off);
      lrow[r] = lrow[r] * sc + rs;
      mrow[r] = mnew;
      scale_r[r] = sc;
    }
#pragma unroll
    for (int i = 0; i < 8; i++)
#pragma unroll
      for (int r = 0; r < 4; r++) acc[i][r] *= scale_r[r];
    __syncthreads();
#pragma unroll
    for (int nt = 0; nt < 4; nt++)
#pragma unroll
      for (int r = 0; r < 4; r++) {
        int row = g * 4 + r, col = nt * 16 + cc;
        int byteoff = row * 128 + (((col >> 3) ^ (row & 7)) << 4) + ((col & 7) << 1);
        *reinterpret_cast<bf16*>(reinterpret_cast<char*>(pls) + byteoff) = (bf16)sv[nt][r];
      }
    __syncthreads();
#pragma unroll
    for (int kk2 = 0; kk2 < 2; kk2++) {
      int slot = (kk2 * 4 + g) ^ (cc & 7);
      bf16x8 pa = *reinterpret_cast<const bf16x8*>(reinterpret_cast<char*>(pls) + cc * 128 + slot * 16);
      const bf16* Vp = Vt + ((size_t)bh * 128 + cc) * S + k0 + kk2 * 32 + g * 8;
#pragma unroll
      for (int nt = 0; nt < 8; nt++) {
        bf16x8 bv = *reinterpret_cast<const bf16x8*>(Vp + (size_t)nt * 16 * S);
        acc[nt] = __builtin_amdgcn_mfma_f32_16x16x32_bf16(pa, bv, acc[nt], 0, 0, 0);
      }
    }
  }
#pragma unroll
  for (int nt = 0; nt < 8; nt++)
#pragma unroll
    for (int r = 0; r < 4; r++) {
      int qrow = q0 + g * 4 + r;
      size_t t = (size_t)b * S + qrow;
      O[t * (H * DPH) + h * DPH + nt * 16 + cc] = (bf16)(acc[nt][r] / lrow[r]);
    }
}

// ---------------- host ----------------
extern "C" void kernel_launch(void* const* d_in, const int* in_sizes, int n_in,
                              void* d_out, int out_size, void* d_ws, size_t ws_size,
                              hipStream_t stream) {
  const float* inputs    = (const float*)d_in[0];
  const int*   pos_ids   = (const int*)d_in[1];
  const float* Wq_down   = (const float*)d_in[3];
  const float* q_norm_w  = (const float*)d_in[4];
  const float* Wq_up     = (const float*)d_in[5];
  const float* Wkv_down  = (const float*)d_in[6];
  const float* kv_norm_w = (const float*)d_in[7];
  const float* Wkv_up    = (const float*)d_in[8];
  const float* Wout      = (const float*)d_in[9];
  float* out = (float*)d_out;

  char* ws = (char*)d_ws;
  size_t off = 0;
  auto alloc = [&](size_t bytes) -> void* {
    void* p = ws + off;
    off += (bytes + 255) & ~(size_t)255;
    return p;
  };

  bf16*  in_bf = (bf16*)alloc((size_t)T * D * 2);
  bf16*  WqdT  = (bf16*)alloc((size_t)DC_Q * D * 2);
  bf16*  WquT  = (bf16*)alloc((size_t)(H * QHD) * DC_Q * 2);
  bf16*  WkvdT = (bf16*)alloc((size_t)80 * D * 2);
  bf16*  WoutT = (bf16*)alloc((size_t)D * (H * DPH) * 2);
  float* cq    = (float*)alloc((size_t)T * DC_Q * 4);
  bf16*  cqn   = (bf16*)alloc((size_t)T * DC_Q * 2);
  bf16*  qbf   = (bf16*)alloc((size_t)T * (H * QHD) * 2);
  float* ckv   = (float*)alloc((size_t)T * 80 * 4);
  bf16*  kemb  = (bf16*)alloc((size_t)T * DR * 2);
  bf16*  kvb   = (bf16*)alloc((size_t)T * (H * MEG) * 2);
  bf16*  Qb    = (bf16*)alloc((size_t)B * H * S * QHD * 2);
  bf16*  Kb    = (bf16*)alloc((size_t)B * H * S * QHD * 2);
  bf16*  Vt    = (bf16*)alloc((size_t)B * H * DPH * S * 2);
  bf16*  abf   = (bf16*)alloc((size_t)T * (H * DPH) * 2);
  float* cos_t = (float*)alloc((size_t)S * 32 * 4);
  float* sin_t = (float*)alloc((size_t)S * 32 * 4);

  rope_table_kernel<<<S * 32 / 64, 64, 0, stream>>>(cos_t, sin_t);
  cast_bf16_kernel<<<(T * D / 4 + 255) / 256, 256, 0, stream>>>(inputs, in_bf, T * D);
  transpose_cast_kernel<<<dim3((DC_Q + 31) / 32, (D + 31) / 32), 256, 0, stream>>>(Wq_down, WqdT, D, DC_Q);
  transpose_cast_kernel<<<dim3((H * QHD + 31) / 32, (DC_Q + 31) / 32), 256, 0, stream>>>(Wq_up, WquT, DC_Q, H * QHD);
  transpose_cast_kernel<<<dim3((80 + 31) / 32, (D + 31) / 32), 256, 0, stream>>>(Wkv_down, WkvdT, D, 80);
  transpose_cast_kernel<<<dim3((D + 31) / 32, (H * DPH + 31) / 32), 256, 0, stream>>>(Wout, WoutT, H * DPH, D);

  gemm_bt_kernel<float><<<dim3(DC_Q / 128, T / 128), 256, 0, stream>>>(in_bf, WqdT, cq, T, DC_Q, D);
  rmsnorm_q_kernel<<<T / 4, 256, 0, stream>>>(cq, q_norm_w, cqn);
  gemm_bt_kernel<bf16><<<dim3(H * QHD / 128, T / 128), 256, 0, stream>>>(cqn, WquT, qbf, T, H * QHD, DC_Q);
  gemm_bt_kernel<float><<<dim3(1, T / 128), 256, 0, stream>>>(in_bf, WkvdT, ckv, T, 80, D);
  kv_fused_kernel<<<T, 256, 0, stream>>>(ckv, kv_norm_w, Wkv_up, pos_ids, cos_t, sin_t, kvb, kemb);
  build_q_kernel<<<B * H * S, 192, 0, stream>>>(qbf, pos_ids, cos_t, sin_t, Qb);
  build_k_kernel<<<B * H * S, 192, 0, stream>>>(kvb, kemb, Kb);
  build_vt_kernel<<<dim3(S / 64, B * H), 256, 0, stream>>>(kvb, Vt);
  attn_kernel<<<dim3(S / 16, B * H), 64, 0, stream>>>(Qb, Kb, Vt, abf);
  gemm_bt_kernel<float><<<dim3(D / 128, T / 128), 256, 0, stream>>>(abf, WoutT, out, T, D, D);
}

// Round 2
// 704.596 us; speedup vs baseline: 1.4004x; 1.4004x over previous
//
#include <hip/hip_runtime.h>

typedef __bf16 bf16;
typedef __bf16 bf16x8 __attribute__((ext_vector_type(8)));
typedef __bf16 bf16x4 __attribute__((ext_vector_type(4)));
typedef float f32x4 __attribute__((ext_vector_type(4)));

constexpr int D = 2048, H = 16, DPH = 128, DR = 64, DC_KV = 16, DC_Q = 512;
constexpr int QHD = 192, MEG = 256, B = 2, S = 2048;
constexpr int T = B * S;
constexpr float EPS = 1e-7f;
constexpr float SCALE = 0.07216878364870323f; // 1/sqrt(192)

static __device__ __forceinline__ bf16x8 zero8() {
  bf16x8 v;
#pragma unroll
  for (int j = 0; j < 8; j++) v[j] = (bf16)0.f;
  return v;
}

static __device__ __forceinline__ void gload_lds16(const bf16* g, bf16* l) {
  __builtin_amdgcn_global_load_lds(
      (const __attribute__((address_space(1))) unsigned int*)g,
      (__attribute__((address_space(3))) unsigned int*)l, 16, 0, 0);
}

// ---------------- rope table (f64 precision, once) ----------------
__global__ void rope_table_kernel(float* __restrict__ cos_t, float* __restrict__ sin_t) {
  int i = blockIdx.x * 64 + threadIdx.x;  // over S*32
  int pos = i >> 5, j = i & 31;
  double invf = pow(10000.0, -(double)(2 * j) / 64.0);
  double a = (double)pos * invf;
  cos_t[i] = (float)cos(a);
  sin_t[i] = (float)sin(a);
}

// ---------------- f32 -> bf16 cast ----------------
__global__ void cast_bf16_kernel(const float* __restrict__ in, bf16* __restrict__ out, int n) {
  int i = (blockIdx.x * blockDim.x + threadIdx.x) * 4;
  if (i < n) {
    float4 v = *reinterpret_cast<const float4*>(in + i);
    bf16x4 o;
    o[0] = (bf16)v.x; o[1] = (bf16)v.y; o[2] = (bf16)v.z; o[3] = (bf16)v.w;
    *reinterpret_cast<bf16x4*>(out + i) = o;
  }
}

// ---------------- transpose + cast: out[n][k] = (bf16) in[k][n], in is K x N f32 ----------------
__global__ __launch_bounds__(256) void transpose_cast_kernel(
    const float* __restrict__ in, bf16* __restrict__ out, int K, int N) {
  __shared__ float tile[32][33];
  int k0 = blockIdx.y * 32, n0 = blockIdx.x * 32;
  int tid = threadIdx.x;
#pragma unroll
  for (int e = tid; e < 1024; e += 256) {
    int i = e >> 5, j = e & 31;
    int k = k0 + i, n = n0 + j;
    tile[i][j] = (k < K && n < N) ? in[(size_t)k * N + n] : 0.f;
  }
  __syncthreads();
#pragma unroll
  for (int e = tid; e < 1024; e += 256) {
    int jj = e >> 5, ii = e & 31;
    int n = n0 + jj, k = k0 + ii;
    if (k < K && n < N) out[(size_t)n * K + k] = (bf16)tile[ii][jj];
  }
}

// ---------------- RMSNorm over 512 dims (q path) ----------------
__global__ __launch_bounds__(256) void rmsnorm_q_kernel(
    const float* __restrict__ cq, const float* __restrict__ w, bf16* __restrict__ outp) {
  int wid = threadIdx.x >> 6, lane = threadIdx.x & 63;
  int t = blockIdx.x * 4 + wid;
  const float* x = cq + (size_t)t * DC_Q;
  float4 v0 = *reinterpret_cast<const float4*>(x + lane * 8);
  float4 v1 = *reinterpret_cast<const float4*>(x + lane * 8 + 4);
  float ss = v0.x * v0.x + v0.y * v0.y + v0.z * v0.z + v0.w * v0.w +
             v1.x * v1.x + v1.y * v1.y + v1.z * v1.z + v1.w * v1.w;
#pragma unroll
  for (int off = 32; off; off >>= 1) ss += __shfl_xor(ss, off);
  float r = rsqrtf(ss / (float)DC_Q + EPS);
  const float* wp = w + lane * 8;
  float vv[8] = {v0.x, v0.y, v0.z, v0.w, v1.x, v1.y, v1.z, v1.w};
  bf16x8 o;
#pragma unroll
  for (int j = 0; j < 8; j++) o[j] = (bf16)(vv[j] * r * wp[j]);
  *reinterpret_cast<bf16x8*>(outp + (size_t)t * DC_Q + lane * 8) = o;
}

// ---------------- kv path: rmsnorm(16) + tiny GEMM (K=16) + k_rope RoPE ----------------
__global__ __launch_bounds__(256) void kv_fused_kernel(
    const float* __restrict__ ckv, const float* __restrict__ kvw,
    const float* __restrict__ Wkv_up, const int* __restrict__ pos_ids,
    const float* __restrict__ cos_t, const float* __restrict__ sin_t,
    bf16* __restrict__ kvb, bf16* __restrict__ kemb) {
  int t = blockIdx.x;
  const float* x = ckv + (size_t)t * 80;
  float c[16];
  float ss = 0.f;
#pragma unroll
  for (int k = 0; k < 16; k++) { float v = x[k]; c[k] = v; ss += v * v; }
  float r = rsqrtf(ss / 16.f + EPS);
#pragma unroll
  for (int k = 0; k < 16; k++) c[k] = c[k] * r * kvw[k];
  int n = threadIdx.x;
#pragma unroll
  for (int rep = 0; rep < 16; rep++, n += 256) {
    float acc = 0.f;
#pragma unroll
    for (int k = 0; k < 16; k++) acc += c[k] * Wkv_up[k * (H * MEG) + n];
    kvb[(size_t)t * (H * MEG) + n] = (bf16)acc;
  }
  if (threadIdx.x < 32) {
    int j = threadIdx.x;
    int pos = pos_ids[t];
    float cf = cos_t[pos * 32 + j], sf = sin_t[pos * 32 + j];
    float x0 = x[16 + 2 * j], x1 = x[16 + 2 * j + 1];
    kemb[(size_t)t * DR + j]      = (bf16)(x0 * cf - x1 * sf);
    kemb[(size_t)t * DR + 32 + j] = (bf16)(x1 * cf + x0 * sf);
  }
}

// ---------------- build V^T (B*H, 128, S) ----------------
__global__ __launch_bounds__(256) void build_vt_kernel(
    const bf16* __restrict__ kvb, bf16* __restrict__ Vt) {
  __shared__ bf16 tile[128][72];
  int bh = blockIdx.y;
  int b = bh >> 4, h = bh & 15;
  int s0 = blockIdx.x * 64;
  int tid = threadIdx.x;
#pragma unroll
  for (int e = tid; e < 8192; e += 256) {
    int si = e >> 7, v = e & 127;
    tile[v][si] = kvb[(size_t)(b * S + s0 + si) * (H * MEG) + h * MEG + 128 + v];
  }
  __syncthreads();
#pragma unroll
  for (int e = tid; e < 8192; e += 256) {
    int v = e >> 6, si = e & 63;
    Vt[((size_t)bh * 128 + v) * S + s0 + si] = tile[v][si];
  }
}

// ---------------- bf16 MFMA GEMM: C(MxN) = A(MxK) * Bt(NxK)^T ----------------
template <typename OutT>
__global__ __launch_bounds__(256) void gemm_bt_kernel(
    const bf16* __restrict__ A, const bf16* __restrict__ Bt,
    OutT* __restrict__ C, int M, int N, int K) {
  __shared__ bf16 As[128 * 64];
  __shared__ bf16 Bs[128 * 64];
  int tid = threadIdx.x;
  int wid = tid >> 6, lane = tid & 63;
  int g = lane >> 4, c = lane & 15;
  int wr = wid >> 1, wc = wid & 1;
  int m0 = blockIdx.y * 128, n0 = blockIdx.x * 128;

  f32x4 acc[4][4] = {};
  int nk = K >> 6;
  for (int kt = 0; kt < nk; kt++) {
    int k0 = kt << 6;
    __syncthreads();
#pragma unroll
    for (int r = 0; r < 4; r++) {
      int gg = tid + r * 256;
      int row = gg >> 3, slot = gg & 7;
      int sw = slot ^ (row & 7);
      {
        int gr = m0 + row;
        bf16x8 v = zero8();
        if (gr < M) v = *reinterpret_cast<const bf16x8*>(A + (size_t)gr * K + k0 + slot * 8);
        *reinterpret_cast<bf16x8*>(As + row * 64 + sw * 8) = v;
      }
      {
        int gr = n0 + row;
        bf16x8 v = zero8();
        if (gr < N) v = *reinterpret_cast<const bf16x8*>(Bt + (size_t)gr * K + k0 + slot * 8);
        *reinterpret_cast<bf16x8*>(Bs + row * 64 + sw * 8) = v;
      }
    }
    __syncthreads();
#pragma unroll
    for (int kk = 0; kk < 2; kk++) {
      bf16x8 af[4], bfr[4];
#pragma unroll
      for (int mi = 0; mi < 4; mi++) {
        int row = wr * 64 + mi * 16 + c;
        int sl = (kk * 4 + g) ^ (row & 7);
        af[mi] = *reinterpret_cast<const bf16x8*>(As + row * 64 + sl * 8);
      }
#pragma unroll
      for (int ni = 0; ni < 4; ni++) {
        int row = wc * 64 + ni * 16 + c;
        int sl = (kk * 4 + g) ^ (row & 7);
        bfr[ni] = *reinterpret_cast<const bf16x8*>(Bs + row * 64 + sl * 8);
      }
#pragma unroll
      for (int mi = 0; mi < 4; mi++)
#pragma unroll
        for (int ni = 0; ni < 4; ni++)
          acc[mi][ni] = __builtin_amdgcn_mfma_f32_16x16x32_bf16(af[mi], bfr[ni], acc[mi][ni], 0, 0, 0);
    }
  }
#pragma unroll
  for (int mi = 0; mi < 4; mi++)
#pragma unroll
    for (int ni = 0; ni < 4; ni++)
#pragma unroll
      for (int r = 0; r < 4; r++) {
        int row = m0 + wr * 64 + mi * 16 + g * 4 + r;
        int col = n0 + wc * 64 + ni * 16 + c;
        if (row < M && col < N) C[(size_t)row * N + col] = (OutT)acc[mi][ni][r];
      }
}

// ---------------- flash attention: 4 waves, 128 q-rows per block, 64-key tiles ----------------
// K assembled from kvb+kemb during LDS staging; Q-RoPE folded into fragment preload.
// LDS layouts are [slot][row] with 16B entries -> conflict-free ds_read_b128.
__global__ __launch_bounds__(256) void attn_kernel(
    const bf16* __restrict__ qbf, const bf16* __restrict__ kvb,
    const bf16* __restrict__ kemb, const bf16* __restrict__ Vt,
    const int* __restrict__ pos_ids,
    const float* __restrict__ cos_t, const float* __restrict__ sin_t,
    bf16* __restrict__ O) {
  __shared__ bf16 Kls[24][64][8];   // 24 KB: K slot s = cols s*8..s*8+7, row = key
  __shared__ bf16 Vls[8][128][8];   // 16 KB: V slot s = keys s*8..s*8+7, row = v
  __shared__ bf16 Pls[4][16 * 64];  // 8 KB: per-wave P staging (swizzled)

  int lin = blockIdx.y * gridDim.x + blockIdx.x;  // 0..511
  int bh = lin & 31;          // 4 bh per XCD -> KV set ~fits XCD L2
  int qb = 15 - (lin >> 5);   // heavy causal blocks dispatched first
  int b = bh >> 4, h = bh & 15;
  int q0 = qb * 128;
  int tid = threadIdx.x;
  int w = tid >> 6, lane = tid & 63;
  int g = lane >> 4, cc = lane & 15;
  int qw0 = q0 + w * 32;

  // ---- Q fragments (with RoPE on cols 128..191), kept in registers ----
  bf16x8 aq[2][6];
#pragma unroll
  for (int m = 0; m < 2; m++) {
    int qrow = qw0 + m * 16 + cc;
    const bf16* qp = qbf + (size_t)(b * S + qrow) * (H * QHD) + h * QHD;
#pragma unroll
    for (int kk = 0; kk < 4; kk++)
      aq[m][kk] = *reinterpret_cast<const bf16x8*>(qp + kk * 32 + g * 8);
    int pos = pos_ids[b * S + qrow];
    float4 c0 = *reinterpret_cast<const float4*>(cos_t + pos * 32 + g * 8);
    float4 c1 = *reinterpret_cast<const float4*>(cos_t + pos * 32 + g * 8 + 4);
    float4 s0 = *reinterpret_cast<const float4*>(sin_t + pos * 32 + g * 8);
    float4 s1 = *reinterpret_cast<const float4*>(sin_t + pos * 32 + g * 8 + 4);
    bf16x8 x01 = *reinterpret_cast<const bf16x8*>(qp + 128 + g * 16);
    bf16x8 x23 = *reinterpret_cast<const bf16x8*>(qp + 128 + g * 16 + 8);
    float cf[8] = {c0.x, c0.y, c0.z, c0.w, c1.x, c1.y, c1.z, c1.w};
    float sf[8] = {s0.x, s0.y, s0.z, s0.w, s1.x, s1.y, s1.z, s1.w};
    float x0v[8], x1v[8];
#pragma unroll
    for (int j = 0; j < 4; j++) { x0v[j] = (float)x01[2 * j]; x1v[j] = (float)x01[2 * j + 1]; }
#pragma unroll
    for (int j = 0; j < 4; j++) { x0v[4 + j] = (float)x23[2 * j]; x1v[4 + j] = (float)x23[2 * j + 1]; }
#pragma unroll
    for (int j = 0; j < 8; j++) {
      aq[m][4][j] = (bf16)(x0v[j] * cf[j] - x1v[j] * sf[j]);
      aq[m][5][j] = (bf16)(x1v[j] * cf[j] + x0v[j] * sf[j]);
    }
  }

  float mrow[2][4], lrow[2][4];
  f32x4 acc[2][8] = {};
#pragma unroll
  for (int m = 0; m < 2; m++)
#pragma unroll
    for (int r = 0; r < 4; r++) { mrow[m][r] = -1e30f; lrow[m][r] = 0.f; }

  int nkt = q0 / 64 + 2;
  for (int kt = 0; kt < nkt; kt++) {
    int k0 = kt * 64;
    __syncthreads();  // previous tile's LDS reads complete
    // ---- stage K: slot s covers cols s*8..s*8+7; s<16 from kvb, s>=16 from kemb
#pragma unroll
    for (int s6 = 0; s6 < 6; s6++) {
      int s = w * 6 + s6;
      const bf16* src = (s < 16)
          ? kvb + (size_t)(b * S + k0 + lane) * (H * MEG) + h * MEG + s * 8
          : kemb + (size_t)(b * S + k0 + lane) * DR + (s - 16) * 8;
      gload_lds16(src, &Kls[s][lane][0]);
    }
    // ---- stage V: slot s covers keys s*8..s*8+7, rows = v
#pragma unroll
    for (int c4 = 0; c4 < 4; c4++) {
      int ch = w * 4 + c4;
      int s = ch >> 1, hf = ch & 1;
      int v = hf * 64 + lane;
      const bf16* src = Vt + ((size_t)bh * DPH + v) * S + k0 + s * 8;
      gload_lds16(src, &Vls[s][v][0]);
    }
    __syncthreads();  // compiler drains vmcnt before barrier

    if (k0 > qw0 + 31) continue;  // fully masked for this wave (barriers still aligned)

    // ---- QK^T ----
    f32x4 sacc[2][4] = {};
#pragma unroll
    for (int kk = 0; kk < 6; kk++) {
#pragma unroll
      for (int nt = 0; nt < 4; nt++) {
        bf16x8 bk = *reinterpret_cast<const bf16x8*>(&Kls[kk * 4 + g][nt * 16 + cc][0]);
        sacc[0][nt] = __builtin_amdgcn_mfma_f32_16x16x32_bf16(aq[0][kk], bk, sacc[0][nt], 0, 0, 0);
        sacc[1][nt] = __builtin_amdgcn_mfma_f32_16x16x32_bf16(aq[1][kk], bk, sacc[1][nt], 0, 0, 0);
      }
    }

    bool diag = (k0 + 63 > qw0);
    char* pbase = reinterpret_cast<char*>(&Pls[w][0]);
#pragma unroll
    for (int m = 0; m < 2; m++) {
      float sv[4][4];
#pragma unroll
      for (int nt = 0; nt < 4; nt++)
#pragma unroll
        for (int r = 0; r < 4; r++) {
          float x = sacc[m][nt][r] * SCALE;
          if (diag) {
            int qrow = qw0 + m * 16 + g * 4 + r, kcol = k0 + nt * 16 + cc;
            if (kcol > qrow) x = -1e30f;
          }
          sv[nt][r] = x;
        }
      float scl[4];
#pragma unroll
      for (int r = 0; r < 4; r++) {
        float tm = fmaxf(fmaxf(sv[0][r], sv[1][r]), fmaxf(sv[2][r], sv[3][r]));
#pragma unroll
        for (int off = 1; off < 16; off <<= 1) tm = fmaxf(tm, __shfl_xor(tm, off));
        float mold = mrow[m][r];
        float mnew = fmaxf(mold, tm);
        float sc = __expf(mold - mnew);
        float rs = 0.f;
#pragma unroll
        for (int nt = 0; nt < 4; nt++) {
          float p = __expf(sv[nt][r] - mnew);
          sv[nt][r] = p;
          rs += p;
        }
#pragma unroll
        for (int off = 1; off < 16; off <<= 1) rs += __shfl_xor(rs, off);
        lrow[m][r] = lrow[m][r] * sc + rs;
        mrow[m][r] = mnew;
        scl[r] = sc;
      }
#pragma unroll
      for (int nt = 0; nt < 8; nt++)
#pragma unroll
        for (int r = 0; r < 4; r++) acc[m][nt][r] *= scl[r];
      // ---- P -> LDS (swizzled), wave-local ----
#pragma unroll
      for (int nt = 0; nt < 4; nt++)
#pragma unroll
        for (int r = 0; r < 4; r++) {
          int row = g * 4 + r, col = nt * 16 + cc;
          int off2 = row * 128 + (((col >> 3) ^ (row & 7)) << 4) + ((col & 7) << 1);
          *reinterpret_cast<bf16*>(pbase + off2) = (bf16)sv[nt][r];
        }
      asm volatile("s_waitcnt lgkmcnt(0)" ::: "memory");
      // ---- PV ----
#pragma unroll
      for (int kk2 = 0; kk2 < 2; kk2++) {
        int slot = (kk2 * 4 + g) ^ (cc & 7);
        bf16x8 pa = *reinterpret_cast<const bf16x8*>(pbase + cc * 128 + slot * 16);
#pragma unroll
        for (int nt = 0; nt < 8; nt++) {
          bf16x8 bv = *reinterpret_cast<const bf16x8*>(&Vls[kk2 * 4 + g][nt * 16 + cc][0]);
          acc[m][nt] = __builtin_amdgcn_mfma_f32_16x16x32_bf16(pa, bv, acc[m][nt], 0, 0, 0);
        }
      }
    }
  }

#pragma unroll
  for (int m = 0; m < 2; m++)
#pragma unroll
    for (int nt = 0; nt < 8; nt++)
#pragma unroll
      for (int r = 0; r < 4; r++) {
        int qrow = qw0 + m * 16 + g * 4 + r;
        O[(size_t)(b * S + qrow) * (H * DPH) + h * DPH + nt * 16 + cc] =
            (bf16)(acc[m][nt][r] / lrow[m][r]);
      }
}

// ---------------- host ----------------
extern "C" void kernel_launch(void* const* d_in, const int* in_sizes, int n_in,
                              void* d_out, int out_size, void* d_ws, size_t ws_size,
                              hipStream_t stream) {
  const float* inputs    = (const float*)d_in[0];
  const int*   pos_ids   = (const int*)d_in[1];
  const float* Wq_down   = (const float*)d_in[3];
  const float* q_norm_w  = (const float*)d_in[4];
  const float* Wq_up     = (const float*)d_in[5];
  const float* Wkv_down  = (const float*)d_in[6];
  const float* kv_norm_w = (const float*)d_in[7];
  const float* Wkv_up    = (const float*)d_in[8];
  const float* Wout      = (const float*)d_in[9];
  float* out = (float*)d_out;

  char* ws = (char*)d_ws;
  size_t off = 0;
  auto alloc = [&](size_t bytes) -> void* {
    void* p = ws + off;
    off += (bytes + 255) & ~(size_t)255;
    return p;
  };

  bf16*  in_bf = (bf16*)alloc((size_t)T * D * 2);
  bf16*  WqdT  = (bf16*)alloc((size_t)DC_Q * D * 2);
  bf16*  WquT  = (bf16*)alloc((size_t)(H * QHD) * DC_Q * 2);
  bf16*  WkvdT = (bf16*)alloc((size_t)80 * D * 2);
  bf16*  WoutT = (bf16*)alloc((size_t)D * (H * DPH) * 2);
  float* cq    = (float*)alloc((size_t)T * DC_Q * 4);
  bf16*  cqn   = (bf16*)alloc((size_t)T * DC_Q * 2);
  bf16*  qbf   = (bf16*)alloc((size_t)T * (H * QHD) * 2);
  float* ckv   = (float*)alloc((size_t)T * 80 * 4);
  bf16*  kemb  = (bf16*)alloc((size_t)T * DR * 2);
  bf16*  kvb   = (bf16*)alloc((size_t)T * (H * MEG) * 2);
  bf16*  Vt    = (bf16*)alloc((size_t)B * H * DPH * S * 2);
  bf16*  abf   = (bf16*)alloc((size_t)T * (H * DPH) * 2);
  float* cos_t = (float*)alloc((size_t)S * 32 * 4);
  float* sin_t = (float*)alloc((size_t)S * 32 * 4);

  rope_table_kernel<<<S * 32 / 64, 64, 0, stream>>>(cos_t, sin_t);
  cast_bf16_kernel<<<(T * D / 4 + 255) / 256, 256, 0, stream>>>(inputs, in_bf, T * D);
  transpose_cast_kernel<<<dim3((DC_Q + 31) / 32, (D + 31) / 32), 256, 0, stream>>>(Wq_down, WqdT, D, DC_Q);
  transpose_cast_kernel<<<dim3((H * QHD + 31) / 32, (DC_Q + 31) / 32), 256, 0, stream>>>(Wq_up, WquT, DC_Q, H * QHD);
  transpose_cast_kernel<<<dim3((80 + 31) / 32, (D + 31) / 32), 256, 0, stream>>>(Wkv_down, WkvdT, D, 80);
  transpose_cast_kernel<<<dim3((D + 31) / 32, (H * DPH + 31) / 32), 256, 0, stream>>>(Wout, WoutT, H * DPH, D);

  gemm_bt_kernel<float><<<dim3(DC_Q / 128, T / 128), 256, 0, stream>>>(in_bf, WqdT, cq, T, DC_Q, D);
  rmsnorm_q_kernel<<<T / 4, 256, 0, stream>>>(cq, q_norm_w, cqn);
  gemm_bt_kernel<bf16><<<dim3(H * QHD / 128, T / 128), 256, 0, stream>>>(cqn, WquT, qbf, T, H * QHD, DC_Q);
  gemm_bt_kernel<float><<<dim3(1, T / 128), 256, 0, stream>>>(in_bf, WkvdT, ckv, T, 80, D);
  kv_fused_kernel<<<T, 256, 0, stream>>>(ckv, kv_norm_w, Wkv_up, pos_ids, cos_t, sin_t, kvb, kemb);
  build_vt_kernel<<<dim3(S / 64, B * H), 256, 0, stream>>>(kvb, Vt);
  attn_kernel<<<dim3(16, 32), 256, 0, stream>>>(qbf, kvb, kemb, Vt, pos_ids, cos_t, sin_t, abf);
  gemm_bt_kernel<float><<<dim3(D / 128, T / 128), 256, 0, stream>>>(abf, WoutT, out, T, D, D);
}

// Round 3
// 576.220 us; speedup vs baseline: 1.7124x; 1.2228x over previous
//
#include <hip/hip_runtime.h>

typedef __bf16 bf16;
typedef __bf16 bf16x8 __attribute__((ext_vector_type(8)));
typedef __bf16 bf16x4 __attribute__((ext_vector_type(4)));
typedef float f32x4 __attribute__((ext_vector_type(4)));

constexpr int D = 2048, H = 16, DPH = 128, DR = 64, DC_KV = 16, DC_Q = 512;
constexpr int QHD = 192, MEG = 256, B = 2, S = 2048;
constexpr int T = B * S;
constexpr int NDN = DC_Q + 80;  // fused down-proj width (512 q + 80 kv)
constexpr float EPS = 1e-7f;
constexpr float SCALE = 0.07216878364870323f; // 1/sqrt(192)

static __device__ __forceinline__ bf16x8 zero8() {
  bf16x8 v;
#pragma unroll
  for (int j = 0; j < 8; j++) v[j] = (bf16)0.f;
  return v;
}

#define VMWAIT0 do { asm volatile("s_waitcnt vmcnt(0)" ::: "memory"); __builtin_amdgcn_sched_barrier(0); } while (0)
#define LGWAIT0 do { asm volatile("s_waitcnt lgkmcnt(0)" ::: "memory"); __builtin_amdgcn_sched_barrier(0); } while (0)

// ---------------- rope table (f64 precision, once) ----------------
__global__ void rope_table_kernel(float* __restrict__ cos_t, float* __restrict__ sin_t) {
  int i = blockIdx.x * 64 + threadIdx.x;  // over S*32
  int pos = i >> 5, j = i & 31;
  double invf = pow(10000.0, -(double)(2 * j) / 64.0);
  double a = (double)pos * invf;
  cos_t[i] = (float)cos(a);
  sin_t[i] = (float)sin(a);
}

// ---------------- f32 -> bf16 cast ----------------
__global__ void cast_bf16_kernel(const float* __restrict__ in, bf16* __restrict__ out, int n) {
  int i = (blockIdx.x * blockDim.x + threadIdx.x) * 4;
  if (i < n) {
    float4 v = *reinterpret_cast<const float4*>(in + i);
    bf16x4 o;
    o[0] = (bf16)v.x; o[1] = (bf16)v.y; o[2] = (bf16)v.z; o[3] = (bf16)v.w;
    *reinterpret_cast<bf16x4*>(out + i) = o;
  }
}

// ---------------- transpose + cast: out[n][k] = (bf16) in[k][n], in is K x N f32 ----------------
__global__ __launch_bounds__(256) void transpose_cast_kernel(
    const float* __restrict__ in, bf16* __restrict__ out, int K, int N) {
  __shared__ float tile[32][33];
  int k0 = blockIdx.y * 32, n0 = blockIdx.x * 32;
  int tid = threadIdx.x;
#pragma unroll
  for (int e = tid; e < 1024; e += 256) {
    int i = e >> 5, j = e & 31;
    int k = k0 + i, n = n0 + j;
    tile[i][j] = (k < K && n < N) ? in[(size_t)k * N + n] : 0.f;
  }
  __syncthreads();
#pragma unroll
  for (int e = tid; e < 1024; e += 256) {
    int jj = e >> 5, ii = e & 31;
    int n = n0 + jj, k = k0 + ii;
    if (k < K && n < N) out[(size_t)n * K + k] = (bf16)tile[ii][jj];
  }
}

// ---------------- RMSNorm over 512 dims (q path), input row stride ld ----------------
__global__ __launch_bounds__(256) void rmsnorm_q_kernel(
    const float* __restrict__ cq, const float* __restrict__ w, bf16* __restrict__ outp, int ld) {
  int wid = threadIdx.x >> 6, lane = threadIdx.x & 63;
  int t = blockIdx.x * 4 + wid;
  const float* x = cq + (size_t)t * ld;
  float4 v0 = *reinterpret_cast<const float4*>(x + lane * 8);
  float4 v1 = *reinterpret_cast<const float4*>(x + lane * 8 + 4);
  float ss = v0.x * v0.x + v0.y * v0.y + v0.z * v0.z + v0.w * v0.w +
             v1.x * v1.x + v1.y * v1.y + v1.z * v1.z + v1.w * v1.w;
#pragma unroll
  for (int off = 32; off; off >>= 1) ss += __shfl_xor(ss, off);
  float r = rsqrtf(ss / (float)DC_Q + EPS);
  const float* wp = w + lane * 8;
  float vv[8] = {v0.x, v0.y, v0.z, v0.w, v1.x, v1.y, v1.z, v1.w};
  bf16x8 o;
#pragma unroll
  for (int j = 0; j < 8; j++) o[j] = (bf16)(vv[j] * r * wp[j]);
  *reinterpret_cast<bf16x8*>(outp + (size_t)t * DC_Q + lane * 8) = o;
}

// ---------------- kv path: rmsnorm(16) + tiny GEMM (K=16) + k_rope RoPE ----------------
__global__ __launch_bounds__(256) void kv_fused_kernel(
    const float* __restrict__ ckv, int ld, const float* __restrict__ kvw,
    const float* __restrict__ Wkv_up, const int* __restrict__ pos_ids,
    const float* __restrict__ cos_t, const float* __restrict__ sin_t,
    bf16* __restrict__ kvb, bf16* __restrict__ kemb) {
  int t = blockIdx.x;
  const float* x = ckv + (size_t)t * ld;
  float c[16];
  float ss = 0.f;
#pragma unroll
  for (int k = 0; k < 16; k++) { float v = x[k]; c[k] = v; ss += v * v; }
  float r = rsqrtf(ss / 16.f + EPS);
#pragma unroll
  for (int k = 0; k < 16; k++) c[k] = c[k] * r * kvw[k];
  int n = threadIdx.x;
#pragma unroll
  for (int rep = 0; rep < 16; rep++, n += 256) {
    float acc = 0.f;
#pragma unroll
    for (int k = 0; k < 16; k++) acc += c[k] * Wkv_up[k * (H * MEG) + n];
    kvb[(size_t)t * (H * MEG) + n] = (bf16)acc;
  }
  if (threadIdx.x < 32) {
    int j = threadIdx.x;
    int pos = pos_ids[t];
    float cf = cos_t[pos * 32 + j], sf = sin_t[pos * 32 + j];
    float x0 = x[16 + 2 * j], x1 = x[16 + 2 * j + 1];
    kemb[(size_t)t * DR + j]      = (bf16)(x0 * cf - x1 * sf);
    kemb[(size_t)t * DR + 32 + j] = (bf16)(x1 * cf + x0 * sf);
  }
}

// ---------------- build V^T (B*H, 128, S) ----------------
__global__ __launch_bounds__(256) void build_vt_kernel(
    const bf16* __restrict__ kvb, bf16* __restrict__ Vt) {
  __shared__ bf16 tile[128][72];
  int bh = blockIdx.y;
  int b = bh >> 4, h = bh & 15;
  int s0 = blockIdx.x * 64;
  int tid = threadIdx.x;
#pragma unroll
  for (int e = tid; e < 8192; e += 256) {
    int si = e >> 7, v = e & 127;
    tile[v][si] = kvb[(size_t)(b * S + s0 + si) * (H * MEG) + h * MEG + 128 + v];
  }
  __syncthreads();
#pragma unroll
  for (int e = tid; e < 8192; e += 256) {
    int v = e >> 6, si = e & 63;
    Vt[((size_t)bh * 128 + v) * S + s0 + si] = tile[v][si];
  }
}

// ---------------- bf16 MFMA GEMM: C(MxN) = A(MxK) * Bt(NxK)^T ----------------
template <typename OutT>
__global__ __launch_bounds__(256) void gemm_bt_kernel(
    const bf16* __restrict__ A, const bf16* __restrict__ Bt,
    OutT* __restrict__ C, int M, int N, int K) {
  __shared__ bf16 As[128 * 64];
  __shared__ bf16 Bs[128 * 64];
  int tid = threadIdx.x;
  int wid = tid >> 6, lane = tid & 63;
  int g = lane >> 4, c = lane & 15;
  int wr = wid >> 1, wc = wid & 1;
  int m0 = blockIdx.y * 128, n0 = blockIdx.x * 128;

  f32x4 acc[4][4] = {};
  int nk = K >> 6;
  for (int kt = 0; kt < nk; kt++) {
    int k0 = kt << 6;
    __syncthreads();
#pragma unroll
    for (int r = 0; r < 4; r++) {
      int gg = tid + r * 256;
      int row = gg >> 3, slot = gg & 7;
      int sw = slot ^ (row & 7);
      {
        int gr = m0 + row;
        bf16x8 v = zero8();
        if (gr < M) v = *reinterpret_cast<const bf16x8*>(A + (size_t)gr * K + k0 + slot * 8);
        *reinterpret_cast<bf16x8*>(As + row * 64 + sw * 8) = v;
      }
      {
        int gr = n0 + row;
        bf16x8 v = zero8();
        if (gr < N) v = *reinterpret_cast<const bf16x8*>(Bt + (size_t)gr * K + k0 + slot * 8);
        *reinterpret_cast<bf16x8*>(Bs + row * 64 + sw * 8) = v;
      }
    }
    __syncthreads();
#pragma unroll
    for (int kk = 0; kk < 2; kk++) {
      bf16x8 af[4], bfr[4];
#pragma unroll
      for (int mi = 0; mi < 4; mi++) {
        int row = wr * 64 + mi * 16 + c;
        int sl = (kk * 4 + g) ^ (row & 7);
        af[mi] = *reinterpret_cast<const bf16x8*>(As + row * 64 + sl * 8);
      }
#pragma unroll
      for (int ni = 0; ni < 4; ni++) {
        int row = wc * 64 + ni * 16 + c;
        int sl = (kk * 4 + g) ^ (row & 7);
        bfr[ni] = *reinterpret_cast<const bf16x8*>(Bs + row * 64 + sl * 8);
      }
#pragma unroll
      for (int mi = 0; mi < 4; mi++)
#pragma unroll
        for (int ni = 0; ni < 4; ni++)
          acc[mi][ni] = __builtin_amdgcn_mfma_f32_16x16x32_bf16(af[mi], bfr[ni], acc[mi][ni], 0, 0, 0);
    }
  }
#pragma unroll
  for (int mi = 0; mi < 4; mi++)
#pragma unroll
    for (int ni = 0; ni < 4; ni++)
#pragma unroll
      for (int r = 0; r < 4; r++) {
        int row = m0 + wr * 64 + mi * 16 + g * 4 + r;
        int col = n0 + wc * 64 + ni * 16 + c;
        if (row < M && col < N) C[(size_t)row * N + col] = (OutT)acc[mi][ni][r];
      }
}

// ---------------- flash attention, paired causal q-tiles + async reg-staged K/V ----------------
// Block: 4 waves, Q-tile 64 rows (16/wave), KVBLK 64. Pair (pr, 31-pr): 33 k-tiles/block.
// Pipeline per tile: vmcnt(0); barrier; ds_write staged regs; issue next-tile loads;
// lgkmcnt(0); barrier; compute  -> global latency hides under compute (T14).
__global__ __launch_bounds__(256) void attn_kernel(
    const bf16* __restrict__ qbf, const bf16* __restrict__ kvb,
    const bf16* __restrict__ kemb, const bf16* __restrict__ Vt,
    const int* __restrict__ pos_ids,
    const float* __restrict__ cos_t, const float* __restrict__ sin_t,
    bf16* __restrict__ O) {
  __shared__ bf16 Kls[64][200];   // K rows (keys) x 192 cols, pad->200 (stride 100 words == 4 mod 32)
  __shared__ bf16 Vls[128][72];   // V rows (v) x 64 keys, pad->72
  __shared__ bf16 Pls[4][1024];   // per-wave P staging (swizzled)

  int lin = blockIdx.x;           // 0..511
  int bh = lin & 31;              // XCD i serves bh % 8 == i -> 4 bh per XCD
  int pr = lin >> 5;              // pair index 0..15
  int b = bh >> 4, h = bh & 15;
  int tid = threadIdx.x;
  int w = tid >> 6, lane = tid & 63;
  int g = lane >> 4, cc = lane & 15;

  auto load_stg = [&](int k0, bf16x8* stg) {
    const bf16* bk = kvb + (size_t)(b * S + k0) * (H * MEG) + h * MEG;
#pragma unroll
    for (int i = 0; i < 4; i++) {
      int eid = i * 256 + tid, key = eid >> 4, ch = eid & 15;
      stg[i] = *reinterpret_cast<const bf16x8*>(bk + (size_t)key * (H * MEG) + ch * 8);
    }
    const bf16* be = kemb + (size_t)(b * S + k0) * DR;
#pragma unroll
    for (int i = 0; i < 2; i++) {
      int eid = i * 256 + tid, key = eid >> 3, ch = eid & 7;
      stg[4 + i] = *reinterpret_cast<const bf16x8*>(be + (size_t)key * DR + ch * 8);
    }
    const bf16* bv = Vt + (size_t)bh * DPH * S + k0;
#pragma unroll
    for (int i = 0; i < 4; i++) {
      int eid = i * 256 + tid, v = eid >> 3, ch = eid & 7;
      stg[6 + i] = *reinterpret_cast<const bf16x8*>(bv + (size_t)v * S + ch * 8);
    }
  };

#pragma unroll 1
  for (int ph = 0; ph < 2; ph++) {
    int qt = ph ? (31 - pr) : pr;
    int q0 = qt * 64;
    int qw0 = q0 + w * 16;
    int nt = qt + 1;

    // ---- Q fragments (RoPE folded), registers ----
    int qrow = qw0 + cc;
    const bf16* qp = qbf + (size_t)(b * S + qrow) * (H * QHD) + h * QHD;
    bf16x8 aq[6];
#pragma unroll
    for (int kk = 0; kk < 4; kk++)
      aq[kk] = *reinterpret_cast<const bf16x8*>(qp + kk * 32 + g * 8);
    {
      int pos = pos_ids[b * S + qrow];
      float4 c0 = *reinterpret_cast<const float4*>(cos_t + pos * 32 + g * 8);
      float4 c1 = *reinterpret_cast<const float4*>(cos_t + pos * 32 + g * 8 + 4);
      float4 s0 = *reinterpret_cast<const float4*>(sin_t + pos * 32 + g * 8);
      float4 s1 = *reinterpret_cast<const float4*>(sin_t + pos * 32 + g * 8 + 4);
      bf16x8 x01 = *reinterpret_cast<const bf16x8*>(qp + 128 + g * 16);
      bf16x8 x23 = *reinterpret_cast<const bf16x8*>(qp + 128 + g * 16 + 8);
      float cf[8] = {c0.x, c0.y, c0.z, c0.w, c1.x, c1.y, c1.z, c1.w};
      float sf[8] = {s0.x, s0.y, s0.z, s0.w, s1.x, s1.y, s1.z, s1.w};
      float x0v[8], x1v[8];
#pragma unroll
      for (int j = 0; j < 4; j++) { x0v[j] = (float)x01[2 * j]; x1v[j] = (float)x01[2 * j + 1]; }
#pragma unroll
      for (int j = 0; j < 4; j++) { x0v[4 + j] = (float)x23[2 * j]; x1v[4 + j] = (float)x23[2 * j + 1]; }
#pragma unroll
      for (int j = 0; j < 8; j++) {
        aq[4][j] = (bf16)(x0v[j] * cf[j] - x1v[j] * sf[j]);
        aq[5][j] = (bf16)(x1v[j] * cf[j] + x0v[j] * sf[j]);
      }
    }

    float mrow[4], lrow[4];
    f32x4 acc[8] = {};
#pragma unroll
    for (int r = 0; r < 4; r++) { mrow[r] = -1e30f; lrow[r] = 0.f; }

    bf16x8 stg[10];
    load_stg(0, stg);  // prologue

#pragma unroll 1
    for (int kt = 0; kt < nt; kt++) {
      VMWAIT0;
      __builtin_amdgcn_s_barrier();   // all waves done reading previous tile's LDS
      __builtin_amdgcn_sched_barrier(0);
      // ---- ds_write staged regs -> LDS ----
#pragma unroll
      for (int i = 0; i < 4; i++) {
        int eid = i * 256 + tid, key = eid >> 4, ch = eid & 15;
        *reinterpret_cast<bf16x8*>(&Kls[key][ch * 8]) = stg[i];
      }
#pragma unroll
      for (int i = 0; i < 2; i++) {
        int eid = i * 256 + tid, key = eid >> 3, ch = eid & 7;
        *reinterpret_cast<bf16x8*>(&Kls[key][128 + ch * 8]) = stg[4 + i];
      }
#pragma unroll
      for (int i = 0; i < 4; i++) {
        int eid = i * 256 + tid, v = eid >> 3, ch = eid & 7;
        *reinterpret_cast<bf16x8*>(&Vls[v][ch * 8]) = stg[6 + i];
      }
      if (kt + 1 < nt) load_stg((kt + 1) * 64, stg);  // flies during compute
      LGWAIT0;
      __builtin_amdgcn_s_barrier();   // LDS tile visible to all waves
      __builtin_amdgcn_sched_barrier(0);

      int k0 = kt * 64;
      // ---- QK^T ----
      f32x4 sacc[4] = {};
      __builtin_amdgcn_s_setprio(1);
#pragma unroll
      for (int kk = 0; kk < 6; kk++) {
#pragma unroll
        for (int ntb = 0; ntb < 4; ntb++) {
          bf16x8 bk2 = *reinterpret_cast<const bf16x8*>(&Kls[ntb * 16 + cc][kk * 32 + g * 8]);
          sacc[ntb] = __builtin_amdgcn_mfma_f32_16x16x32_bf16(aq[kk], bk2, sacc[ntb], 0, 0, 0);
        }
      }
      __builtin_amdgcn_s_setprio(0);

      bool diag = (kt == nt - 1);
      char* pbase = reinterpret_cast<char*>(&Pls[w][0]);
      float sv[4][4];
#pragma unroll
      for (int ntb = 0; ntb < 4; ntb++)
#pragma unroll
        for (int r = 0; r < 4; r++) {
          float x = sacc[ntb][r] * SCALE;
          if (diag) {
            int qr = qw0 + g * 4 + r, kc = k0 + ntb * 16 + cc;
            if (kc > qr) x = -1e30f;
          }
          sv[ntb][r] = x;
        }
      float scl[4];
#pragma unroll
      for (int r = 0; r < 4; r++) {
        float tm = fmaxf(fmaxf(sv[0][r], sv[1][r]), fmaxf(sv[2][r], sv[3][r]));
#pragma unroll
        for (int off = 1; off < 16; off <<= 1) tm = fmaxf(tm, __shfl_xor(tm, off));
        float mold = mrow[r];
        float mnew = fmaxf(mold, tm);
        float sc = __expf(mold - mnew);
        float rs = 0.f;
#pragma unroll
        for (int ntb = 0; ntb < 4; ntb++) {
          float p = __expf(sv[ntb][r] - mnew);
          sv[ntb][r] = p;
          rs += p;
        }
#pragma unroll
        for (int off = 1; off < 16; off <<= 1) rs += __shfl_xor(rs, off);
        lrow[r] = lrow[r] * sc + rs;
        mrow[r] = mnew;
        scl[r] = sc;
      }
#pragma unroll
      for (int ntb = 0; ntb < 8; ntb++)
#pragma unroll
        for (int r = 0; r < 4; r++) acc[ntb][r] *= scl[r];
      // ---- P -> LDS (swizzled), wave-local ----
#pragma unroll
      for (int ntb = 0; ntb < 4; ntb++)
#pragma unroll
        for (int r = 0; r < 4; r++) {
          int row = g * 4 + r, col = ntb * 16 + cc;
          int off2 = row * 128 + (((col >> 3) ^ (row & 7)) << 4) + ((col & 7) << 1);
          *reinterpret_cast<bf16*>(pbase + off2) = (bf16)sv[ntb][r];
        }
      LGWAIT0;
      // ---- PV ----
      __builtin_amdgcn_s_setprio(1);
#pragma unroll
      for (int kk2 = 0; kk2 < 2; kk2++) {
        int slot = (kk2 * 4 + g) ^ (cc & 7);
        bf16x8 pa = *reinterpret_cast<const bf16x8*>(pbase + cc * 128 + slot * 16);
#pragma unroll
        for (int ntb = 0; ntb < 8; ntb++) {
          bf16x8 bv2 = *reinterpret_cast<const bf16x8*>(&Vls[ntb * 16 + cc][kk2 * 32 + g * 8]);
          acc[ntb] = __builtin_amdgcn_mfma_f32_16x16x32_bf16(pa, bv2, acc[ntb], 0, 0, 0);
        }
      }
      __builtin_amdgcn_s_setprio(0);
    }

    // ---- epilogue: normalize + store ----
#pragma unroll
    for (int ntb = 0; ntb < 8; ntb++)
#pragma unroll
      for (int r = 0; r < 4; r++) {
        int qr = qw0 + g * 4 + r;
        O[(size_t)(b * S + qr) * (H * DPH) + h * DPH + ntb * 16 + cc] =
            (bf16)(acc[ntb][r] / lrow[r]);
      }
  }
}

// ---------------- host ----------------
extern "C" void kernel_launch(void* const* d_in, const int* in_sizes, int n_in,
                              void* d_out, int out_size, void* d_ws, size_t ws_size,
                              hipStream_t stream) {
  const float* inputs    = (const float*)d_in[0];
  const int*   pos_ids   = (const int*)d_in[1];
  const float* Wq_down   = (const float*)d_in[3];
  const float* q_norm_w  = (const float*)d_in[4];
  const float* Wq_up     = (const float*)d_in[5];
  const float* Wkv_down  = (const float*)d_in[6];
  const float* kv_norm_w = (const float*)d_in[7];
  const float* Wkv_up    = (const float*)d_in[8];
  const float* Wout      = (const float*)d_in[9];
  float* out = (float*)d_out;

  char* ws = (char*)d_ws;
  size_t off = 0;
  auto alloc = [&](size_t bytes) -> void* {
    void* p = ws + off;
    off += (bytes + 255) & ~(size_t)255;
    return p;
  };

  bf16*  in_bf = (bf16*)alloc((size_t)T * D * 2);
  bf16*  WdT   = (bf16*)alloc((size_t)NDN * D * 2);          // fused down-proj weights^T
  bf16*  WquT  = (bf16*)alloc((size_t)(H * QHD) * DC_Q * 2);
  bf16*  WoutT = (bf16*)alloc((size_t)D * (H * DPH) * 2);
  float* cqkv  = (float*)alloc((size_t)T * NDN * 4);         // fused down-proj output
  bf16*  cqn   = (bf16*)alloc((size_t)T * DC_Q * 2);
  bf16*  qbf   = (bf16*)alloc((size_t)T * (H * QHD) * 2);
  bf16*  kemb  = (bf16*)alloc((size_t)T * DR * 2);
  bf16*  kvb   = (bf16*)alloc((size_t)T * (H * MEG) * 2);
  bf16*  Vt    = (bf16*)alloc((size_t)B * H * DPH * S * 2);
  bf16*  abf   = (bf16*)alloc((size_t)T * (H * DPH) * 2);
  float* cos_t = (float*)alloc((size_t)S * 32 * 4);
  float* sin_t = (float*)alloc((size_t)S * 32 * 4);

  rope_table_kernel<<<S * 32 / 64, 64, 0, stream>>>(cos_t, sin_t);
  cast_bf16_kernel<<<(T * D / 4 + 255) / 256, 256, 0, stream>>>(inputs, in_bf, T * D);
  transpose_cast_kernel<<<dim3((DC_Q + 31) / 32, (D + 31) / 32), 256, 0, stream>>>(Wq_down, WdT, D, DC_Q);
  transpose_cast_kernel<<<dim3((80 + 31) / 32, (D + 31) / 32), 256, 0, stream>>>(Wkv_down, WdT + (size_t)DC_Q * D, D, 80);
  transpose_cast_kernel<<<dim3((H * QHD + 31) / 32, (DC_Q + 31) / 32), 256, 0, stream>>>(Wq_up, WquT, DC_Q, H * QHD);
  transpose_cast_kernel<<<dim3((D + 31) / 32, (H * DPH + 31) / 32), 256, 0, stream>>>(Wout, WoutT, H * DPH, D);

  gemm_bt_kernel<float><<<dim3((NDN + 127) / 128, T / 128), 256, 0, stream>>>(in_bf, WdT, cqkv, T, NDN, D);
  rmsnorm_q_kernel<<<T / 4, 256, 0, stream>>>(cqkv, q_norm_w, cqn, NDN);
  gemm_bt_kernel<bf16><<<dim3(H * QHD / 128, T / 128), 256, 0, stream>>>(cqn, WquT, qbf, T, H * QHD, DC_Q);
  kv_fused_kernel<<<T, 256, 0, stream>>>(cqkv + DC_Q, NDN, kv_norm_w, Wkv_up, pos_ids, cos_t, sin_t, kvb, kemb);
  build_vt_kernel<<<dim3(S / 64, B * H), 256, 0, stream>>>(kvb, Vt);
  attn_kernel<<<512, 256, 0, stream>>>(qbf, kvb, kemb, Vt, pos_ids, cos_t, sin_t, abf);
  gemm_bt_kernel<float><<<dim3(D / 128, T / 128), 256, 0, stream>>>(abf, WoutT, out, T, D, D);
}

// Round 4
// 377.516 us; speedup vs baseline: 2.6137x; 1.5263x over previous
//
#include <hip/hip_runtime.h>

typedef __bf16 bf16;
typedef __bf16 bf16x8 __attribute__((ext_vector_type(8)));
typedef __bf16 bf16x4 __attribute__((ext_vector_type(4)));
typedef float f32x4 __attribute__((ext_vector_type(4)));

constexpr int D = 2048, H = 16, DPH = 128, DR = 64, DC_KV = 16, DC_Q = 512;
constexpr int QHD = 192, MEG = 256, B = 2, S = 2048;
constexpr int T = B * S;
constexpr int NDNP = 640;   // fused down-proj width (512 q + 80 kv), padded to x128
constexpr int KVUK = 64;    // kv_up GEMM K (16 real + 48 zero pad)
constexpr float EPS = 1e-7f;
constexpr float SCALE = 0.07216878364870323f; // 1/sqrt(192)

static __device__ __forceinline__ bf16x8 zero8() {
  bf16x8 v;
#pragma unroll
  for (int j = 0; j < 8; j++) v[j] = (bf16)0.f;
  return v;
}

static __device__ __forceinline__ void gload_lds16(const bf16* g, bf16* l) {
  __builtin_amdgcn_global_load_lds(
      (const __attribute__((address_space(1))) unsigned int*)g,
      (__attribute__((address_space(3))) unsigned int*)l, 16, 0, 0);
}

#define VMWAIT0 do { asm volatile("s_waitcnt vmcnt(0)" ::: "memory"); __builtin_amdgcn_sched_barrier(0); } while (0)
#define LGWAIT0 do { asm volatile("s_waitcnt lgkmcnt(0)" ::: "memory"); __builtin_amdgcn_sched_barrier(0); } while (0)

// ---------------- rope table (f64 precision, once) ----------------
__global__ void rope_table_kernel(float* __restrict__ cos_t, float* __restrict__ sin_t) {
  int i = blockIdx.x * 64 + threadIdx.x;  // over S*32
  int pos = i >> 5, j = i & 31;
  double invf = pow(10000.0, -(double)(2 * j) / 64.0);
  double a = (double)pos * invf;
  cos_t[i] = (float)cos(a);
  sin_t[i] = (float)sin(a);
}

// ---------------- zero fill (bf16, n multiple of 8) ----------------
__global__ void zero_bf16_kernel(bf16* __restrict__ p, int n) {
  int i = (blockIdx.x * 256 + threadIdx.x) * 8;
  if (i < n) *reinterpret_cast<bf16x8*>(p + i) = zero8();
}

// ---------------- f32 -> bf16 cast ----------------
__global__ void cast_bf16_kernel(const float* __restrict__ in, bf16* __restrict__ out, int n) {
  int i = (blockIdx.x * blockDim.x + threadIdx.x) * 4;
  if (i < n) {
    float4 v = *reinterpret_cast<const float4*>(in + i);
    bf16x4 o;
    o[0] = (bf16)v.x; o[1] = (bf16)v.y; o[2] = (bf16)v.z; o[3] = (bf16)v.w;
    *reinterpret_cast<bf16x4*>(out + i) = o;
  }
}

// ---------------- transpose + cast: out[n][k] = (bf16) in[k][n], in is K x N f32 ----------------
__global__ __launch_bounds__(256) void transpose_cast_kernel(
    const float* __restrict__ in, bf16* __restrict__ out, int K, int N, int ldo) {
  __shared__ float tile[32][33];
  int k0 = blockIdx.y * 32, n0 = blockIdx.x * 32;
  int tid = threadIdx.x;
#pragma unroll
  for (int e = tid; e < 1024; e += 256) {
    int i = e >> 5, j = e & 31;
    int k = k0 + i, n = n0 + j;
    tile[i][j] = (k < K && n < N) ? in[(size_t)k * N + n] : 0.f;
  }
  __syncthreads();
#pragma unroll
  for (int e = tid; e < 1024; e += 256) {
    int jj = e >> 5, ii = e & 31;
    int n = n0 + jj, k = k0 + ii;
    if (k < K && n < N) out[(size_t)n * ldo + k] = (bf16)tile[ii][jj];
  }
}

// ---------------- RMSNorm over 512 dims (q path), input row stride ld ----------------
__global__ __launch_bounds__(256) void rmsnorm_q_kernel(
    const float* __restrict__ cq, const float* __restrict__ w, bf16* __restrict__ outp, int ld) {
  int wid = threadIdx.x >> 6, lane = threadIdx.x & 63;
  int t = blockIdx.x * 4 + wid;
  const float* x = cq + (size_t)t * ld;
  float4 v0 = *reinterpret_cast<const float4*>(x + lane * 8);
  float4 v1 = *reinterpret_cast<const float4*>(x + lane * 8 + 4);
  float ss = v0.x * v0.x + v0.y * v0.y + v0.z * v0.z + v0.w * v0.w +
             v1.x * v1.x + v1.y * v1.y + v1.z * v1.z + v1.w * v1.w;
#pragma unroll
  for (int off = 32; off; off >>= 1) ss += __shfl_xor(ss, off);
  float r = rsqrtf(ss / (float)DC_Q + EPS);
  const float* wp = w + lane * 8;
  float vv[8] = {v0.x, v0.y, v0.z, v0.w, v1.x, v1.y, v1.z, v1.w};
  bf16x8 o;
#pragma unroll
  for (int j = 0; j < 8; j++) o[j] = (bf16)(vv[j] * r * wp[j]);
  *reinterpret_cast<bf16x8*>(outp + (size_t)t * DC_Q + lane * 8) = o;
}

// ---------------- kv prep: rmsnorm(16) -> padded bf16 row; k_rope RoPE ----------------
__global__ __launch_bounds__(64) void kv_prep_kernel(
    const float* __restrict__ cqkv, const float* __restrict__ kvw,
    const int* __restrict__ pos_ids,
    const float* __restrict__ cos_t, const float* __restrict__ sin_t,
    bf16* __restrict__ ckv_n, bf16* __restrict__ kemb) {
  int t = blockIdx.x;
  int lane = threadIdx.x;
  const float* x = cqkv + (size_t)t * NDNP + DC_Q;
  float v = (lane < 16) ? x[lane] : 0.f;
  float ss = v * v;
#pragma unroll
  for (int off = 1; off < 16; off <<= 1) ss += __shfl_xor(ss, off);
  float r = rsqrtf(ss / 16.f + EPS);
  ckv_n[(size_t)t * KVUK + lane] = (lane < 16) ? (bf16)(v * r * kvw[lane & 15]) : (bf16)0.f;
  if (lane < 32) {
    int j = lane;
    int pos = pos_ids[t];
    float cf = cos_t[pos * 32 + j], sf = sin_t[pos * 32 + j];
    float x0 = x[16 + 2 * j], x1 = x[16 + 2 * j + 1];
    kemb[(size_t)t * DR + j]      = (bf16)(x0 * cf - x1 * sf);
    kemb[(size_t)t * DR + 32 + j] = (bf16)(x1 * cf + x0 * sf);
  }
}

// ---------------- build V^T (B*H, 128, S) ----------------
__global__ __launch_bounds__(256) void build_vt_kernel(
    const bf16* __restrict__ kvb, bf16* __restrict__ Vt) {
  __shared__ bf16 tile[128][72];
  int bh = blockIdx.y;
  int b = bh >> 4, h = bh & 15;
  int s0 = blockIdx.x * 64;
  int tid = threadIdx.x;
#pragma unroll
  for (int e = tid; e < 8192; e += 256) {
    int si = e >> 7, v = e & 127;
    tile[v][si] = kvb[(size_t)(b * S + s0 + si) * (H * MEG) + h * MEG + 128 + v];
  }
  __syncthreads();
#pragma unroll
  for (int e = tid; e < 8192; e += 256) {
    int v = e >> 6, si = e & 63;
    Vt[((size_t)bh * 128 + v) * S + s0 + si] = tile[v][si];
  }
}

// ---------------- bf16 MFMA GEMM: C(MxN) = A(MxK) * Bt(NxK)^T ----------------
// Full tiles only: M, N multiples of 128, K multiple of 64.
// Staging: global_load_lds width-16, linear LDS dest + pre-swizzled global source (rule #21).
template <typename OutT>
__global__ __launch_bounds__(256) void gemm_bt_kernel(
    const bf16* __restrict__ A, const bf16* __restrict__ Bt,
    OutT* __restrict__ C, int M, int N, int K) {
  __shared__ bf16 As[128 * 64];
  __shared__ bf16 Bs[128 * 64];
  int tid = threadIdx.x;
  int wid = tid >> 6, lane = tid & 63;
  int g = lane >> 4, c = lane & 15;
  int wr = wid >> 1, wc = wid & 1;
  int m0 = blockIdx.y * 128, n0 = blockIdx.x * 128;
  int lrow8 = lane >> 3, lslot = lane & 7;

  f32x4 acc[4][4] = {};
  int nk = K >> 6;
  for (int kt = 0; kt < nk; kt++) {
    int k0 = kt << 6;
    __syncthreads();
#pragma unroll
    for (int r = 0; r < 4; r++) {
      int row = (r * 4 + wid) * 8 + lrow8;
      int sslot = lslot ^ (row & 7);
      gload_lds16(A + (size_t)(m0 + row) * K + k0 + sslot * 8, As + row * 64 + lslot * 8);
      gload_lds16(Bt + (size_t)(n0 + row) * K + k0 + sslot * 8, Bs + row * 64 + lslot * 8);
    }
    __syncthreads();
#pragma unroll
    for (int kk = 0; kk < 2; kk++) {
      bf16x8 af[4], bfr[4];
#pragma unroll
      for (int mi = 0; mi < 4; mi++) {
        int row = wr * 64 + mi * 16 + c;
        int sl = (kk * 4 + g) ^ (row & 7);
        af[mi] = *reinterpret_cast<const bf16x8*>(As + row * 64 + sl * 8);
      }
#pragma unroll
      for (int ni = 0; ni < 4; ni++) {
        int row = wc * 64 + ni * 16 + c;
        int sl = (kk * 4 + g) ^ (row & 7);
        bfr[ni] = *reinterpret_cast<const bf16x8*>(Bs + row * 64 + sl * 8);
      }
#pragma unroll
      for (int mi = 0; mi < 4; mi++)
#pragma unroll
        for (int ni = 0; ni < 4; ni++)
          acc[mi][ni] = __builtin_amdgcn_mfma_f32_16x16x32_bf16(af[mi], bfr[ni], acc[mi][ni], 0, 0, 0);
    }
  }
#pragma unroll
  for (int mi = 0; mi < 4; mi++)
#pragma unroll
    for (int ni = 0; ni < 4; ni++)
#pragma unroll
      for (int r = 0; r < 4; r++) {
        int row = m0 + wr * 64 + mi * 16 + g * 4 + r;
        int col = n0 + wc * 64 + ni * 16 + c;
        C[(size_t)row * N + col] = (OutT)acc[mi][ni][r];
      }
}

// ---------------- flash attention: 4 waves, Q-tile 128 (32/wave, 2 m-frags), KV tile 64 ----------------
// T14 reg-staged pipeline; LDS as 16B entries with odd slot stride (65 / 129)
// -> every 16-lane read/write quarter spreads over all 8 bank groups (2-way = free).
__global__ __launch_bounds__(256, 2) void attn_kernel(
    const bf16* __restrict__ qbf, const bf16* __restrict__ kvb,
    const bf16* __restrict__ kemb, const bf16* __restrict__ Vt,
    const int* __restrict__ pos_ids,
    const float* __restrict__ cos_t, const float* __restrict__ sin_t,
    bf16* __restrict__ O) {
  __shared__ bf16 Kls[24 * 65 * 8];  // entry (s,key) at (s*65+key)*8, s<16: kvb cols s*8.., s>=16: kemb
  __shared__ bf16 Vls[8 * 129 * 8];  // entry (s,v) at (s*129+v)*8: keys s*8..s*8+7 of dim v
  __shared__ bf16 Pls[4][2048];      // per-wave 32x64 P staging (swizzled)

  int lin = blockIdx.x;              // 0..511
  int bh = lin & 31;                 // 4 bh per XCD
  int qi = 15 - (lin >> 5);          // heavy q-tiles dispatched first
  int b = bh >> 4, h = bh & 15;
  int q0 = qi * 128;
  int tid = threadIdx.x;
  int w = tid >> 6, lane = tid & 63;
  int g = lane >> 4, cc = lane & 15;
  int qw0 = q0 + w * 32;
  int nt = 2 * (qi + 1);

  auto load_stg = [&](int k0, bf16x8* stg) {
    const bf16* bk = kvb + (size_t)(b * S + k0) * (H * MEG) + h * MEG;
#pragma unroll
    for (int i = 0; i < 4; i++) {
      int key = i * 16 + (tid >> 4), ch = tid & 15;
      stg[i] = *reinterpret_cast<const bf16x8*>(bk + (size_t)key * (H * MEG) + ch * 8);
    }
    const bf16* be = kemb + (size_t)(b * S + k0) * DR;
#pragma unroll
    for (int i = 0; i < 2; i++) {
      int key = i * 32 + (tid >> 3), ch = tid & 7;
      stg[4 + i] = *reinterpret_cast<const bf16x8*>(be + (size_t)key * DR + ch * 8);
    }
    const bf16* bv = Vt + (size_t)bh * DPH * S + k0;
#pragma unroll
    for (int i = 0; i < 4; i++) {
      int v = i * 32 + (tid >> 3), ch = tid & 7;
      stg[6 + i] = *reinterpret_cast<const bf16x8*>(bv + (size_t)v * S + ch * 8);
    }
  };

  // ---- Q fragments (RoPE folded), registers ----
  bf16x8 aq[2][6];
#pragma unroll
  for (int m = 0; m < 2; m++) {
    int qrow = qw0 + m * 16 + cc;
    const bf16* qp = qbf + (size_t)(b * S + qrow) * (H * QHD) + h * QHD;
#pragma unroll
    for (int kk = 0; kk < 4; kk++)
      aq[m][kk] = *reinterpret_cast<const bf16x8*>(qp + kk * 32 + g * 8);
    int pos = pos_ids[b * S + qrow];
    float4 c0 = *reinterpret_cast<const float4*>(cos_t + pos * 32 + g * 8);
    float4 c1 = *reinterpret_cast<const float4*>(cos_t + pos * 32 + g * 8 + 4);
    float4 s0 = *reinterpret_cast<const float4*>(sin_t + pos * 32 + g * 8);
    float4 s1 = *reinterpret_cast<const float4*>(sin_t + pos * 32 + g * 8 + 4);
    bf16x8 x01 = *reinterpret_cast<const bf16x8*>(qp + 128 + g * 16);
    bf16x8 x23 = *reinterpret_cast<const bf16x8*>(qp + 128 + g * 16 + 8);
    float cf[8] = {c0.x, c0.y, c0.z, c0.w, c1.x, c1.y, c1.z, c1.w};
    float sf[8] = {s0.x, s0.y, s0.z, s0.w, s1.x, s1.y, s1.z, s1.w};
    float x0v[8], x1v[8];
#pragma unroll
    for (int j = 0; j < 4; j++) { x0v[j] = (float)x01[2 * j]; x1v[j] = (float)x01[2 * j + 1]; }
#pragma unroll
    for (int j = 0; j < 4; j++) { x0v[4 + j] = (float)x23[2 * j]; x1v[4 + j] = (float)x23[2 * j + 1]; }
#pragma unroll
    for (int j = 0; j < 8; j++) {
      aq[m][4][j] = (bf16)(x0v[j] * cf[j] - x1v[j] * sf[j]);
      aq[m][5][j] = (bf16)(x1v[j] * cf[j] + x0v[j] * sf[j]);
    }
  }

  float mrow[2][4], lrow[2][4];
  f32x4 acc[2][8] = {};
#pragma unroll
  for (int m = 0; m < 2; m++)
#pragma unroll
    for (int r = 0; r < 4; r++) { mrow[m][r] = -1e30f; lrow[m][r] = 0.f; }

  bf16x8 stg[10];
  load_stg(0, stg);  // prologue
  char* pbase = reinterpret_cast<char*>(&Pls[w][0]);

#pragma unroll 1
  for (int kt = 0; kt < nt; kt++) {
    VMWAIT0;
    __builtin_amdgcn_s_barrier();   // all waves done reading previous tile's LDS
    __builtin_amdgcn_sched_barrier(0);
    // ---- ds_write staged regs -> LDS (entry layouts, quarter-wave spread over 8 bank groups) ----
#pragma unroll
    for (int i = 0; i < 4; i++) {
      int key = i * 16 + (tid >> 4), ch = tid & 15;
      *reinterpret_cast<bf16x8*>(&Kls[(ch * 65 + key) * 8]) = stg[i];
    }
#pragma unroll
    for (int i = 0; i < 2; i++) {
      int key = i * 32 + (tid >> 3), ch = tid & 7;
      *reinterpret_cast<bf16x8*>(&Kls[((16 + ch) * 65 + key) * 8]) = stg[4 + i];
    }
#pragma unroll
    for (int i = 0; i < 4; i++) {
      int v = i * 32 + (tid >> 3), ch = tid & 7;
      *reinterpret_cast<bf16x8*>(&Vls[(ch * 129 + v) * 8]) = stg[6 + i];
    }
    if (kt + 1 < nt) load_stg((kt + 1) * 64, stg);  // flies during compute (T14)
    LGWAIT0;
    __builtin_amdgcn_s_barrier();   // LDS tile visible to all waves
    __builtin_amdgcn_sched_barrier(0);

    int k0 = kt * 64;
    if (k0 > qw0 + 31) continue;    // fully masked for this wave (barriers stay aligned)

    // ---- QK^T: each K fragment feeds both m-frags ----
    f32x4 sacc[2][4] = {};
    __builtin_amdgcn_s_setprio(1);
#pragma unroll
    for (int kk = 0; kk < 6; kk++) {
#pragma unroll
      for (int ntb = 0; ntb < 4; ntb++) {
        bf16x8 bk2 = *reinterpret_cast<const bf16x8*>(&Kls[((kk * 4 + g) * 65 + ntb * 16 + cc) * 8]);
        sacc[0][ntb] = __builtin_amdgcn_mfma_f32_16x16x32_bf16(aq[0][kk], bk2, sacc[0][ntb], 0, 0, 0);
        sacc[1][ntb] = __builtin_amdgcn_mfma_f32_16x16x32_bf16(aq[1][kk], bk2, sacc[1][ntb], 0, 0, 0);
      }
    }
    __builtin_amdgcn_s_setprio(0);

    // ---- softmax per m-frag; P staged to LDS rows m*16.. ----
#pragma unroll
    for (int m = 0; m < 2; m++) {
      bool diag = (k0 + 63 > qw0 + m * 16);
      float sv[4][4];
#pragma unroll
      for (int ntb = 0; ntb < 4; ntb++)
#pragma unroll
        for (int r = 0; r < 4; r++) {
          float x = sacc[m][ntb][r] * SCALE;
          if (diag) {
            int qr = qw0 + m * 16 + g * 4 + r, kc = k0 + ntb * 16 + cc;
            if (kc > qr) x = -1e30f;
          }
          sv[ntb][r] = x;
        }
      float scl[4];
#pragma unroll
      for (int r = 0; r < 4; r++) {
        float tm = fmaxf(fmaxf(sv[0][r], sv[1][r]), fmaxf(sv[2][r], sv[3][r]));
#pragma unroll
        for (int off = 1; off < 16; off <<= 1) tm = fmaxf(tm, __shfl_xor(tm, off));
        float mold = mrow[m][r];
        float mnew = fmaxf(mold, tm);
        float sc = __expf(mold - mnew);
        float rs = 0.f;
#pragma unroll
        for (int ntb = 0; ntb < 4; ntb++) {
          float p = __expf(sv[ntb][r] - mnew);
          sv[ntb][r] = p;
          rs += p;
        }
#pragma unroll
        for (int off = 1; off < 16; off <<= 1) rs += __shfl_xor(rs, off);
        lrow[m][r] = lrow[m][r] * sc + rs;
        mrow[m][r] = mnew;
        scl[r] = sc;
      }
#pragma unroll
      for (int ntb = 0; ntb < 8; ntb++)
#pragma unroll
        for (int r = 0; r < 4; r++) acc[m][ntb][r] *= scl[r];
#pragma unroll
      for (int ntb = 0; ntb < 4; ntb++)
#pragma unroll
        for (int r = 0; r < 4; r++) {
          int row = m * 16 + g * 4 + r, col = ntb * 16 + cc;
          int off2 = row * 128 + (((col >> 3) ^ (row & 7)) << 4) + ((col & 7) << 1);
          *reinterpret_cast<bf16*>(pbase + off2) = (bf16)sv[ntb][r];
        }
    }
    LGWAIT0;
    // ---- PV: each V fragment feeds both m-frags ----
    __builtin_amdgcn_s_setprio(1);
#pragma unroll
    for (int kk2 = 0; kk2 < 2; kk2++) {
      bf16x8 pa[2];
#pragma unroll
      for (int m = 0; m < 2; m++) {
        int row = m * 16 + cc;
        int slot = (kk2 * 4 + g) ^ (cc & 7);
        pa[m] = *reinterpret_cast<const bf16x8*>(pbase + row * 128 + slot * 16);
      }
#pragma unroll
      for (int ntb = 0; ntb < 8; ntb++) {
        bf16x8 bv2 = *reinterpret_cast<const bf16x8*>(&Vls[((kk2 * 4 + g) * 129 + ntb * 16 + cc) * 8]);
        acc[0][ntb] = __builtin_amdgcn_mfma_f32_16x16x32_bf16(pa[0], bv2, acc[0][ntb], 0, 0, 0);
        acc[1][ntb] = __builtin_amdgcn_mfma_f32_16x16x32_bf16(pa[1], bv2, acc[1][ntb], 0, 0, 0);
      }
    }
    __builtin_amdgcn_s_setprio(0);
  }

  // ---- epilogue: normalize + store ----
#pragma unroll
  for (int m = 0; m < 2; m++)
#pragma unroll
    for (int ntb = 0; ntb < 8; ntb++)
#pragma unroll
      for (int r = 0; r < 4; r++) {
        int qr = qw0 + m * 16 + g * 4 + r;
        O[(size_t)(b * S + qr) * (H * DPH) + h * DPH + ntb * 16 + cc] =
            (bf16)(acc[m][ntb][r] / lrow[m][r]);
      }
}

// ---------------- host ----------------
extern "C" void kernel_launch(void* const* d_in, const int* in_sizes, int n_in,
                              void* d_out, int out_size, void* d_ws, size_t ws_size,
                              hipStream_t stream) {
  const float* inputs    = (const float*)d_in[0];
  const int*   pos_ids   = (const int*)d_in[1];
  const float* Wq_down   = (const float*)d_in[3];
  const float* q_norm_w  = (const float*)d_in[4];
  const float* Wq_up     = (const float*)d_in[5];
  const float* Wkv_down  = (const float*)d_in[6];
  const float* kv_norm_w = (const float*)d_in[7];
  const float* Wkv_up    = (const float*)d_in[8];
  const float* Wout      = (const float*)d_in[9];
  float* out = (float*)d_out;

  char* ws = (char*)d_ws;
  size_t off = 0;
  auto alloc = [&](size_t bytes) -> void* {
    void* p = ws + off;
    off += (bytes + 255) & ~(size_t)255;
    return p;
  };

  bf16*  in_bf = (bf16*)alloc((size_t)T * D * 2);
  bf16*  WdT   = (bf16*)alloc((size_t)NDNP * D * 2);         // fused down-proj weights^T (rows 592.. zero)
  bf16*  WquT  = (bf16*)alloc((size_t)(H * QHD) * DC_Q * 2);
  bf16*  WkvuT = (bf16*)alloc((size_t)(H * MEG) * KVUK * 2); // kv_up weights^T, K-padded with zeros
  bf16*  WoutT = (bf16*)alloc((size_t)D * (H * DPH) * 2);
  float* cqkv  = (float*)alloc((size_t)T * NDNP * 4);        // fused down-proj output
  bf16*  cqn   = (bf16*)alloc((size_t)T * DC_Q * 2);
  bf16*  ckvn  = (bf16*)alloc((size_t)T * KVUK * 2);         // normalized c_kv, K-padded
  bf16*  qbf   = (bf16*)alloc((size_t)T * (H * QHD) * 2);
  bf16*  kemb  = (bf16*)alloc((size_t)T * DR * 2);
  bf16*  kvb   = (bf16*)alloc((size_t)T * (H * MEG) * 2);
  bf16*  Vt    = (bf16*)alloc((size_t)B * H * DPH * S * 2);
  bf16*  abf   = (bf16*)alloc((size_t)T * (H * DPH) * 2);
  float* cos_t = (float*)alloc((size_t)S * 32 * 4);
  float* sin_t = (float*)alloc((size_t)S * 32 * 4);

  rope_table_kernel<<<S * 32 / 64, 64, 0, stream>>>(cos_t, sin_t);
  cast_bf16_kernel<<<(T * D / 4 + 255) / 256, 256, 0, stream>>>(inputs, in_bf, T * D);
  zero_bf16_kernel<<<(NDNP * D / 8 + 255) / 256, 256, 0, stream>>>(WdT, NDNP * D);
  zero_bf16_kernel<<<(H * MEG * KVUK / 8 + 255) / 256, 256, 0, stream>>>(WkvuT, H * MEG * KVUK);
  transpose_cast_kernel<<<dim3((DC_Q + 31) / 32, (D + 31) / 32), 256, 0, stream>>>(Wq_down, WdT, D, DC_Q, D);
  transpose_cast_kernel<<<dim3((80 + 31) / 32, (D + 31) / 32), 256, 0, stream>>>(Wkv_down, WdT + (size_t)DC_Q * D, D, 80, D);
  transpose_cast_kernel<<<dim3((H * QHD + 31) / 32, (DC_Q + 31) / 32), 256, 0, stream>>>(Wq_up, WquT, DC_Q, H * QHD, DC_Q);
  transpose_cast_kernel<<<dim3((H * MEG + 31) / 32, 1), 256, 0, stream>>>(Wkv_up, WkvuT, DC_KV, H * MEG, KVUK);
  transpose_cast_kernel<<<dim3((D + 31) / 32, (H * DPH + 31) / 32), 256, 0, stream>>>(Wout, WoutT, H * DPH, D, H * DPH);

  gemm_bt_kernel<float><<<dim3(NDNP / 128, T / 128), 256, 0, stream>>>(in_bf, WdT, cqkv, T, NDNP, D);
  rmsnorm_q_kernel<<<T / 4, 256, 0, stream>>>(cqkv, q_norm_w, cqn, NDNP);
  kv_prep_kernel<<<T, 64, 0, stream>>>(cqkv, kv_norm_w, pos_ids, cos_t, sin_t, ckvn, kemb);
  gemm_bt_kernel<bf16><<<dim3(H * QHD / 128, T / 128), 256, 0, stream>>>(cqn, WquT, qbf, T, H * QHD, DC_Q);
  gemm_bt_kernel<bf16><<<dim3(H * MEG / 128, T / 128), 256, 0, stream>>>(ckvn, WkvuT, kvb, T, H * MEG, KVUK);
  build_vt_kernel<<<dim3(S / 64, B * H), 256, 0, stream>>>(kvb, Vt);
  attn_kernel<<<512, 256, 0, stream>>>(qbf, kvb, kemb, Vt, pos_ids, cos_t, sin_t, abf);
  gemm_bt_kernel<float><<<dim3(D / 128, T / 128), 256, 0, stream>>>(abf, WoutT, out, T, D, D);
}

// Round 5
// 367.902 us; speedup vs baseline: 2.6820x; 1.0261x over previous
//
#include <hip/hip_runtime.h>

typedef __bf16 bf16;
typedef __bf16 bf16x8 __attribute__((ext_vector_type(8)));
typedef __bf16 bf16x4 __attribute__((ext_vector_type(4)));
typedef float f32x4 __attribute__((ext_vector_type(4)));

constexpr int D = 2048, H = 16, DPH = 128, DR = 64, DC_KV = 16, DC_Q = 512;
constexpr int QHD = 192, MEG = 256, B = 2, S = 2048;
constexpr int T = B * S;
constexpr int NDNP = 640;   // fused down-proj width (512 q + 80 kv), padded to x128
constexpr int KVUK = 64;    // kv_up GEMM K (16 real + 48 zero pad)
constexpr float EPS = 1e-7f;
constexpr float SCALE = 0.07216878364870323f; // 1/sqrt(192)

static __device__ __forceinline__ bf16x8 zero8() {
  bf16x8 v;
#pragma unroll
  for (int j = 0; j < 8; j++) v[j] = (bf16)0.f;
  return v;
}

static __device__ __forceinline__ void gload_lds16(const bf16* g, bf16* l) {
  __builtin_amdgcn_global_load_lds(
      (const __attribute__((address_space(1))) unsigned int*)g,
      (__attribute__((address_space(3))) unsigned int*)l, 16, 0, 0);
}

#define LGWAIT0 do { asm volatile("s_waitcnt lgkmcnt(0)" ::: "memory"); __builtin_amdgcn_sched_barrier(0); } while (0)

// ---------------- rope table (f64 precision, once) ----------------
__global__ void rope_table_kernel(float* __restrict__ cos_t, float* __restrict__ sin_t) {
  int i = blockIdx.x * 64 + threadIdx.x;  // over S*32
  int pos = i >> 5, j = i & 31;
  double invf = pow(10000.0, -(double)(2 * j) / 64.0);
  double a = (double)pos * invf;
  cos_t[i] = (float)cos(a);
  sin_t[i] = (float)sin(a);
}

// ---------------- zero fill (bf16, n multiple of 8) ----------------
__global__ void zero_bf16_kernel(bf16* __restrict__ p, int n) {
  int i = (blockIdx.x * 256 + threadIdx.x) * 8;
  if (i < n) *reinterpret_cast<bf16x8*>(p + i) = zero8();
}

// ---------------- f32 -> bf16 cast ----------------
__global__ void cast_bf16_kernel(const float* __restrict__ in, bf16* __restrict__ out, int n) {
  int i = (blockIdx.x * blockDim.x + threadIdx.x) * 4;
  if (i < n) {
    float4 v = *reinterpret_cast<const float4*>(in + i);
    bf16x4 o;
    o[0] = (bf16)v.x; o[1] = (bf16)v.y; o[2] = (bf16)v.z; o[3] = (bf16)v.w;
    *reinterpret_cast<bf16x4*>(out + i) = o;
  }
}

// ---------------- transpose + cast: out[n][k] = (bf16) in[k][n], in is K x N f32 ----------------
__global__ __launch_bounds__(256) void transpose_cast_kernel(
    const float* __restrict__ in, bf16* __restrict__ out, int K, int N, int ldo) {
  __shared__ float tile[32][33];
  int k0 = blockIdx.y * 32, n0 = blockIdx.x * 32;
  int tid = threadIdx.x;
#pragma unroll
  for (int e = tid; e < 1024; e += 256) {
    int i = e >> 5, j = e & 31;
    int k = k0 + i, n = n0 + j;
    tile[i][j] = (k < K && n < N) ? in[(size_t)k * N + n] : 0.f;
  }
  __syncthreads();
#pragma unroll
  for (int e = tid; e < 1024; e += 256) {
    int jj = e >> 5, ii = e & 31;
    int n = n0 + jj, k = k0 + ii;
    if (k < K && n < N) out[(size_t)n * ldo + k] = (bf16)tile[ii][jj];
  }
}

// ---------------- RMSNorm over 512 dims (q path), input row stride ld ----------------
__global__ __launch_bounds__(256) void rmsnorm_q_kernel(
    const float* __restrict__ cq, const float* __restrict__ w, bf16* __restrict__ outp, int ld) {
  int wid = threadIdx.x >> 6, lane = threadIdx.x & 63;
  int t = blockIdx.x * 4 + wid;
  const float* x = cq + (size_t)t * ld;
  float4 v0 = *reinterpret_cast<const float4*>(x + lane * 8);
  float4 v1 = *reinterpret_cast<const float4*>(x + lane * 8 + 4);
  float ss = v0.x * v0.x + v0.y * v0.y + v0.z * v0.z + v0.w * v0.w +
             v1.x * v1.x + v1.y * v1.y + v1.z * v1.z + v1.w * v1.w;
#pragma unroll
  for (int off = 32; off; off >>= 1) ss += __shfl_xor(ss, off);
  float r = rsqrtf(ss / (float)DC_Q + EPS);
  const float* wp = w + lane * 8;
  float vv[8] = {v0.x, v0.y, v0.z, v0.w, v1.x, v1.y, v1.z, v1.w};
  bf16x8 o;
#pragma unroll
  for (int j = 0; j < 8; j++) o[j] = (bf16)(vv[j] * r * wp[j]);
  *reinterpret_cast<bf16x8*>(outp + (size_t)t * DC_Q + lane * 8) = o;
}

// ---------------- kv prep: rmsnorm(16) -> padded bf16 row; k_rope RoPE ----------------
__global__ __launch_bounds__(64) void kv_prep_kernel(
    const float* __restrict__ cqkv, const float* __restrict__ kvw,
    const int* __restrict__ pos_ids,
    const float* __restrict__ cos_t, const float* __restrict__ sin_t,
    bf16* __restrict__ ckv_n, bf16* __restrict__ kemb) {
  int t = blockIdx.x;
  int lane = threadIdx.x;
  const float* x = cqkv + (size_t)t * NDNP + DC_Q;
  float v = (lane < 16) ? x[lane] : 0.f;
  float ss = v * v;
#pragma unroll
  for (int off = 1; off < 16; off <<= 1) ss += __shfl_xor(ss, off);
  float r = rsqrtf(ss / 16.f + EPS);
  ckv_n[(size_t)t * KVUK + lane] = (lane < 16) ? (bf16)(v * r * kvw[lane & 15]) : (bf16)0.f;
  if (lane < 32) {
    int j = lane;
    int pos = pos_ids[t];
    float cf = cos_t[pos * 32 + j], sf = sin_t[pos * 32 + j];
    float x0 = x[16 + 2 * j], x1 = x[16 + 2 * j + 1];
    kemb[(size_t)t * DR + j]      = (bf16)(x0 * cf - x1 * sf);
    kemb[(size_t)t * DR + 32 + j] = (bf16)(x1 * cf + x0 * sf);
  }
}

// ---------------- build V^T (B*H, 128, S) ----------------
__global__ __launch_bounds__(256) void build_vt_kernel(
    const bf16* __restrict__ kvb, bf16* __restrict__ Vt) {
  __shared__ bf16 tile[128][72];
  int bh = blockIdx.y;
  int b = bh >> 4, h = bh & 15;
  int s0 = blockIdx.x * 64;
  int tid = threadIdx.x;
#pragma unroll
  for (int e = tid; e < 8192; e += 256) {
    int si = e >> 7, v = e & 127;
    tile[v][si] = kvb[(size_t)(b * S + s0 + si) * (H * MEG) + h * MEG + 128 + v];
  }
  __syncthreads();
#pragma unroll
  for (int e = tid; e < 8192; e += 256) {
    int v = e >> 6, si = e & 63;
    Vt[((size_t)bh * 128 + v) * S + s0 + si] = tile[v][si];
  }
}

// ---------------- bf16 MFMA GEMM: C(MxN) = A(MxK) * Bt(NxK)^T ----------------
// Full tiles only: M, N multiples of 128, K multiple of 64. XCD-swizzled block map.
template <typename OutT>
__global__ __launch_bounds__(256) void gemm_bt_kernel(
    const bf16* __restrict__ A, const bf16* __restrict__ Bt,
    OutT* __restrict__ C, int M, int N, int K) {
  __shared__ bf16 As[128 * 64];
  __shared__ bf16 Bs[128 * 64];
  int tid = threadIdx.x;
  int wid = tid >> 6, lane = tid & 63;
  int g = lane >> 4, c = lane & 15;
  int wr = wid >> 1, wc = wid & 1;
  // XCD-aware bijective swizzle (all grids here have nwg % 8 == 0)
  int nbx = gridDim.x;
  int lin = blockIdx.y * nbx + blockIdx.x;
  int cpx = (nbx * gridDim.y) >> 3;
  int swz = (lin & 7) * cpx + (lin >> 3);
  int m0 = (swz / nbx) * 128, n0 = (swz % nbx) * 128;
  int lrow8 = lane >> 3, lslot = lane & 7;

  f32x4 acc[4][4] = {};
  int nk = K >> 6;
  for (int kt = 0; kt < nk; kt++) {
    int k0 = kt << 6;
    __syncthreads();
#pragma unroll
    for (int r = 0; r < 4; r++) {
      int row = (r * 4 + wid) * 8 + lrow8;
      int sslot = lslot ^ (row & 7);
      gload_lds16(A + (size_t)(m0 + row) * K + k0 + sslot * 8, As + row * 64 + lslot * 8);
      gload_lds16(Bt + (size_t)(n0 + row) * K + k0 + sslot * 8, Bs + row * 64 + lslot * 8);
    }
    __syncthreads();
#pragma unroll
    for (int kk = 0; kk < 2; kk++) {
      bf16x8 af[4], bfr[4];
#pragma unroll
      for (int mi = 0; mi < 4; mi++) {
        int row = wr * 64 + mi * 16 + c;
        int sl = (kk * 4 + g) ^ (row & 7);
        af[mi] = *reinterpret_cast<const bf16x8*>(As + row * 64 + sl * 8);
      }
#pragma unroll
      for (int ni = 0; ni < 4; ni++) {
        int row = wc * 64 + ni * 16 + c;
        int sl = (kk * 4 + g) ^ (row & 7);
        bfr[ni] = *reinterpret_cast<const bf16x8*>(Bs + row * 64 + sl * 8);
      }
#pragma unroll
      for (int mi = 0; mi < 4; mi++)
#pragma unroll
        for (int ni = 0; ni < 4; ni++)
          acc[mi][ni] = __builtin_amdgcn_mfma_f32_16x16x32_bf16(af[mi], bfr[ni], acc[mi][ni], 0, 0, 0);
    }
  }
#pragma unroll
  for (int mi = 0; mi < 4; mi++)
#pragma unroll
    for (int ni = 0; ni < 4; ni++)
#pragma unroll
      for (int r = 0; r < 4; r++) {
        int row = m0 + wr * 64 + mi * 16 + g * 4 + r;
        int col = n0 + wc * 64 + ni * 16 + c;
        C[(size_t)row * N + col] = (OutT)acc[mi][ni][r];
      }
}

// ---------------- flash attention: paired causal q-tiles, LDS double-buffer ----------------
// 256 blocks = 32 bh x 8 pairs; block does q-tiles (qi, 15-qi) of 128 rows -> exactly 34
// k-tiles per block, 1 block/CU (97 KB LDS) => perfect static balance.
// Per tile: issue 10 global_load_lds (t+1 -> buf^1); vmcnt(10); barrier; compute buf; barrier.
__global__ __launch_bounds__(256, 1) void attn_kernel(
    const bf16* __restrict__ qbf, const bf16* __restrict__ kvb,
    const bf16* __restrict__ kemb, const bf16* __restrict__ Vt,
    const int* __restrict__ pos_ids,
    const float* __restrict__ cos_t, const float* __restrict__ sin_t,
    bf16* __restrict__ O) {
  __shared__ bf16 Kls[2][24 * 65 * 8];  // entry (s,key) at (s*65+key)*8; s<16: kvb cols, s>=16: kemb
  __shared__ bf16 Vls[2][8 * 129 * 8];  // entry (s,v) at (s*129+v)*8: keys s*8..s*8+7 of dim v
  __shared__ bf16 Pls[4][2048];         // per-wave 32x64 P staging (swizzled)

  int lin = blockIdx.x;              // 0..255
  int bh = lin & 31;                 // 4 bh per XCD
  int pr = lin >> 5;                 // pair index 0..7
  int b = bh >> 4, h = bh & 15;
  int tid = threadIdx.x;
  int w = tid >> 6, lane = tid & 63;
  int g = lane >> 4, cc = lane & 15;
  char* pbase = reinterpret_cast<char*>(&Pls[w][0]);

  // stage one 64-key tile: 10 global_load_lds per wave, linear 1KB LDS runs (rule #21 safe)
  auto stage = [&](int k0, int buf) {
    const bf16* bk = kvb + (size_t)(b * S + k0 + lane) * (H * MEG) + h * MEG;
    const bf16* be = kemb + (size_t)(b * S + k0 + lane) * DR;
#pragma unroll
    for (int i = 0; i < 6; i++) {
      int s = w * 6 + i;
      const bf16* src = (s < 16) ? (bk + s * 8) : (be + (s - 16) * 8);
      gload_lds16(src, &Kls[buf][s * 65 * 8]);
    }
#pragma unroll
    for (int i = 0; i < 4; i++) {
      int s = w * 2 + (i >> 1), hf = i & 1;
      const bf16* src = Vt + ((size_t)bh * DPH + hf * 64 + lane) * S + k0 + s * 8;
      gload_lds16(src, &Vls[buf][(s * 129 + hf * 64) * 8]);
    }
  };

#pragma unroll 1
  for (int ph = 0; ph < 2; ph++) {
    int qi = ph ? (15 - pr) : pr;
    int q0 = qi * 128;
    int qw0 = q0 + w * 32;
    int nt = 2 * qi + 2;

    __syncthreads();   // prior phase's LDS reads + stores drained (full waitcnt via syncthreads)
    stage(0, 0);       // prologue loads fly under Q setup

    // ---- Q fragments (RoPE folded), registers ----
    bf16x8 aq[2][6];
#pragma unroll
    for (int m = 0; m < 2; m++) {
      int qrow = qw0 + m * 16 + cc;
      const bf16* qp = qbf + (size_t)(b * S + qrow) * (H * QHD) + h * QHD;
#pragma unroll
      for (int kk = 0; kk < 4; kk++)
        aq[m][kk] = *reinterpret_cast<const bf16x8*>(qp + kk * 32 + g * 8);
      int pos = pos_ids[b * S + qrow];
      float4 c0 = *reinterpret_cast<const float4*>(cos_t + pos * 32 + g * 8);
      float4 c1 = *reinterpret_cast<const float4*>(cos_t + pos * 32 + g * 8 + 4);
      float4 s0 = *reinterpret_cast<const float4*>(sin_t + pos * 32 + g * 8);
      float4 s1 = *reinterpret_cast<const float4*>(sin_t + pos * 32 + g * 8 + 4);
      bf16x8 x01 = *reinterpret_cast<const bf16x8*>(qp + 128 + g * 16);
      bf16x8 x23 = *reinterpret_cast<const bf16x8*>(qp + 128 + g * 16 + 8);
      float cf[8] = {c0.x, c0.y, c0.z, c0.w, c1.x, c1.y, c1.z, c1.w};
      float sf[8] = {s0.x, s0.y, s0.z, s0.w, s1.x, s1.y, s1.z, s1.w};
      float x0v[8], x1v[8];
#pragma unroll
      for (int j = 0; j < 4; j++) { x0v[j] = (float)x01[2 * j]; x1v[j] = (float)x01[2 * j + 1]; }
#pragma unroll
      for (int j = 0; j < 4; j++) { x0v[4 + j] = (float)x23[2 * j]; x1v[4 + j] = (float)x23[2 * j + 1]; }
#pragma unroll
      for (int j = 0; j < 8; j++) {
        aq[m][4][j] = (bf16)(x0v[j] * cf[j] - x1v[j] * sf[j]);
        aq[m][5][j] = (bf16)(x1v[j] * cf[j] + x0v[j] * sf[j]);
      }
    }

    float mrow[2][4], lrow[2][4];
    f32x4 acc[2][8] = {};
#pragma unroll
    for (int m = 0; m < 2; m++)
#pragma unroll
      for (int r = 0; r < 4; r++) { mrow[m][r] = -1e30f; lrow[m][r] = 0.f; }

#pragma unroll 1
    for (int kt = 0; kt < nt; kt++) {
      int cur = kt & 1;
      __builtin_amdgcn_s_barrier();   // A: all waves done reading buf[cur^1] -> safe to overwrite
      __builtin_amdgcn_sched_barrier(0);
      if (kt + 1 < nt) {
        stage((kt + 1) * 64, cur ^ 1);
        asm volatile("s_waitcnt vmcnt(10)" ::: "memory");  // tile kt's loads (and older) landed
      } else {
        asm volatile("s_waitcnt vmcnt(0)" ::: "memory");
      }
      __builtin_amdgcn_sched_barrier(0);
      __builtin_amdgcn_s_barrier();   // B: buf[cur] fully staged by all waves
      __builtin_amdgcn_sched_barrier(0);

      int k0 = kt * 64;
      if (k0 <= qw0 + 31) {
        // ---- QK^T: each K fragment feeds both m-frags ----
        f32x4 sacc[2][4] = {};
        __builtin_amdgcn_s_setprio(1);
#pragma unroll
        for (int kk = 0; kk < 6; kk++) {
#pragma unroll
          for (int ntb = 0; ntb < 4; ntb++) {
            bf16x8 bk2 = *reinterpret_cast<const bf16x8*>(&Kls[cur][((kk * 4 + g) * 65 + ntb * 16 + cc) * 8]);
            sacc[0][ntb] = __builtin_amdgcn_mfma_f32_16x16x32_bf16(aq[0][kk], bk2, sacc[0][ntb], 0, 0, 0);
            sacc[1][ntb] = __builtin_amdgcn_mfma_f32_16x16x32_bf16(aq[1][kk], bk2, sacc[1][ntb], 0, 0, 0);
          }
        }
        __builtin_amdgcn_s_setprio(0);

        // ---- softmax per m-frag; P staged to LDS rows m*16.. ----
#pragma unroll
        for (int m = 0; m < 2; m++) {
          bool diag = (k0 + 63 > qw0 + m * 16);
          float sv[4][4];
#pragma unroll
          for (int ntb = 0; ntb < 4; ntb++)
#pragma unroll
            for (int r = 0; r < 4; r++) {
              float x = sacc[m][ntb][r] * SCALE;
              if (diag) {
                int qr = qw0 + m * 16 + g * 4 + r, kc = k0 + ntb * 16 + cc;
                if (kc > qr) x = -1e30f;
              }
              sv[ntb][r] = x;
            }
          float scl[4];
#pragma unroll
          for (int r = 0; r < 4; r++) {
            float tm = fmaxf(fmaxf(sv[0][r], sv[1][r]), fmaxf(sv[2][r], sv[3][r]));
#pragma unroll
            for (int off = 1; off < 16; off <<= 1) tm = fmaxf(tm, __shfl_xor(tm, off));
            float mold = mrow[m][r];
            float mnew = fmaxf(mold, tm);
            float sc = __expf(mold - mnew);
            float rs = 0.f;
#pragma unroll
            for (int ntb = 0; ntb < 4; ntb++) {
              float p = __expf(sv[ntb][r] - mnew);
              sv[ntb][r] = p;
              rs += p;
            }
#pragma unroll
            for (int off = 1; off < 16; off <<= 1) rs += __shfl_xor(rs, off);
            lrow[m][r] = lrow[m][r] * sc + rs;
            mrow[m][r] = mnew;
            scl[r] = sc;
          }
#pragma unroll
          for (int ntb = 0; ntb < 8; ntb++)
#pragma unroll
            for (int r = 0; r < 4; r++) acc[m][ntb][r] *= scl[r];
#pragma unroll
          for (int ntb = 0; ntb < 4; ntb++)
#pragma unroll
            for (int r = 0; r < 4; r++) {
              int row = m * 16 + g * 4 + r, col = ntb * 16 + cc;
              int off2 = row * 128 + (((col >> 3) ^ (row & 7)) << 4) + ((col & 7) << 1);
              *reinterpret_cast<bf16*>(pbase + off2) = (bf16)sv[ntb][r];
            }
        }
        LGWAIT0;
        // ---- PV: each V fragment feeds both m-frags ----
        __builtin_amdgcn_s_setprio(1);
#pragma unroll
        for (int kk2 = 0; kk2 < 2; kk2++) {
          bf16x8 pa[2];
#pragma unroll
          for (int m = 0; m < 2; m++) {
            int row = m * 16 + cc;
            int slot = (kk2 * 4 + g) ^ (cc & 7);
            pa[m] = *reinterpret_cast<const bf16x8*>(pbase + row * 128 + slot * 16);
          }
#pragma unroll
          for (int ntb = 0; ntb < 8; ntb++) {
            bf16x8 bv2 = *reinterpret_cast<const bf16x8*>(&Vls[cur][((kk2 * 4 + g) * 129 + ntb * 16 + cc) * 8]);
            acc[0][ntb] = __builtin_amdgcn_mfma_f32_16x16x32_bf16(pa[0], bv2, acc[0][ntb], 0, 0, 0);
            acc[1][ntb] = __builtin_amdgcn_mfma_f32_16x16x32_bf16(pa[1], bv2, acc[1][ntb], 0, 0, 0);
          }
        }
        __builtin_amdgcn_s_setprio(0);
      }
    }

    // ---- epilogue: normalize + store ----
#pragma unroll
    for (int m = 0; m < 2; m++)
#pragma unroll
      for (int ntb = 0; ntb < 8; ntb++)
#pragma unroll
        for (int r = 0; r < 4; r++) {
          int qr = qw0 + m * 16 + g * 4 + r;
          O[(size_t)(b * S + qr) * (H * DPH) + h * DPH + ntb * 16 + cc] =
              (bf16)(acc[m][ntb][r] / lrow[m][r]);
        }
  }
}

// ---------------- host ----------------
extern "C" void kernel_launch(void* const* d_in, const int* in_sizes, int n_in,
                              void* d_out, int out_size, void* d_ws, size_t ws_size,
                              hipStream_t stream) {
  const float* inputs    = (const float*)d_in[0];
  const int*   pos_ids   = (const int*)d_in[1];
  const float* Wq_down   = (const float*)d_in[3];
  const float* q_norm_w  = (const float*)d_in[4];
  const float* Wq_up     = (const float*)d_in[5];
  const float* Wkv_down  = (const float*)d_in[6];
  const float* kv_norm_w = (const float*)d_in[7];
  const float* Wkv_up    = (const float*)d_in[8];
  const float* Wout      = (const float*)d_in[9];
  float* out = (float*)d_out;

  char* ws = (char*)d_ws;
  size_t off = 0;
  auto alloc = [&](size_t bytes) -> void* {
    void* p = ws + off;
    off += (bytes + 255) & ~(size_t)255;
    return p;
  };

  bf16*  in_bf = (bf16*)alloc((size_t)T * D * 2);
  bf16*  WdT   = (bf16*)alloc((size_t)NDNP * D * 2);         // fused down-proj weights^T (rows 592.. zero)
  bf16*  WquT  = (bf16*)alloc((size_t)(H * QHD) * DC_Q * 2);
  bf16*  WkvuT = (bf16*)alloc((size_t)(H * MEG) * KVUK * 2); // kv_up weights^T, K-padded with zeros
  bf16*  WoutT = (bf16*)alloc((size_t)D * (H * DPH) * 2);
  float* cqkv  = (float*)alloc((size_t)T * NDNP * 4);        // fused down-proj output
  bf16*  cqn   = (bf16*)alloc((size_t)T * DC_Q * 2);
  bf16*  ckvn  = (bf16*)alloc((size_t)T * KVUK * 2);         // normalized c_kv, K-padded
  bf16*  qbf   = (bf16*)alloc((size_t)T * (H * QHD) * 2);
  bf16*  kemb  = (bf16*)alloc((size_t)T * DR * 2);
  bf16*  kvb   = (bf16*)alloc((size_t)T * (H * MEG) * 2);
  bf16*  Vt    = (bf16*)alloc((size_t)B * H * DPH * S * 2);
  bf16*  abf   = (bf16*)alloc((size_t)T * (H * DPH) * 2);
  float* cos_t = (float*)alloc((size_t)S * 32 * 4);
  float* sin_t = (float*)alloc((size_t)S * 32 * 4);

  rope_table_kernel<<<S * 32 / 64, 64, 0, stream>>>(cos_t, sin_t);
  cast_bf16_kernel<<<(T * D / 4 + 255) / 256, 256, 0, stream>>>(inputs, in_bf, T * D);
  zero_bf16_kernel<<<(NDNP * D / 8 + 255) / 256, 256, 0, stream>>>(WdT, NDNP * D);
  zero_bf16_kernel<<<(H * MEG * KVUK / 8 + 255) / 256, 256, 0, stream>>>(WkvuT, H * MEG * KVUK);
  transpose_cast_kernel<<<dim3((DC_Q + 31) / 32, (D + 31) / 32), 256, 0, stream>>>(Wq_down, WdT, D, DC_Q, D);
  transpose_cast_kernel<<<dim3((80 + 31) / 32, (D + 31) / 32), 256, 0, stream>>>(Wkv_down, WdT + (size_t)DC_Q * D, D, 80, D);
  transpose_cast_kernel<<<dim3((H * QHD + 31) / 32, (DC_Q + 31) / 32), 256, 0, stream>>>(Wq_up, WquT, DC_Q, H * QHD, DC_Q);
  transpose_cast_kernel<<<dim3((H * MEG + 31) / 32, 1), 256, 0, stream>>>(Wkv_up, WkvuT, DC_KV, H * MEG, KVUK);
  transpose_cast_kernel<<<dim3((D + 31) / 32, (H * DPH + 31) / 32), 256, 0, stream>>>(Wout, WoutT, H * DPH, D, H * DPH);

  gemm_bt_kernel<float><<<dim3(NDNP / 128, T / 128), 256, 0, stream>>>(in_bf, WdT, cqkv, T, NDNP, D);
  rmsnorm_q_kernel<<<T / 4, 256, 0, stream>>>(cqkv, q_norm_w, cqn, NDNP);
  kv_prep_kernel<<<T, 64, 0, stream>>>(cqkv, kv_norm_w, pos_ids, cos_t, sin_t, ckvn, kemb);
  gemm_bt_kernel<bf16><<<dim3(H * QHD / 128, T / 128), 256, 0, stream>>>(cqn, WquT, qbf, T, H * QHD, DC_Q);
  gemm_bt_kernel<bf16><<<dim3(H * MEG / 128, T / 128), 256, 0, stream>>>(ckvn, WkvuT, kvb, T, H * MEG, KVUK);
  build_vt_kernel<<<dim3(S / 64, B * H), 256, 0, stream>>>(kvb, Vt);
  attn_kernel<<<256, 256, 0, stream>>>(qbf, kvb, kemb, Vt, pos_ids, cos_t, sin_t, abf);
  gemm_bt_kernel<float><<<dim3(D / 128, T / 128), 256, 0, stream>>>(abf, WoutT, out, T, D, D);
}

// Round 6
// 330.862 us; speedup vs baseline: 2.9823x; 1.1120x over previous
//
#include <hip/hip_runtime.h>

typedef __bf16 bf16;
typedef __bf16 bf16x8 __attribute__((ext_vector_type(8)));
typedef __bf16 bf16x4 __attribute__((ext_vector_type(4)));
typedef float f32x4 __attribute__((ext_vector_type(4)));

constexpr int D = 2048, H = 16, DPH = 128, DR = 64, DC_KV = 16, DC_Q = 512;
constexpr int QHD = 192, MEG = 256, B = 2, S = 2048;
constexpr int T = B * S;
constexpr int NDNP = 640;   // fused down-proj width (512 q + 80 kv), padded to x128
constexpr int KVUK = 64;    // kv_up GEMM K (16 real + 48 zero pad)
constexpr float EPS = 1e-7f;
constexpr float SCALE = 0.07216878364870323f; // 1/sqrt(192)

static __device__ __forceinline__ bf16x8 zero8() {
  bf16x8 v;
#pragma unroll
  for (int j = 0; j < 8; j++) v[j] = (bf16)0.f;
  return v;
}

static __device__ __forceinline__ void gload_lds16(const bf16* g, bf16* l) {
  __builtin_amdgcn_global_load_lds(
      (const __attribute__((address_space(1))) unsigned int*)g,
      (__attribute__((address_space(3))) unsigned int*)l, 16, 0, 0);
}

#define LGWAIT0 do { asm volatile("s_waitcnt lgkmcnt(0)" ::: "memory"); __builtin_amdgcn_sched_barrier(0); } while (0)

// ---------------- rope table (f64 precision, once) ----------------
__global__ void rope_table_kernel(float* __restrict__ cos_t, float* __restrict__ sin_t) {
  int i = blockIdx.x * 64 + threadIdx.x;  // over S*32
  int pos = i >> 5, j = i & 31;
  double invf = pow(10000.0, -(double)(2 * j) / 64.0);
  double a = (double)pos * invf;
  cos_t[i] = (float)cos(a);
  sin_t[i] = (float)sin(a);
}

// ---------------- zero fill (bf16, n multiple of 8) ----------------
__global__ void zero_bf16_kernel(bf16* __restrict__ p, int n) {
  int i = (blockIdx.x * 256 + threadIdx.x) * 8;
  if (i < n) *reinterpret_cast<bf16x8*>(p + i) = zero8();
}

// ---------------- f32 -> bf16 cast ----------------
__global__ void cast_bf16_kernel(const float* __restrict__ in, bf16* __restrict__ out, int n) {
  int i = (blockIdx.x * blockDim.x + threadIdx.x) * 4;
  if (i < n) {
    float4 v = *reinterpret_cast<const float4*>(in + i);
    bf16x4 o;
    o[0] = (bf16)v.x; o[1] = (bf16)v.y; o[2] = (bf16)v.z; o[3] = (bf16)v.w;
    *reinterpret_cast<bf16x4*>(out + i) = o;
  }
}

// ---------------- transpose + cast: out[n][k] = (bf16) in[k][n], in is K x N f32 ----------------
__global__ __launch_bounds__(256) void transpose_cast_kernel(
    const float* __restrict__ in, bf16* __restrict__ out, int K, int N, int ldo) {
  __shared__ float tile[32][33];
  int k0 = blockIdx.y * 32, n0 = blockIdx.x * 32;
  int tid = threadIdx.x;
#pragma unroll
  for (int e = tid; e < 1024; e += 256) {
    int i = e >> 5, j = e & 31;
    int k = k0 + i, n = n0 + j;
    tile[i][j] = (k < K && n < N) ? in[(size_t)k * N + n] : 0.f;
  }
  __syncthreads();
#pragma unroll
  for (int e = tid; e < 1024; e += 256) {
    int jj = e >> 5, ii = e & 31;
    int n = n0 + jj, k = k0 + ii;
    if (k < K && n < N) out[(size_t)n * ldo + k] = (bf16)tile[ii][jj];
  }
}

// ---------------- RMSNorm over 512 dims (q path), input row stride ld ----------------
__global__ __launch_bounds__(256) void rmsnorm_q_kernel(
    const float* __restrict__ cq, const float* __restrict__ w, bf16* __restrict__ outp, int ld) {
  int wid = threadIdx.x >> 6, lane = threadIdx.x & 63;
  int t = blockIdx.x * 4 + wid;
  const float* x = cq + (size_t)t * ld;
  float4 v0 = *reinterpret_cast<const float4*>(x + lane * 8);
  float4 v1 = *reinterpret_cast<const float4*>(x + lane * 8 + 4);
  float ss = v0.x * v0.x + v0.y * v0.y + v0.z * v0.z + v0.w * v0.w +
             v1.x * v1.x + v1.y * v1.y + v1.z * v1.z + v1.w * v1.w;
#pragma unroll
  for (int off = 32; off; off >>= 1) ss += __shfl_xor(ss, off);
  float r = rsqrtf(ss / (float)DC_Q + EPS);
  const float* wp = w + lane * 8;
  float vv[8] = {v0.x, v0.y, v0.z, v0.w, v1.x, v1.y, v1.z, v1.w};
  bf16x8 o;
#pragma unroll
  for (int j = 0; j < 8; j++) o[j] = (bf16)(vv[j] * r * wp[j]);
  *reinterpret_cast<bf16x8*>(outp + (size_t)t * DC_Q + lane * 8) = o;
}

// ---------------- kv prep: rmsnorm(16) -> padded bf16 row; k_rope RoPE ----------------
__global__ __launch_bounds__(64) void kv_prep_kernel(
    const float* __restrict__ cqkv, const float* __restrict__ kvw,
    const int* __restrict__ pos_ids,
    const float* __restrict__ cos_t, const float* __restrict__ sin_t,
    bf16* __restrict__ ckv_n, bf16* __restrict__ kemb) {
  int t = blockIdx.x;
  int lane = threadIdx.x;
  const float* x = cqkv + (size_t)t * NDNP + DC_Q;
  float v = (lane < 16) ? x[lane] : 0.f;
  float ss = v * v;
#pragma unroll
  for (int off = 1; off < 16; off <<= 1) ss += __shfl_xor(ss, off);
  float r = rsqrtf(ss / 16.f + EPS);
  ckv_n[(size_t)t * KVUK + lane] = (lane < 16) ? (bf16)(v * r * kvw[lane & 15]) : (bf16)0.f;
  if (lane < 32) {
    int j = lane;
    int pos = pos_ids[t];
    float cf = cos_t[pos * 32 + j], sf = sin_t[pos * 32 + j];
    float x0 = x[16 + 2 * j], x1 = x[16 + 2 * j + 1];
    kemb[(size_t)t * DR + j]      = (bf16)(x0 * cf - x1 * sf);
    kemb[(size_t)t * DR + 32 + j] = (bf16)(x1 * cf + x0 * sf);
  }
}

// ---------------- build V^T (B*H, 128, S) ----------------
__global__ __launch_bounds__(256) void build_vt_kernel(
    const bf16* __restrict__ kvb, bf16* __restrict__ Vt) {
  __shared__ bf16 tile[128][72];
  int bh = blockIdx.y;
  int b = bh >> 4, h = bh & 15;
  int s0 = blockIdx.x * 64;
  int tid = threadIdx.x;
#pragma unroll
  for (int e = tid; e < 8192; e += 256) {
    int si = e >> 7, v = e & 127;
    tile[v][si] = kvb[(size_t)(b * S + s0 + si) * (H * MEG) + h * MEG + 128 + v];
  }
  __syncthreads();
#pragma unroll
  for (int e = tid; e < 8192; e += 256) {
    int v = e >> 6, si = e & 63;
    Vt[((size_t)bh * 128 + v) * S + s0 + si] = tile[v][si];
  }
}

// ---------------- bf16 MFMA GEMM: C(MxN) = A(MxK) * Bt(NxK)^T ----------------
// Full tiles only: M, N multiples of 128, K multiple of 64. XCD-swizzled block map.
template <typename OutT>
__global__ __launch_bounds__(256) void gemm_bt_kernel(
    const bf16* __restrict__ A, const bf16* __restrict__ Bt,
    OutT* __restrict__ C, int M, int N, int K) {
  __shared__ bf16 As[128 * 64];
  __shared__ bf16 Bs[128 * 64];
  int tid = threadIdx.x;
  int wid = tid >> 6, lane = tid & 63;
  int g = lane >> 4, c = lane & 15;
  int wr = wid >> 1, wc = wid & 1;
  // XCD-aware bijective swizzle (all grids here have nwg % 8 == 0)
  int nbx = gridDim.x;
  int lin = blockIdx.y * nbx + blockIdx.x;
  int cpx = (nbx * gridDim.y) >> 3;
  int swz = (lin & 7) * cpx + (lin >> 3);
  int m0 = (swz / nbx) * 128, n0 = (swz % nbx) * 128;
  int lrow8 = lane >> 3, lslot = lane & 7;

  f32x4 acc[4][4] = {};
  int nk = K >> 6;
  for (int kt = 0; kt < nk; kt++) {
    int k0 = kt << 6;
    __syncthreads();
#pragma unroll
    for (int r = 0; r < 4; r++) {
      int row = (r * 4 + wid) * 8 + lrow8;
      int sslot = lslot ^ (row & 7);
      gload_lds16(A + (size_t)(m0 + row) * K + k0 + sslot * 8, As + row * 64 + lslot * 8);
      gload_lds16(Bt + (size_t)(n0 + row) * K + k0 + sslot * 8, Bs + row * 64 + lslot * 8);
    }
    __syncthreads();
#pragma unroll
    for (int kk = 0; kk < 2; kk++) {
      bf16x8 af[4], bfr[4];
#pragma unroll
      for (int mi = 0; mi < 4; mi++) {
        int row = wr * 64 + mi * 16 + c;
        int sl = (kk * 4 + g) ^ (row & 7);
        af[mi] = *reinterpret_cast<const bf16x8*>(As + row * 64 + sl * 8);
      }
#pragma unroll
      for (int ni = 0; ni < 4; ni++) {
        int row = wc * 64 + ni * 16 + c;
        int sl = (kk * 4 + g) ^ (row & 7);
        bfr[ni] = *reinterpret_cast<const bf16x8*>(Bs + row * 64 + sl * 8);
      }
#pragma unroll
      for (int mi = 0; mi < 4; mi++)
#pragma unroll
        for (int ni = 0; ni < 4; ni++)
          acc[mi][ni] = __builtin_amdgcn_mfma_f32_16x16x32_bf16(af[mi], bfr[ni], acc[mi][ni], 0, 0, 0);
    }
  }
#pragma unroll
  for (int mi = 0; mi < 4; mi++)
#pragma unroll
    for (int ni = 0; ni < 4; ni++)
#pragma unroll
      for (int r = 0; r < 4; r++) {
        int row = m0 + wr * 64 + mi * 16 + g * 4 + r;
        int col = n0 + wc * 64 + ni * 16 + c;
        C[(size_t)row * N + col] = (OutT)acc[mi][ni][r];
      }
}

// ---------------- flash attention: paired causal q-tiles, dbuf COALESCED staging ----------------
// 256 blocks = 32 bh x 8 pairs; block does q-tiles (qi, 15-qi) of 128 rows -> exactly 34
// k-tiles, 1 block/CU. LDS tiles are key-major [key][slot] so every global_load_lds reads
// contiguous 128-256B runs; XOR involution slot^=(key&7) applied at global SOURCE and at
// ds_read (LDS dest linear per rule #21) keeps reads ~conflict-free.
__global__ __launch_bounds__(256, 1) void attn_kernel(
    const bf16* __restrict__ qbf, const bf16* __restrict__ kvb,
    const bf16* __restrict__ kemb, const bf16* __restrict__ Vt,
    const int* __restrict__ pos_ids,
    const float* __restrict__ cos_t, const float* __restrict__ sin_t,
    bf16* __restrict__ O) {
  __shared__ bf16 KlsA[2][64 * 16 * 8];  // [key][slot^(key&7)] cols 0..127 (16KB/buf)
  __shared__ bf16 KlsB[2][64 * 8 * 8];   // [key][slot^(key&7)] rope cols 128..191 (8KB/buf)
  __shared__ bf16 VlsT[2][128 * 8 * 8];  // [v][slot^(v&7)] keys of tile (16KB/buf)
  __shared__ bf16 Pls[4][2048];          // per-wave 32x64 P staging (swizzled)

  int lin = blockIdx.x;              // 0..255
  int bh = lin & 31;                 // 4 bh per XCD
  int pr = lin >> 5;                 // pair index 0..7
  int b = bh >> 4, h = bh & 15;
  int tid = threadIdx.x;
  int w = tid >> 6, lane = tid & 63;
  int g = lane >> 4, cc = lane & 15;
  char* pbase = reinterpret_cast<char*>(&Pls[w][0]);

  // stage one 64-key tile: 10 coalesced global_load_lds per wave
  auto stage = [&](int k0, int buf) {
    const bf16* bkbase = kvb + (size_t)(b * S + k0) * (H * MEG) + h * MEG;
#pragma unroll
    for (int ii = 0; ii < 4; ii++) {      // K-A: 4 keys/instr, 256B runs of 16 lanes
      int i = w * 4 + ii;
      int key = i * 4 + (lane >> 4), d = lane & 15, s = d ^ (key & 7);
      gload_lds16(bkbase + (size_t)key * (H * MEG) + s * 8, &KlsA[buf][i * 512]);
    }
    const bf16* bebase = kemb + (size_t)(b * S + k0) * DR;
#pragma unroll
    for (int jj = 0; jj < 2; jj++) {      // K-B: 8 keys/instr, 128B runs of 8 lanes
      int j = w * 2 + jj;
      int key = j * 8 + (lane >> 3), d = lane & 7, s = d ^ (key & 7);
      gload_lds16(bebase + (size_t)key * DR + s * 8, &KlsB[buf][j * 512]);
    }
    const bf16* bvbase = Vt + (size_t)bh * DPH * S + k0;
#pragma unroll
    for (int nn = 0; nn < 4; nn++) {      // V: 8 v-rows/instr, 128B runs of 8 lanes
      int n = w * 4 + nn;
      int v = n * 8 + (lane >> 3), d = lane & 7, s = d ^ (v & 7);
      gload_lds16(bvbase + (size_t)v * S + s * 8, &VlsT[buf][n * 512]);
    }
  };

#pragma unroll 1
  for (int ph = 0; ph < 2; ph++) {
    int qi = ph ? (15 - pr) : pr;
    int q0 = qi * 128;
    int qw0 = q0 + w * 32;
    int nt = 2 * qi + 2;

    __syncthreads();   // prior phase's LDS reads drained
    stage(0, 0);       // prologue loads fly under Q setup

    // ---- Q fragments (RoPE folded), registers ----
    bf16x8 aq[2][6];
#pragma unroll
    for (int m = 0; m < 2; m++) {
      int qrow = qw0 + m * 16 + cc;
      const bf16* qp = qbf + (size_t)(b * S + qrow) * (H * QHD) + h * QHD;
#pragma unroll
      for (int kk = 0; kk < 4; kk++)
        aq[m][kk] = *reinterpret_cast<const bf16x8*>(qp + kk * 32 + g * 8);
      int pos = pos_ids[b * S + qrow];
      float4 c0 = *reinterpret_cast<const float4*>(cos_t + pos * 32 + g * 8);
      float4 c1 = *reinterpret_cast<const float4*>(cos_t + pos * 32 + g * 8 + 4);
      float4 s0 = *reinterpret_cast<const float4*>(sin_t + pos * 32 + g * 8);
      float4 s1 = *reinterpret_cast<const float4*>(sin_t + pos * 32 + g * 8 + 4);
      bf16x8 x01 = *reinterpret_cast<const bf16x8*>(qp + 128 + g * 16);
      bf16x8 x23 = *reinterpret_cast<const bf16x8*>(qp + 128 + g * 16 + 8);
      float cf[8] = {c0.x, c0.y, c0.z, c0.w, c1.x, c1.y, c1.z, c1.w};
      float sf[8] = {s0.x, s0.y, s0.z, s0.w, s1.x, s1.y, s1.z, s1.w};
      float x0v[8], x1v[8];
#pragma unroll
      for (int j = 0; j < 4; j++) { x0v[j] = (float)x01[2 * j]; x1v[j] = (float)x01[2 * j + 1]; }
#pragma unroll
      for (int j = 0; j < 4; j++) { x0v[4 + j] = (float)x23[2 * j]; x1v[4 + j] = (float)x23[2 * j + 1]; }
#pragma unroll
      for (int j = 0; j < 8; j++) {
        aq[m][4][j] = (bf16)(x0v[j] * cf[j] - x1v[j] * sf[j]);
        aq[m][5][j] = (bf16)(x1v[j] * cf[j] + x0v[j] * sf[j]);
      }
    }

    float mrow[2][4], lrow[2][4];
    f32x4 acc[2][8] = {};
#pragma unroll
    for (int m = 0; m < 2; m++)
#pragma unroll
      for (int r = 0; r < 4; r++) { mrow[m][r] = -1e30f; lrow[m][r] = 0.f; }

#pragma unroll 1
    for (int kt = 0; kt < nt; kt++) {
      int cur = kt & 1;
      __builtin_amdgcn_s_barrier();   // A: all waves done reading buf[cur^1]
      __builtin_amdgcn_sched_barrier(0);
      if (kt + 1 < nt) {
        stage((kt + 1) * 64, cur ^ 1);
        asm volatile("s_waitcnt vmcnt(10)" ::: "memory");  // tile kt's loads landed
      } else {
        asm volatile("s_waitcnt vmcnt(0)" ::: "memory");
      }
      __builtin_amdgcn_sched_barrier(0);
      __builtin_amdgcn_s_barrier();   // B: buf[cur] fully staged
      __builtin_amdgcn_sched_barrier(0);

      int k0 = kt * 64;
      if (k0 <= qw0 + 31) {
        // ---- QK^T: each K fragment feeds both m-frags ----
        f32x4 sacc[2][4] = {};
        __builtin_amdgcn_s_setprio(1);
#pragma unroll
        for (int kk = 0; kk < 6; kk++) {
#pragma unroll
          for (int ntb = 0; ntb < 4; ntb++) {
            int key = ntb * 16 + cc;
            bf16x8 bk2 = (kk < 4)
              ? *reinterpret_cast<const bf16x8*>(&KlsA[cur][(key * 16 + ((kk * 4 + g) ^ (key & 7))) * 8])
              : *reinterpret_cast<const bf16x8*>(&KlsB[cur][(key * 8 + (((kk - 4) * 4 + g) ^ (key & 7))) * 8]);
            sacc[0][ntb] = __builtin_amdgcn_mfma_f32_16x16x32_bf16(aq[0][kk], bk2, sacc[0][ntb], 0, 0, 0);
            sacc[1][ntb] = __builtin_amdgcn_mfma_f32_16x16x32_bf16(aq[1][kk], bk2, sacc[1][ntb], 0, 0, 0);
          }
        }
        __builtin_amdgcn_s_setprio(0);

        // ---- softmax per m-frag; P staged to LDS rows m*16.. ----
#pragma unroll
        for (int m = 0; m < 2; m++) {
          bool diag = (k0 + 63 > qw0 + m * 16);
          float sv[4][4];
#pragma unroll
          for (int ntb = 0; ntb < 4; ntb++)
#pragma unroll
            for (int r = 0; r < 4; r++) {
              float x = sacc[m][ntb][r] * SCALE;
              if (diag) {
                int qr = qw0 + m * 16 + g * 4 + r, kc = k0 + ntb * 16 + cc;
                if (kc > qr) x = -1e30f;
              }
              sv[ntb][r] = x;
            }
          float scl[4];
#pragma unroll
          for (int r = 0; r < 4; r++) {
            float tm = fmaxf(fmaxf(sv[0][r], sv[1][r]), fmaxf(sv[2][r], sv[3][r]));
#pragma unroll
            for (int off = 1; off < 16; off <<= 1) tm = fmaxf(tm, __shfl_xor(tm, off));
            float mold = mrow[m][r];
            float mnew = fmaxf(mold, tm);
            float sc = __expf(mold - mnew);
            float rs = 0.f;
#pragma unroll
            for (int ntb = 0; ntb < 4; ntb++) {
              float p = __expf(sv[ntb][r] - mnew);
              sv[ntb][r] = p;
              rs += p;
            }
#pragma unroll
            for (int off = 1; off < 16; off <<= 1) rs += __shfl_xor(rs, off);
            lrow[m][r] = lrow[m][r] * sc + rs;
            mrow[m][r] = mnew;
            scl[r] = sc;
          }
#pragma unroll
          for (int ntb = 0; ntb < 8; ntb++)
#pragma unroll
            for (int r = 0; r < 4; r++) acc[m][ntb][r] *= scl[r];
          // P-write swizzle: f(row) = (g<<1)^r spreads the 4 g-rows over 8 slot quads
#pragma unroll
          for (int ntb = 0; ntb < 4; ntb++)
#pragma unroll
            for (int r = 0; r < 4; r++) {
              int row = m * 16 + g * 4 + r;
              int fr = (g << 1) ^ r;
              int off2 = row * 128 + ((((ntb << 1) + (cc >> 3)) ^ fr) << 4) + ((cc & 7) << 1);
              *reinterpret_cast<bf16*>(pbase + off2) = (bf16)sv[ntb][r];
            }
        }
        LGWAIT0;
        // ---- PV: each V fragment feeds both m-frags ----
        __builtin_amdgcn_s_setprio(1);
        int fcc = ((cc >> 2) << 1) ^ (cc & 3);
#pragma unroll
        for (int kk2 = 0; kk2 < 2; kk2++) {
          bf16x8 pa[2];
#pragma unroll
          for (int m = 0; m < 2; m++)
            pa[m] = *reinterpret_cast<const bf16x8*>(pbase + (m * 16 + cc) * 128 + (((kk2 * 4 + g) ^ fcc) << 4));
#pragma unroll
          for (int ntb = 0; ntb < 8; ntb++) {
            int v = ntb * 16 + cc;
            bf16x8 bv2 = *reinterpret_cast<const bf16x8*>(&VlsT[cur][(v * 8 + ((kk2 * 4 + g) ^ (v & 7))) * 8]);
            acc[0][ntb] = __builtin_amdgcn_mfma_f32_16x16x32_bf16(pa[0], bv2, acc[0][ntb], 0, 0, 0);
            acc[1][ntb] = __builtin_amdgcn_mfma_f32_16x16x32_bf16(pa[1], bv2, acc[1][ntb], 0, 0, 0);
          }
        }
        __builtin_amdgcn_s_setprio(0);
      }
    }

    // ---- epilogue: normalize + store ----
#pragma unroll
    for (int m = 0; m < 2; m++)
#pragma unroll
      for (int ntb = 0; ntb < 8; ntb++)
#pragma unroll
        for (int r = 0; r < 4; r++) {
          int qr = qw0 + m * 16 + g * 4 + r;
          O[(size_t)(b * S + qr) * (H * DPH) + h * DPH + ntb * 16 + cc] =
              (bf16)(acc[m][ntb][r] / lrow[m][r]);
        }
  }
}

// ---------------- host ----------------
extern "C" void kernel_launch(void* const* d_in, const int* in_sizes, int n_in,
                              void* d_out, int out_size, void* d_ws, size_t ws_size,
                              hipStream_t stream) {
  const float* inputs    = (const float*)d_in[0];
  const int*   pos_ids   = (const int*)d_in[1];
  const float* Wq_down   = (const float*)d_in[3];
  const float* q_norm_w  = (const float*)d_in[4];
  const float* Wq_up     = (const float*)d_in[5];
  const float* Wkv_down  = (const float*)d_in[6];
  const float* kv_norm_w = (const float*)d_in[7];
  const float* Wkv_up    = (const float*)d_in[8];
  const float* Wout      = (const float*)d_in[9];
  float* out = (float*)d_out;

  char* ws = (char*)d_ws;
  size_t off = 0;
  auto alloc = [&](size_t bytes) -> void* {
    void* p = ws + off;
    off += (bytes + 255) & ~(size_t)255;
    return p;
  };

  bf16*  in_bf = (bf16*)alloc((size_t)T * D * 2);
  bf16*  WdT   = (bf16*)alloc((size_t)NDNP * D * 2);         // fused down-proj weights^T (rows 592.. zero)
  bf16*  WquT  = (bf16*)alloc((size_t)(H * QHD) * DC_Q * 2);
  bf16*  WkvuT = (bf16*)alloc((size_t)(H * MEG) * KVUK * 2); // kv_up weights^T, K-padded with zeros
  bf16*  WoutT = (bf16*)alloc((size_t)D * (H * DPH) * 2);
  float* cqkv  = (float*)alloc((size_t)T * NDNP * 4);        // fused down-proj output
  bf16*  cqn   = (bf16*)alloc((size_t)T * DC_Q * 2);
  bf16*  ckvn  = (bf16*)alloc((size_t)T * KVUK * 2);         // normalized c_kv, K-padded
  bf16*  qbf   = (bf16*)alloc((size_t)T * (H * QHD) * 2);
  bf16*  kemb  = (bf16*)alloc((size_t)T * DR * 2);
  bf16*  kvb   = (bf16*)alloc((size_t)T * (H * MEG) * 2);
  bf16*  Vt    = (bf16*)alloc((size_t)B * H * DPH * S * 2);
  bf16*  abf   = (bf16*)alloc((size_t)T * (H * DPH) * 2);
  float* cos_t = (float*)alloc((size_t)S * 32 * 4);
  float* sin_t = (float*)alloc((size_t)S * 32 * 4);

  rope_table_kernel<<<S * 32 / 64, 64, 0, stream>>>(cos_t, sin_t);
  cast_bf16_kernel<<<(T * D / 4 + 255) / 256, 256, 0, stream>>>(inputs, in_bf, T * D);
  zero_bf16_kernel<<<(NDNP * D / 8 + 255) / 256, 256, 0, stream>>>(WdT, NDNP * D);
  zero_bf16_kernel<<<(H * MEG * KVUK / 8 + 255) / 256, 256, 0, stream>>>(WkvuT, H * MEG * KVUK);
  transpose_cast_kernel<<<dim3((DC_Q + 31) / 32, (D + 31) / 32), 256, 0, stream>>>(Wq_down, WdT, D, DC_Q, D);
  transpose_cast_kernel<<<dim3((80 + 31) / 32, (D + 31) / 32), 256, 0, stream>>>(Wkv_down, WdT + (size_t)DC_Q * D, D, 80, D);
  transpose_cast_kernel<<<dim3((H * QHD + 31) / 32, (DC_Q + 31) / 32), 256, 0, stream>>>(Wq_up, WquT, DC_Q, H * QHD, DC_Q);
  transpose_cast_kernel<<<dim3((H * MEG + 31) / 32, 1), 256, 0, stream>>>(Wkv_up, WkvuT, DC_KV, H * MEG, KVUK);
  transpose_cast_kernel<<<dim3((D + 31) / 32, (H * DPH + 31) / 32), 256, 0, stream>>>(Wout, WoutT, H * DPH, D, H * DPH);

  gemm_bt_kernel<float><<<dim3(NDNP / 128, T / 128), 256, 0, stream>>>(in_bf, WdT, cqkv, T, NDNP, D);
  rmsnorm_q_kernel<<<T / 4, 256, 0, stream>>>(cqkv, q_norm_w, cqn, NDNP);
  kv_prep_kernel<<<T, 64, 0, stream>>>(cqkv, kv_norm_w, pos_ids, cos_t, sin_t, ckvn, kemb);
  gemm_bt_kernel<bf16><<<dim3(H * QHD / 128, T / 128), 256, 0, stream>>>(cqn, WquT, qbf, T, H * QHD, DC_Q);
  gemm_bt_kernel<bf16><<<dim3(H * MEG / 128, T / 128), 256, 0, stream>>>(ckvn, WkvuT, kvb, T, H * MEG, KVUK);
  build_vt_kernel<<<dim3(S / 64, B * H), 256, 0, stream>>>(kvb, Vt);
  attn_kernel<<<256, 256, 0, stream>>>(qbf, kvb, kemb, Vt, pos_ids, cos_t, sin_t, abf);
  gemm_bt_kernel<float><<<dim3(D / 128, T / 128), 256, 0, stream>>>(abf, WoutT, out, T, D, D);
}

// Round 7
// 258.543 us; speedup vs baseline: 3.8165x; 1.2797x over previous
//
#include <hip/hip_runtime.h>

typedef __bf16 bf16;
typedef __bf16 bf16x8 __attribute__((ext_vector_type(8)));
typedef __bf16 bf16x4 __attribute__((ext_vector_type(4)));
typedef float f32x4 __attribute__((ext_vector_type(4)));

constexpr int D = 2048, H = 16, DPH = 128, DR = 64, DC_KV = 16, DC_Q = 512;
constexpr int QHD = 192, MEG = 256, B = 2, S = 2048;
constexpr int T = B * S;
constexpr int NDNP = 640;   // fused down-proj width (512 q + 80 kv), padded to x128
constexpr float EPS = 1e-7f;
constexpr float SCALE = 0.07216878364870323f; // 1/sqrt(192)

static __device__ __forceinline__ bf16x8 zero8() {
  bf16x8 v;
#pragma unroll
  for (int j = 0; j < 8; j++) v[j] = (bf16)0.f;
  return v;
}

static __device__ __forceinline__ void gload_lds16(const bf16* g, bf16* l) {
  __builtin_amdgcn_global_load_lds(
      (const __attribute__((address_space(1))) unsigned int*)g,
      (__attribute__((address_space(3))) unsigned int*)l, 16, 0, 0);
}

#define LGWAIT0 do { asm volatile("s_waitcnt lgkmcnt(0)" ::: "memory"); __builtin_amdgcn_sched_barrier(0); } while (0)

// ---------------- rope table (f64 precision, once) ----------------
__global__ void rope_table_kernel(float* __restrict__ cos_t, float* __restrict__ sin_t) {
  int i = blockIdx.x * 64 + threadIdx.x;  // over S*32
  int pos = i >> 5, j = i & 31;
  double invf = pow(10000.0, -(double)(2 * j) / 64.0);
  double a = (double)pos * invf;
  cos_t[i] = (float)cos(a);
  sin_t[i] = (float)sin(a);
}

// ---------------- zero fill (bf16, n multiple of 8) ----------------
__global__ void zero_bf16_kernel(bf16* __restrict__ p, int n) {
  int i = (blockIdx.x * 256 + threadIdx.x) * 8;
  if (i < n) *reinterpret_cast<bf16x8*>(p + i) = zero8();
}

// ---------------- f32 -> bf16 cast ----------------
__global__ void cast_bf16_kernel(const float* __restrict__ in, bf16* __restrict__ out, int n) {
  int i = (blockIdx.x * blockDim.x + threadIdx.x) * 4;
  if (i < n) {
    float4 v = *reinterpret_cast<const float4*>(in + i);
    bf16x4 o;
    o[0] = (bf16)v.x; o[1] = (bf16)v.y; o[2] = (bf16)v.z; o[3] = (bf16)v.w;
    *reinterpret_cast<bf16x4*>(out + i) = o;
  }
}

// ---------------- transpose + cast: out[n][k] = (bf16) in[k][n], in is K x N f32 ----------------
__global__ __launch_bounds__(256) void transpose_cast_kernel(
    const float* __restrict__ in, bf16* __restrict__ out, int K, int N, int ldo) {
  __shared__ float tile[32][33];
  int k0 = blockIdx.y * 32, n0 = blockIdx.x * 32;
  int tid = threadIdx.x;
#pragma unroll
  for (int e = tid; e < 1024; e += 256) {
    int i = e >> 5, j = e & 31;
    int k = k0 + i, n = n0 + j;
    tile[i][j] = (k < K && n < N) ? in[(size_t)k * N + n] : 0.f;
  }
  __syncthreads();
#pragma unroll
  for (int e = tid; e < 1024; e += 256) {
    int jj = e >> 5, ii = e & 31;
    int n = n0 + jj, k = k0 + ii;
    if (k < K && n < N) out[(size_t)n * ldo + k] = (bf16)tile[ii][jj];
  }
}

// ---------------- absorbed weights: WkT[h][c][v], WvU[h][v][c] from Wkv_up f32 ----------------
__global__ __launch_bounds__(256) void prep_wkwv_kernel(
    const float* __restrict__ Wkv_up, bf16* __restrict__ WkT, bf16* __restrict__ WvU) {
  int idx = blockIdx.x * 256 + threadIdx.x;
  if (idx < 32768) {
    int h = idx >> 11, c = (idx >> 7) & 15, v = idx & 127;
    WkT[idx] = (bf16)Wkv_up[(size_t)c * (H * MEG) + h * MEG + v];
  } else {
    int j = idx - 32768;
    int h = j >> 11, v = (j >> 4) & 127, c = j & 15;
    WvU[j] = (bf16)Wkv_up[(size_t)c * (H * MEG) + h * MEG + 128 + v];
  }
}

// ---------------- RMSNorm over 512 dims (q path), input row stride ld ----------------
__global__ __launch_bounds__(256) void rmsnorm_q_kernel(
    const float* __restrict__ cq, const float* __restrict__ w, bf16* __restrict__ outp, int ld) {
  int wid = threadIdx.x >> 6, lane = threadIdx.x & 63;
  int t = blockIdx.x * 4 + wid;
  const float* x = cq + (size_t)t * ld;
  float4 v0 = *reinterpret_cast<const float4*>(x + lane * 8);
  float4 v1 = *reinterpret_cast<const float4*>(x + lane * 8 + 4);
  float ss = v0.x * v0.x + v0.y * v0.y + v0.z * v0.z + v0.w * v0.w +
             v1.x * v1.x + v1.y * v1.y + v1.z * v1.z + v1.w * v1.w;
#pragma unroll
  for (int off = 32; off; off >>= 1) ss += __shfl_xor(ss, off);
  float r = rsqrtf(ss / (float)DC_Q + EPS);
  const float* wp = w + lane * 8;
  float vv[8] = {v0.x, v0.y, v0.z, v0.w, v1.x, v1.y, v1.z, v1.w};
  bf16x8 o;
#pragma unroll
  for (int j = 0; j < 8; j++) o[j] = (bf16)(vv[j] * r * wp[j]);
  *reinterpret_cast<bf16x8*>(outp + (size_t)t * DC_Q + lane * 8) = o;
}

// ---------------- kv prep: Kc row = [rope64 | c16 | zero pad..128]; cT[c][s] = c_kv^T ----------------
__global__ __launch_bounds__(64) void kv_prep_kernel(
    const float* __restrict__ cqkv, const float* __restrict__ kvw,
    const int* __restrict__ pos_ids,
    const float* __restrict__ cos_t, const float* __restrict__ sin_t,
    bf16* __restrict__ KcG, bf16* __restrict__ cTG) {
  int t = blockIdx.x;
  int lane = threadIdx.x;
  int b = t >> 11, s = t & (S - 1);
  const float* x = cqkv + (size_t)t * NDNP + DC_Q;
  float v = (lane < 16) ? x[lane] : 0.f;
  float ss = v * v;
#pragma unroll
  for (int off = 1; off < 16; off <<= 1) ss += __shfl_xor(ss, off);
  float r = rsqrtf(ss / 16.f + EPS);
  bf16* krow = KcG + ((size_t)t << 7);
  if (lane < 16) {
    bf16 cn = (bf16)(v * r * kvw[lane]);
    krow[64 + lane] = cn;
    cTG[(size_t)(b * 16 + lane) * S + s] = cn;
  } else {
    krow[64 + lane] = (bf16)0.f;   // dims 80..127 zero
  }
  if (lane < 32) {
    int j = lane;
    int pos = pos_ids[t];
    float cf = cos_t[pos * 32 + j], sf = sin_t[pos * 32 + j];
    float x0 = x[16 + 2 * j], x1 = x[16 + 2 * j + 1];
    krow[j]      = (bf16)(x0 * cf - x1 * sf);
    krow[32 + j] = (bf16)(x1 * cf + x0 * sf);
  }
}

// ---------------- q prep: Qp row = [rope64 | qc16 | zero16] per (b,h,s); qc = q_nope . Wk_h ----------------
__global__ __launch_bounds__(256) void qprep_kernel(
    const bf16* __restrict__ qbf, const bf16* __restrict__ WkT,
    const int* __restrict__ pos_ids,
    const float* __restrict__ cos_t, const float* __restrict__ sin_t,
    bf16* __restrict__ Qp) {
  int wv = blockIdx.x * 4 + (threadIdx.x >> 6);
  int lane = threadIdx.x & 63;
  int t = wv >> 4, h = wv & 15;
  int b = t >> 11, s = t & (S - 1);
  const bf16* qsrc = qbf + (size_t)t * (H * QHD) + h * QHD;
  int c = lane & 15, vq = lane >> 4;
  const bf16* wk = WkT + (size_t)((h * 16 + c) * 128 + vq * 32);
  const bf16* qn = qsrc + vq * 32;
  float part = 0.f;
#pragma unroll
  for (int u = 0; u < 4; u++) {
    bf16x8 qa = *reinterpret_cast<const bf16x8*>(qn + u * 8);
    bf16x8 wa = *reinterpret_cast<const bf16x8*>(wk + u * 8);
#pragma unroll
    for (int j = 0; j < 8; j++) part += (float)qa[j] * (float)wa[j];
  }
  part += __shfl_xor(part, 16);
  part += __shfl_xor(part, 32);
  bf16* qrow = Qp + (size_t)((b * 16 + h) * 2048 + s) * 96;
  if (lane < 16) qrow[64 + lane] = (bf16)part;
  else if (lane < 32) qrow[64 + lane] = (bf16)0.f;   // dims 80..95 zero
  if (lane < 32) {
    int j = lane;
    int pos = pos_ids[t];
    float cf = cos_t[pos * 32 + j], sf = sin_t[pos * 32 + j];
    float x0 = (float)qsrc[128 + 2 * j], x1 = (float)qsrc[128 + 2 * j + 1];
    qrow[j]      = (bf16)(x0 * cf - x1 * sf);
    qrow[32 + j] = (bf16)(x1 * cf + x0 * sf);
  }
}

// ---------------- oc expansion: abf[t][h*128+v] = sum_c OC[t][h][c] * WvU[h][v][c] ----------------
__global__ __launch_bounds__(256) void ocexp_kernel(
    const bf16* __restrict__ OC, const bf16* __restrict__ WvU,
    bf16* __restrict__ abf) {
  int t = blockIdx.x;
  int tid = threadIdx.x;
  const bf16* ocr = OC + (size_t)t * 256;
#pragma unroll
  for (int rep = 0; rep < 8; rep++) {
    int idx = rep * 256 + tid;           // = h*128 + v
    int h = idx >> 7;
    const bf16* oh = ocr + h * 16;
    const bf16* wv = WvU + (size_t)idx * 16;
    bf16x8 a0 = *reinterpret_cast<const bf16x8*>(oh);
    bf16x8 a1 = *reinterpret_cast<const bf16x8*>(oh + 8);
    bf16x8 w0 = *reinterpret_cast<const bf16x8*>(wv);
    bf16x8 w1 = *reinterpret_cast<const bf16x8*>(wv + 8);
    float acc = 0.f;
#pragma unroll
    for (int j = 0; j < 8; j++)
      acc += (float)a0[j] * (float)w0[j] + (float)a1[j] * (float)w1[j];
    abf[(size_t)t * 2048 + idx] = (bf16)acc;
  }
}

// ---------------- bf16 MFMA GEMM: C(MxN) = A(MxK) * Bt(NxK)^T ----------------
template <typename OutT>
__global__ __launch_bounds__(256) void gemm_bt_kernel(
    const bf16* __restrict__ A, const bf16* __restrict__ Bt,
    OutT* __restrict__ C, int M, int N, int K) {
  __shared__ bf16 As[128 * 64];
  __shared__ bf16 Bs[128 * 64];
  int tid = threadIdx.x;
  int wid = tid >> 6, lane = tid & 63;
  int g = lane >> 4, c = lane & 15;
  int wr = wid >> 1, wc = wid & 1;
  int nbx = gridDim.x;
  int lin = blockIdx.y * nbx + blockIdx.x;
  int cpx = (nbx * gridDim.y) >> 3;
  int swz = (lin & 7) * cpx + (lin >> 3);
  int m0 = (swz / nbx) * 128, n0 = (swz % nbx) * 128;
  int lrow8 = lane >> 3, lslot = lane & 7;

  f32x4 acc[4][4] = {};
  int nk = K >> 6;
  for (int kt = 0; kt < nk; kt++) {
    int k0 = kt << 6;
    __syncthreads();
#pragma unroll
    for (int r = 0; r < 4; r++) {
      int row = (r * 4 + wid) * 8 + lrow8;
      int sslot = lslot ^ (row & 7);
      gload_lds16(A + (size_t)(m0 + row) * K + k0 + sslot * 8, As + row * 64 + lslot * 8);
      gload_lds16(Bt + (size_t)(n0 + row) * K + k0 + sslot * 8, Bs + row * 64 + lslot * 8);
    }
    __syncthreads();
#pragma unroll
    for (int kk = 0; kk < 2; kk++) {
      bf16x8 af[4], bfr[4];
#pragma unroll
      for (int mi = 0; mi < 4; mi++) {
        int row = wr * 64 + mi * 16 + c;
        int sl = (kk * 4 + g) ^ (row & 7);
        af[mi] = *reinterpret_cast<const bf16x8*>(As + row * 64 + sl * 8);
      }
#pragma unroll
      for (int ni = 0; ni < 4; ni++) {
        int row = wc * 64 + ni * 16 + c;
        int sl = (kk * 4 + g) ^ (row & 7);
        bfr[ni] = *reinterpret_cast<const bf16x8*>(Bs + row * 64 + sl * 8);
      }
#pragma unroll
      for (int mi = 0; mi < 4; mi++)
#pragma unroll
        for (int ni = 0; ni < 4; ni++)
          acc[mi][ni] = __builtin_amdgcn_mfma_f32_16x16x32_bf16(af[mi], bfr[ni], acc[mi][ni], 0, 0, 0);
    }
  }
#pragma unroll
  for (int mi = 0; mi < 4; mi++)
#pragma unroll
    for (int ni = 0; ni < 4; ni++)
#pragma unroll
      for (int r = 0; r < 4; r++) {
        int row = m0 + wr * 64 + mi * 16 + g * 4 + r;
        int col = n0 + wc * 64 + ni * 16 + c;
        C[(size_t)row * N + col] = (OutT)acc[mi][ni][r];
      }
}

// ---------------- absorbed flash attention ----------------
// 256 blocks (1/CU): b(2) x head-group(2) x pair(64). 8 waves (512 thr) = 8 heads, 2 waves/SIMD.
// Wave: 16 q-rows (tile qt), K' = [rope64|c16|pad] shared across heads; PV contracts to 16 c-dims.
// Pair (qt, 127-qt): exactly 17 k-tiles (128 keys) per block -> perfect balance.
// LDS: Kc [key][16 slots, ^key&15], cT [c][16 slots, ^c], P per-wave [q][16 slots, ^q]. All
// staged via coalesced global_load_lds with source-side swizzle (linear LDS dest).
__global__ __launch_bounds__(512, 1) void attn_kernel(
    const bf16* __restrict__ Qp, const bf16* __restrict__ KcG,
    const bf16* __restrict__ cTG, bf16* __restrict__ OC) {
  __shared__ bf16 Kls[2][128 * 128];   // 32KB x2
  __shared__ bf16 Cls[2][16 * 128];    // 4KB x2
  __shared__ bf16 Pls[8][16 * 128];    // 4KB per wave

  int lin = blockIdx.x;           // 0..255
  int b  = lin & 1;
  int hg = (lin >> 1) & 1;
  int pr = lin >> 2;              // 0..63
  int tid = threadIdx.x;
  int w = tid >> 6, lane = tid & 63;
  int g = lane >> 4, cc = lane & 15;
  int h = hg * 8 + w;
  char* pbase = reinterpret_cast<char*>(&Pls[w][0]);

  auto stage = [&](int k0, int buf) {
#pragma unroll
    for (int i = 0; i < 4; i++) {
      int id = w * 4 + i;
      int key = id * 4 + (lane >> 4);
      int sg = (lane & 15) ^ (key & 15);
      gload_lds16(KcG + (((size_t)(b * S + k0 + key)) << 7) + sg * 8,
                  &Kls[buf][id * 512]);
    }
    if (w >= 4) {
      int c = (w - 4) * 4 + (lane >> 4);
      int sg = (lane & 15) ^ c;
      gload_lds16(cTG + (size_t)(b * 16 + c) * S + k0 + sg * 8,
                  &Cls[buf][(w - 4) * 512]);
    }
  };

#pragma unroll 1
  for (int ph = 0; ph < 2; ph++) {
    int qt = ph ? (127 - pr) : pr;
    int q0 = qt * 16;
    int nt = qt / 8 + 1;

    __syncthreads();     // prior phase fully drained
    stage(0, 0);

    bf16x8 aq[3];
    const bf16* qp = Qp + (size_t)((b * 16 + h) * 2048 + q0 + cc) * 96;
#pragma unroll
    for (int kk = 0; kk < 3; kk++)
      aq[kk] = *reinterpret_cast<const bf16x8*>(qp + kk * 32 + g * 8);

    float mrow[4], lrow[4];
    f32x4 oc = {};
#pragma unroll
    for (int r = 0; r < 4; r++) { mrow[r] = -1e30f; lrow[r] = 0.f; }

#pragma unroll 1
    for (int kt = 0; kt < nt; kt++) {
      int cur = kt & 1;
      __builtin_amdgcn_s_barrier();      // A: buf[cur^1] free to overwrite
      __builtin_amdgcn_sched_barrier(0);
      if (kt + 1 < nt) {
        stage((kt + 1) * 128, cur ^ 1);
        if (w < 4) { asm volatile("s_waitcnt vmcnt(4)" ::: "memory"); }
        else       { asm volatile("s_waitcnt vmcnt(5)" ::: "memory"); }
      } else {
        asm volatile("s_waitcnt vmcnt(0)" ::: "memory");
      }
      __builtin_amdgcn_sched_barrier(0);
      __builtin_amdgcn_s_barrier();      // B: buf[cur] staged
      __builtin_amdgcn_sched_barrier(0);

      int k0 = kt * 128;
      // ---- QK^T over 96 dims (3 K-steps) x 128 keys ----
      f32x4 sacc[8] = {};
      __builtin_amdgcn_s_setprio(1);
#pragma unroll
      for (int kk = 0; kk < 3; kk++)
#pragma unroll
        for (int ntb = 0; ntb < 8; ntb++) {
          int key = ntb * 16 + cc;
          bf16x8 bk = *reinterpret_cast<const bf16x8*>(
              &Kls[cur][(key * 16 + ((kk * 4 + g) ^ (key & 15))) * 8]);
          sacc[ntb] = __builtin_amdgcn_mfma_f32_16x16x32_bf16(aq[kk], bk, sacc[ntb], 0, 0, 0);
        }
      __builtin_amdgcn_s_setprio(0);

      // ---- softmax ----
      bool diag = (kt == nt - 1);
      float sv[8][4];
#pragma unroll
      for (int ntb = 0; ntb < 8; ntb++)
#pragma unroll
        for (int r = 0; r < 4; r++) {
          float x = sacc[ntb][r] * SCALE;
          if (diag) {
            int qr = q0 + g * 4 + r, kc = k0 + ntb * 16 + cc;
            if (kc > qr) x = -1e30f;
          }
          sv[ntb][r] = x;
        }
      float scl[4];
#pragma unroll
      for (int r = 0; r < 4; r++) {
        float tm = sv[0][r];
#pragma unroll
        for (int ntb = 1; ntb < 8; ntb++) tm = fmaxf(tm, sv[ntb][r]);
#pragma unroll
        for (int off = 1; off < 16; off <<= 1) tm = fmaxf(tm, __shfl_xor(tm, off));
        float mold = mrow[r];
        float mnew = fmaxf(mold, tm);
        float sc = __expf(mold - mnew);
        float rs = 0.f;
#pragma unroll
        for (int ntb = 0; ntb < 8; ntb++) {
          float p = __expf(sv[ntb][r] - mnew);
          sv[ntb][r] = p;
          rs += p;
        }
#pragma unroll
        for (int off = 1; off < 16; off <<= 1) rs += __shfl_xor(rs, off);
        lrow[r] = lrow[r] * sc + rs;
        mrow[r] = mnew;
        scl[r] = sc;
      }
#pragma unroll
      for (int r = 0; r < 4; r++) oc[r] *= scl[r];
      // ---- P -> per-wave LDS ----
#pragma unroll
      for (int ntb = 0; ntb < 8; ntb++)
#pragma unroll
        for (int r = 0; r < 4; r++) {
          int q = g * 4 + r;
          int entry = q * 16 + (((ntb << 1) | (cc >> 3)) ^ q);
          *reinterpret_cast<bf16*>(pbase + entry * 16 + (cc & 7) * 2) = (bf16)sv[ntb][r];
        }
      LGWAIT0;
      // ---- PV: contract 128 keys into 16 c-dims (4 MFMA) ----
      __builtin_amdgcn_s_setprio(1);
#pragma unroll
      for (int kk2 = 0; kk2 < 4; kk2++) {
        int sl = (kk2 * 4 + g) ^ cc;
        bf16x8 pa = *reinterpret_cast<const bf16x8*>(pbase + (cc * 16 + sl) * 16);
        bf16x8 bv = *reinterpret_cast<const bf16x8*>(&Cls[cur][(cc * 16 + sl) * 8]);
        oc = __builtin_amdgcn_mfma_f32_16x16x32_bf16(pa, bv, oc, 0, 0, 0);
      }
      __builtin_amdgcn_s_setprio(0);
    }

    // ---- epilogue ----
#pragma unroll
    for (int r = 0; r < 4; r++) {
      size_t t = (size_t)b * S + q0 + g * 4 + r;
      OC[t * 256 + h * 16 + cc] = (bf16)(oc[r] / lrow[r]);
    }
  }
}

// ---------------- host ----------------
extern "C" void kernel_launch(void* const* d_in, const int* in_sizes, int n_in,
                              void* d_out, int out_size, void* d_ws, size_t ws_size,
                              hipStream_t stream) {
  const float* inputs    = (const float*)d_in[0];
  const int*   pos_ids   = (const int*)d_in[1];
  const float* Wq_down   = (const float*)d_in[3];
  const float* q_norm_w  = (const float*)d_in[4];
  const float* Wq_up     = (const float*)d_in[5];
  const float* Wkv_down  = (const float*)d_in[6];
  const float* kv_norm_w = (const float*)d_in[7];
  const float* Wkv_up    = (const float*)d_in[8];
  const float* Wout      = (const float*)d_in[9];
  float* out = (float*)d_out;

  char* ws = (char*)d_ws;
  size_t off = 0;
  auto alloc = [&](size_t bytes) -> void* {
    void* p = ws + off;
    off += (bytes + 255) & ~(size_t)255;
    return p;
  };

  bf16*  in_bf = (bf16*)alloc((size_t)T * D * 2);
  bf16*  WdT   = (bf16*)alloc((size_t)NDNP * D * 2);         // fused down-proj weights^T
  bf16*  WquT  = (bf16*)alloc((size_t)(H * QHD) * DC_Q * 2);
  bf16*  WoutT = (bf16*)alloc((size_t)D * (H * DPH) * 2);
  bf16*  WkT   = (bf16*)alloc((size_t)H * 16 * 128 * 2);     // absorbed k weights
  bf16*  WvU   = (bf16*)alloc((size_t)H * 128 * 16 * 2);     // absorbed v weights
  float* cqkv  = (float*)alloc((size_t)T * NDNP * 4);
  bf16*  cqn   = (bf16*)alloc((size_t)T * DC_Q * 2);
  bf16*  qbf   = (bf16*)alloc((size_t)T * (H * QHD) * 2);
  bf16*  KcG   = (bf16*)alloc((size_t)T * 128 * 2);          // [rope64|c16|pad] per token
  bf16*  cTG   = (bf16*)alloc((size_t)B * 16 * S * 2);       // c_kv^T per batch
  bf16*  Qp    = (bf16*)alloc((size_t)B * H * S * 96 * 2);   // absorbed Q
  bf16*  OC    = (bf16*)alloc((size_t)T * H * 16 * 2);       // attention out in c-space
  bf16*  abf   = (bf16*)alloc((size_t)T * (H * DPH) * 2);
  float* cos_t = (float*)alloc((size_t)S * 32 * 4);
  float* sin_t = (float*)alloc((size_t)S * 32 * 4);

  rope_table_kernel<<<S * 32 / 64, 64, 0, stream>>>(cos_t, sin_t);
  cast_bf16_kernel<<<(T * D / 4 + 255) / 256, 256, 0, stream>>>(inputs, in_bf, T * D);
  zero_bf16_kernel<<<(NDNP * D / 8 + 255) / 256, 256, 0, stream>>>(WdT, NDNP * D);
  transpose_cast_kernel<<<dim3((DC_Q + 31) / 32, (D + 31) / 32), 256, 0, stream>>>(Wq_down, WdT, D, DC_Q, D);
  transpose_cast_kernel<<<dim3((80 + 31) / 32, (D + 31) / 32), 256, 0, stream>>>(Wkv_down, WdT + (size_t)DC_Q * D, D, 80, D);
  transpose_cast_kernel<<<dim3((H * QHD + 31) / 32, (DC_Q + 31) / 32), 256, 0, stream>>>(Wq_up, WquT, DC_Q, H * QHD, DC_Q);
  transpose_cast_kernel<<<dim3((D + 31) / 32, (H * DPH + 31) / 32), 256, 0, stream>>>(Wout, WoutT, H * DPH, D, H * DPH);
  prep_wkwv_kernel<<<256, 256, 0, stream>>>(Wkv_up, WkT, WvU);

  gemm_bt_kernel<float><<<dim3(NDNP / 128, T / 128), 256, 0, stream>>>(in_bf, WdT, cqkv, T, NDNP, D);
  rmsnorm_q_kernel<<<T / 4, 256, 0, stream>>>(cqkv, q_norm_w, cqn, NDNP);
  kv_prep_kernel<<<T, 64, 0, stream>>>(cqkv, kv_norm_w, pos_ids, cos_t, sin_t, KcG, cTG);
  gemm_bt_kernel<bf16><<<dim3(H * QHD / 128, T / 128), 256, 0, stream>>>(cqn, WquT, qbf, T, H * QHD, DC_Q);
  qprep_kernel<<<T * H / 4, 256, 0, stream>>>(qbf, WkT, pos_ids, cos_t, sin_t, Qp);
  attn_kernel<<<256, 512, 0, stream>>>(Qp, KcG, cTG, OC);
  ocexp_kernel<<<T, 256, 0, stream>>>(OC, WvU, abf);
  gemm_bt_kernel<float><<<dim3(D / 128, T / 128), 256, 0, stream>>>(abf, WoutT, out, T, D, D);
}

// Round 8
// 187.836 us; speedup vs baseline: 5.2531x; 1.3764x over previous
//
#include <hip/hip_runtime.h>

typedef __bf16 bf16;
typedef __bf16 bf16x8 __attribute__((ext_vector_type(8)));
typedef __bf16 bf16x4 __attribute__((ext_vector_type(4)));
typedef float f32x4 __attribute__((ext_vector_type(4)));

constexpr int D = 2048, H = 16, DPH = 128, DR = 64, DC_KV = 16, DC_Q = 512;
constexpr int QHD = 192, MEG = 256, B = 2, S = 2048;
constexpr int T = B * S;
constexpr int NDNP = 640;   // fused down-proj width (512 q + 80 kv), padded to x128
constexpr int NQX = 1280;   // q gemm width: 256 absorbed qc + 1024 rope
constexpr float EPS = 1e-7f;
constexpr float SCALE = 0.07216878364870323f; // 1/sqrt(192)

static __device__ __forceinline__ bf16x8 zero8() {
  bf16x8 v;
#pragma unroll
  for (int j = 0; j < 8; j++) v[j] = (bf16)0.f;
  return v;
}

static __device__ __forceinline__ void gload_lds16(const bf16* g, bf16* l) {
  __builtin_amdgcn_global_load_lds(
      (const __attribute__((address_space(1))) unsigned int*)g,
      (__attribute__((address_space(3))) unsigned int*)l, 16, 0, 0);
}

#define LGWAIT0 do { asm volatile("s_waitcnt lgkmcnt(0)" ::: "memory"); __builtin_amdgcn_sched_barrier(0); } while (0)

// ---------------- rope table (f64 precision, once) ----------------
__global__ void rope_table_kernel(float* __restrict__ cos_t, float* __restrict__ sin_t) {
  int i = blockIdx.x * 64 + threadIdx.x;  // over S*32
  int pos = i >> 5, j = i & 31;
  double invf = pow(10000.0, -(double)(2 * j) / 64.0);
  double a = (double)pos * invf;
  cos_t[i] = (float)cos(a);
  sin_t[i] = (float)sin(a);
}

// ---------------- zero fill (bf16, n multiple of 8) ----------------
__global__ void zero_bf16_kernel(bf16* __restrict__ p, int n) {
  int i = (blockIdx.x * 256 + threadIdx.x) * 8;
  if (i < n) *reinterpret_cast<bf16x8*>(p + i) = zero8();
}

// ---------------- f32 -> bf16 cast ----------------
__global__ void cast_bf16_kernel(const float* __restrict__ in, bf16* __restrict__ out, int n) {
  int i = (blockIdx.x * blockDim.x + threadIdx.x) * 4;
  if (i < n) {
    float4 v = *reinterpret_cast<const float4*>(in + i);
    bf16x4 o;
    o[0] = (bf16)v.x; o[1] = (bf16)v.y; o[2] = (bf16)v.z; o[3] = (bf16)v.w;
    *reinterpret_cast<bf16x4*>(out + i) = o;
  }
}

// ---------------- transpose + cast: out[n][k] = (bf16) in[k][n], in is K x N f32 ----------------
__global__ __launch_bounds__(256) void transpose_cast_kernel(
    const float* __restrict__ in, bf16* __restrict__ out, int K, int N, int ldo) {
  __shared__ float tile[32][33];
  int k0 = blockIdx.y * 32, n0 = blockIdx.x * 32;
  int tid = threadIdx.x;
#pragma unroll
  for (int e = tid; e < 1024; e += 256) {
    int i = e >> 5, j = e & 31;
    int k = k0 + i, n = n0 + j;
    tile[i][j] = (k < K && n < N) ? in[(size_t)k * N + n] : 0.f;
  }
  __syncthreads();
#pragma unroll
  for (int e = tid; e < 1024; e += 256) {
    int jj = e >> 5, ii = e & 31;
    int n = n0 + jj, k = k0 + ii;
    if (k < K && n < N) out[(size_t)n * ldo + k] = (bf16)tile[ii][jj];
  }
}

// ---------------- W2T[d][h*16+c] = sum_v Wkv_up[c][h*256+128+v] * Wout[h*128+v][d] ----------------
__global__ __launch_bounds__(128) void prep_w2_kernel(
    const float* __restrict__ Wkv_up, const float* __restrict__ Wout,
    bf16* __restrict__ W2T) {
  __shared__ float wv[128][16];   // [v][c]
  int h = blockIdx.y, d0 = blockIdx.x * 128;
  int tid = threadIdx.x;
#pragma unroll
  for (int e = tid; e < 2048; e += 128) {
    int v = e >> 4, c = e & 15;
    wv[v][c] = Wkv_up[(size_t)c * (H * MEG) + h * MEG + 128 + v];
  }
  __syncthreads();
  int d = d0 + tid;
  float acc[16] = {};
  for (int v = 0; v < 128; v++) {
    float wo = Wout[(size_t)(h * 128 + v) * D + d];
    float4 a0 = *reinterpret_cast<const float4*>(&wv[v][0]);
    float4 a1 = *reinterpret_cast<const float4*>(&wv[v][4]);
    float4 a2 = *reinterpret_cast<const float4*>(&wv[v][8]);
    float4 a3 = *reinterpret_cast<const float4*>(&wv[v][12]);
    acc[0] += a0.x * wo;  acc[1] += a0.y * wo;  acc[2] += a0.z * wo;  acc[3] += a0.w * wo;
    acc[4] += a1.x * wo;  acc[5] += a1.y * wo;  acc[6] += a1.z * wo;  acc[7] += a1.w * wo;
    acc[8] += a2.x * wo;  acc[9] += a2.y * wo;  acc[10] += a2.z * wo; acc[11] += a2.w * wo;
    acc[12] += a3.x * wo; acc[13] += a3.y * wo; acc[14] += a3.z * wo; acc[15] += a3.w * wo;
  }
  bf16x8 o0, o1;
#pragma unroll
  for (int c = 0; c < 8; c++) { o0[c] = (bf16)acc[c]; o1[c] = (bf16)acc[8 + c]; }
  *reinterpret_cast<bf16x8*>(&W2T[(size_t)d * 256 + h * 16]) = o0;
  *reinterpret_cast<bf16x8*>(&W2T[(size_t)d * 256 + h * 16 + 8]) = o1;
}

// ---------------- WqxT[h*16+c][k] = sum_v Wq_up[k][h*192+v] * Wkv_up[c][h*256+v] ----------------
__global__ __launch_bounds__(128) void prep_w3_kernel(
    const float* __restrict__ Wq_up, const float* __restrict__ Wkv_up,
    bf16* __restrict__ WqxT) {
  __shared__ float wk[128][16];   // [v][c]
  int h = blockIdx.y, k0 = blockIdx.x * 128;
  int tid = threadIdx.x;
#pragma unroll
  for (int e = tid; e < 2048; e += 128) {
    int v = e >> 4, c = e & 15;
    wk[v][c] = Wkv_up[(size_t)c * (H * MEG) + h * MEG + v];
  }
  __syncthreads();
  int k = k0 + tid;
  float acc[16] = {};
  for (int v = 0; v < 128; v++) {
    float wq = Wq_up[(size_t)k * (H * QHD) + h * QHD + v];
    float4 a0 = *reinterpret_cast<const float4*>(&wk[v][0]);
    float4 a1 = *reinterpret_cast<const float4*>(&wk[v][4]);
    float4 a2 = *reinterpret_cast<const float4*>(&wk[v][8]);
    float4 a3 = *reinterpret_cast<const float4*>(&wk[v][12]);
    acc[0] += a0.x * wq;  acc[1] += a0.y * wq;  acc[2] += a0.z * wq;  acc[3] += a0.w * wq;
    acc[4] += a1.x * wq;  acc[5] += a1.y * wq;  acc[6] += a1.z * wq;  acc[7] += a1.w * wq;
    acc[8] += a2.x * wq;  acc[9] += a2.y * wq;  acc[10] += a2.z * wq; acc[11] += a2.w * wq;
    acc[12] += a3.x * wq; acc[13] += a3.y * wq; acc[14] += a3.z * wq; acc[15] += a3.w * wq;
  }
#pragma unroll
  for (int c = 0; c < 16; c++)
    WqxT[(size_t)(h * 16 + c) * DC_Q + k] = (bf16)acc[c];
}

// ---------------- WqxT[256 + h*64 + j][k] = Wq_up[k][h*192+128+j] (rope cols) ----------------
__global__ __launch_bounds__(256) void prep_wrope_kernel(
    const float* __restrict__ Wq_up, bf16* __restrict__ WqxT) {
  __shared__ float tile[64][65];
  int h = blockIdx.y, k0 = blockIdx.x * 64;
  int tid = threadIdx.x;
#pragma unroll
  for (int p = 0; p < 16; p++) {
    int kk = p * 4 + (tid >> 6), j = tid & 63;
    tile[kk][j] = Wq_up[(size_t)(k0 + kk) * (H * QHD) + h * QHD + 128 + j];
  }
  __syncthreads();
#pragma unroll
  for (int p = 0; p < 16; p++) {
    int n = p * 4 + (tid >> 6), k = tid & 63;
    WqxT[(size_t)(256 + h * 64 + n) * DC_Q + k0 + k] = (bf16)tile[k][n];
  }
}

// ---------------- RMSNorm over 512 dims (q path), input row stride ld ----------------
__global__ __launch_bounds__(256) void rmsnorm_q_kernel(
    const float* __restrict__ cq, const float* __restrict__ w, bf16* __restrict__ outp, int ld) {
  int wid = threadIdx.x >> 6, lane = threadIdx.x & 63;
  int t = blockIdx.x * 4 + wid;
  const float* x = cq + (size_t)t * ld;
  float4 v0 = *reinterpret_cast<const float4*>(x + lane * 8);
  float4 v1 = *reinterpret_cast<const float4*>(x + lane * 8 + 4);
  float ss = v0.x * v0.x + v0.y * v0.y + v0.z * v0.z + v0.w * v0.w +
             v1.x * v1.x + v1.y * v1.y + v1.z * v1.z + v1.w * v1.w;
#pragma unroll
  for (int off = 32; off; off >>= 1) ss += __shfl_xor(ss, off);
  float r = rsqrtf(ss / (float)DC_Q + EPS);
  const float* wp = w + lane * 8;
  float vv[8] = {v0.x, v0.y, v0.z, v0.w, v1.x, v1.y, v1.z, v1.w};
  bf16x8 o;
#pragma unroll
  for (int j = 0; j < 8; j++) o[j] = (bf16)(vv[j] * r * wp[j]);
  *reinterpret_cast<bf16x8*>(outp + (size_t)t * DC_Q + lane * 8) = o;
}

// ---------------- kv prep: Kc row = [rope64 | c16 | zero pad..128]; cT[c][s] = c_kv^T ----------------
__global__ __launch_bounds__(64) void kv_prep_kernel(
    const float* __restrict__ cqkv, const float* __restrict__ kvw,
    const int* __restrict__ pos_ids,
    const float* __restrict__ cos_t, const float* __restrict__ sin_t,
    bf16* __restrict__ KcG, bf16* __restrict__ cTG) {
  int t = blockIdx.x;
  int lane = threadIdx.x;
  int b = t >> 11, s = t & (S - 1);
  const float* x = cqkv + (size_t)t * NDNP + DC_Q;
  float v = (lane < 16) ? x[lane] : 0.f;
  float ss = v * v;
#pragma unroll
  for (int off = 1; off < 16; off <<= 1) ss += __shfl_xor(ss, off);
  float r = rsqrtf(ss / 16.f + EPS);
  bf16* krow = KcG + ((size_t)t << 7);
  if (lane < 16) {
    bf16 cn = (bf16)(v * r * kvw[lane]);
    krow[64 + lane] = cn;
    cTG[(size_t)(b * 16 + lane) * S + s] = cn;
  } else {
    krow[64 + lane] = (bf16)0.f;   // dims 80..127 zero
  }
  if (lane < 32) {
    int j = lane;
    int pos = pos_ids[t];
    float cf = cos_t[pos * 32 + j], sf = sin_t[pos * 32 + j];
    float x0 = x[16 + 2 * j], x1 = x[16 + 2 * j + 1];
    krow[j]      = (bf16)(x0 * cf - x1 * sf);
    krow[32 + j] = (bf16)(x1 * cf + x0 * sf);
  }
}

// ---------------- build Qp (B*H, S, 96) = [rope64 | qc16 | zero16] from qx ----------------
__global__ __launch_bounds__(256) void build_q_kernel(
    const bf16* __restrict__ qx, const int* __restrict__ pos_ids,
    const float* __restrict__ cos_t, const float* __restrict__ sin_t,
    bf16* __restrict__ Qp) {
  int t = blockIdx.x;
  int b = t >> 11, s = t & (S - 1);
  int tid = threadIdx.x;
  int pos = pos_ids[t];
  const bf16* qr = qx + (size_t)t * NQX;
#pragma unroll
  for (int rep = 0; rep < 2; rep++) {
    int item = rep * 256 + tid;
    int h = item >> 5, j = item & 31;
    float cf = cos_t[pos * 32 + j], sf = sin_t[pos * 32 + j];
    float x0 = (float)qr[256 + h * 64 + 2 * j], x1 = (float)qr[256 + h * 64 + 2 * j + 1];
    bf16* qrow = Qp + (size_t)((b * 16 + h) * 2048 + s) * 96;
    qrow[j]      = (bf16)(x0 * cf - x1 * sf);
    qrow[32 + j] = (bf16)(x1 * cf + x0 * sf);
  }
  {
    int h = tid >> 4, c = tid & 15;
    bf16* qrow = Qp + (size_t)((b * 16 + h) * 2048 + s) * 96;
    qrow[64 + c] = qr[h * 16 + c];
    qrow[80 + c] = (bf16)0.f;
  }
}

// ---------------- bf16 MFMA GEMM: C(MxN) = A(MxK) * Bt(NxK)^T ----------------
template <typename OutT>
__global__ __launch_bounds__(256) void gemm_bt_kernel(
    const bf16* __restrict__ A, const bf16* __restrict__ Bt,
    OutT* __restrict__ C, int M, int N, int K) {
  __shared__ bf16 As[128 * 64];
  __shared__ bf16 Bs[128 * 64];
  int tid = threadIdx.x;
  int wid = tid >> 6, lane = tid & 63;
  int g = lane >> 4, c = lane & 15;
  int wr = wid >> 1, wc = wid & 1;
  int nbx = gridDim.x;
  int lin = blockIdx.y * nbx + blockIdx.x;
  int cpx = (nbx * gridDim.y) >> 3;
  int swz = (lin & 7) * cpx + (lin >> 3);
  int m0 = (swz / nbx) * 128, n0 = (swz % nbx) * 128;
  int lrow8 = lane >> 3, lslot = lane & 7;

  f32x4 acc[4][4] = {};
  int nk = K >> 6;
  for (int kt = 0; kt < nk; kt++) {
    int k0 = kt << 6;
    __syncthreads();
#pragma unroll
    for (int r = 0; r < 4; r++) {
      int row = (r * 4 + wid) * 8 + lrow8;
      int sslot = lslot ^ (row & 7);
      gload_lds16(A + (size_t)(m0 + row) * K + k0 + sslot * 8, As + row * 64 + lslot * 8);
      gload_lds16(Bt + (size_t)(n0 + row) * K + k0 + sslot * 8, Bs + row * 64 + lslot * 8);
    }
    __syncthreads();
#pragma unroll
    for (int kk = 0; kk < 2; kk++) {
      bf16x8 af[4], bfr[4];
#pragma unroll
      for (int mi = 0; mi < 4; mi++) {
        int row = wr * 64 + mi * 16 + c;
        int sl = (kk * 4 + g) ^ (row & 7);
        af[mi] = *reinterpret_cast<const bf16x8*>(As + row * 64 + sl * 8);
      }
#pragma unroll
      for (int ni = 0; ni < 4; ni++) {
        int row = wc * 64 + ni * 16 + c;
        int sl = (kk * 4 + g) ^ (row & 7);
        bfr[ni] = *reinterpret_cast<const bf16x8*>(Bs + row * 64 + sl * 8);
      }
#pragma unroll
      for (int mi = 0; mi < 4; mi++)
#pragma unroll
        for (int ni = 0; ni < 4; ni++)
          acc[mi][ni] = __builtin_amdgcn_mfma_f32_16x16x32_bf16(af[mi], bfr[ni], acc[mi][ni], 0, 0, 0);
    }
  }
#pragma unroll
  for (int mi = 0; mi < 4; mi++)
#pragma unroll
    for (int ni = 0; ni < 4; ni++)
#pragma unroll
      for (int r = 0; r < 4; r++) {
        int row = m0 + wr * 64 + mi * 16 + g * 4 + r;
        int col = n0 + wc * 64 + ni * 16 + c;
        C[(size_t)row * N + col] = (OutT)acc[mi][ni][r];
      }
}

// ---------------- absorbed flash attention (unchanged from round 7) ----------------
__global__ __launch_bounds__(512, 1) void attn_kernel(
    const bf16* __restrict__ Qp, const bf16* __restrict__ KcG,
    const bf16* __restrict__ cTG, bf16* __restrict__ OC) {
  __shared__ bf16 Kls[2][128 * 128];   // 32KB x2
  __shared__ bf16 Cls[2][16 * 128];    // 4KB x2
  __shared__ bf16 Pls[8][16 * 128];    // 4KB per wave

  int lin = blockIdx.x;           // 0..255
  int b  = lin & 1;
  int hg = (lin >> 1) & 1;
  int pr = lin >> 2;              // 0..63
  int tid = threadIdx.x;
  int w = tid >> 6, lane = tid & 63;
  int g = lane >> 4, cc = lane & 15;
  int h = hg * 8 + w;
  char* pbase = reinterpret_cast<char*>(&Pls[w][0]);

  auto stage = [&](int k0, int buf) {
#pragma unroll
    for (int i = 0; i < 4; i++) {
      int id = w * 4 + i;
      int key = id * 4 + (lane >> 4);
      int sg = (lane & 15) ^ (key & 15);
      gload_lds16(KcG + (((size_t)(b * S + k0 + key)) << 7) + sg * 8,
                  &Kls[buf][id * 512]);
    }
    if (w >= 4) {
      int c = (w - 4) * 4 + (lane >> 4);
      int sg = (lane & 15) ^ c;
      gload_lds16(cTG + (size_t)(b * 16 + c) * S + k0 + sg * 8,
                  &Cls[buf][(w - 4) * 512]);
    }
  };

#pragma unroll 1
  for (int ph = 0; ph < 2; ph++) {
    int qt = ph ? (127 - pr) : pr;
    int q0 = qt * 16;
    int nt = qt / 8 + 1;

    __syncthreads();     // prior phase fully drained
    stage(0, 0);

    bf16x8 aq[3];
    const bf16* qp = Qp + (size_t)((b * 16 + h) * 2048 + q0 + cc) * 96;
#pragma unroll
    for (int kk = 0; kk < 3; kk++)
      aq[kk] = *reinterpret_cast<const bf16x8*>(qp + kk * 32 + g * 8);

    float mrow[4], lrow[4];
    f32x4 oc = {};
#pragma unroll
    for (int r = 0; r < 4; r++) { mrow[r] = -1e30f; lrow[r] = 0.f; }

#pragma unroll 1
    for (int kt = 0; kt < nt; kt++) {
      int cur = kt & 1;
      __builtin_amdgcn_s_barrier();      // A: buf[cur^1] free to overwrite
      __builtin_amdgcn_sched_barrier(0);
      if (kt + 1 < nt) {
        stage((kt + 1) * 128, cur ^ 1);
        if (w < 4) { asm volatile("s_waitcnt vmcnt(4)" ::: "memory"); }
        else       { asm volatile("s_waitcnt vmcnt(5)" ::: "memory"); }
      } else {
        asm volatile("s_waitcnt vmcnt(0)" ::: "memory");
      }
      __builtin_amdgcn_sched_barrier(0);
      __builtin_amdgcn_s_barrier();      // B: buf[cur] staged
      __builtin_amdgcn_sched_barrier(0);

      int k0 = kt * 128;
      // ---- QK^T over 96 dims (3 K-steps) x 128 keys ----
      f32x4 sacc[8] = {};
      __builtin_amdgcn_s_setprio(1);
#pragma unroll
      for (int kk = 0; kk < 3; kk++)
#pragma unroll
        for (int ntb = 0; ntb < 8; ntb++) {
          int key = ntb * 16 + cc;
          bf16x8 bk = *reinterpret_cast<const bf16x8*>(
              &Kls[cur][(key * 16 + ((kk * 4 + g) ^ (key & 15))) * 8]);
          sacc[ntb] = __builtin_amdgcn_mfma_f32_16x16x32_bf16(aq[kk], bk, sacc[ntb], 0, 0, 0);
        }
      __builtin_amdgcn_s_setprio(0);

      // ---- softmax ----
      bool diag = (kt == nt - 1);
      float sv[8][4];
#pragma unroll
      for (int ntb = 0; ntb < 8; ntb++)
#pragma unroll
        for (int r = 0; r < 4; r++) {
          float x = sacc[ntb][r] * SCALE;
          if (diag) {
            int qr = q0 + g * 4 + r, kc = k0 + ntb * 16 + cc;
            if (kc > qr) x = -1e30f;
          }
          sv[ntb][r] = x;
        }
      float scl[4];
#pragma unroll
      for (int r = 0; r < 4; r++) {
        float tm = sv[0][r];
#pragma unroll
        for (int ntb = 1; ntb < 8; ntb++) tm = fmaxf(tm, sv[ntb][r]);
#pragma unroll
        for (int off = 1; off < 16; off <<= 1) tm = fmaxf(tm, __shfl_xor(tm, off));
        float mold = mrow[r];
        float mnew = fmaxf(mold, tm);
        float sc = __expf(mold - mnew);
        float rs = 0.f;
#pragma unroll
        for (int ntb = 0; ntb < 8; ntb++) {
          float p = __expf(sv[ntb][r] - mnew);
          sv[ntb][r] = p;
          rs += p;
        }
#pragma unroll
        for (int off = 1; off < 16; off <<= 1) rs += __shfl_xor(rs, off);
        lrow[r] = lrow[r] * sc + rs;
        mrow[r] = mnew;
        scl[r] = sc;
      }
#pragma unroll
      for (int r = 0; r < 4; r++) oc[r] *= scl[r];
      // ---- P -> per-wave LDS ----
#pragma unroll
      for (int ntb = 0; ntb < 8; ntb++)
#pragma unroll
        for (int r = 0; r < 4; r++) {
          int q = g * 4 + r;
          int entry = q * 16 + (((ntb << 1) | (cc >> 3)) ^ q);
          *reinterpret_cast<bf16*>(pbase + entry * 16 + (cc & 7) * 2) = (bf16)sv[ntb][r];
        }
      LGWAIT0;
      // ---- PV: contract 128 keys into 16 c-dims (4 MFMA) ----
      __builtin_amdgcn_s_setprio(1);
#pragma unroll
      for (int kk2 = 0; kk2 < 4; kk2++) {
        int sl = (kk2 * 4 + g) ^ cc;
        bf16x8 pa = *reinterpret_cast<const bf16x8*>(pbase + (cc * 16 + sl) * 16);
        bf16x8 bv = *reinterpret_cast<const bf16x8*>(&Cls[cur][(cc * 16 + sl) * 8]);
        oc = __builtin_amdgcn_mfma_f32_16x16x32_bf16(pa, bv, oc, 0, 0, 0);
      }
      __builtin_amdgcn_s_setprio(0);
    }

    // ---- epilogue ----
#pragma unroll
    for (int r = 0; r < 4; r++) {
      size_t t = (size_t)b * S + q0 + g * 4 + r;
      OC[t * 256 + h * 16 + cc] = (bf16)(oc[r] / lrow[r]);
    }
  }
}

// ---------------- host ----------------
extern "C" void kernel_launch(void* const* d_in, const int* in_sizes, int n_in,
                              void* d_out, int out_size, void* d_ws, size_t ws_size,
                              hipStream_t stream) {
  const float* inputs    = (const float*)d_in[0];
  const int*   pos_ids   = (const int*)d_in[1];
  const float* Wq_down   = (const float*)d_in[3];
  const float* q_norm_w  = (const float*)d_in[4];
  const float* Wq_up     = (const float*)d_in[5];
  const float* Wkv_down  = (const float*)d_in[6];
  const float* kv_norm_w = (const float*)d_in[7];
  const float* Wkv_up    = (const float*)d_in[8];
  const float* Wout      = (const float*)d_in[9];
  float* out = (float*)d_out;

  char* ws = (char*)d_ws;
  size_t off = 0;
  auto alloc = [&](size_t bytes) -> void* {
    void* p = ws + off;
    off += (bytes + 255) & ~(size_t)255;
    return p;
  };

  bf16*  in_bf = (bf16*)alloc((size_t)T * D * 2);
  bf16*  WdT   = (bf16*)alloc((size_t)NDNP * D * 2);        // fused down-proj weights^T
  bf16*  WqxT  = (bf16*)alloc((size_t)NQX * DC_Q * 2);      // [absorbed qc 256 | rope 1024] x 512
  bf16*  W2T   = (bf16*)alloc((size_t)D * 256 * 2);         // absorbed out-proj weights^T
  float* cqkv  = (float*)alloc((size_t)T * NDNP * 4);
  bf16*  cqn   = (bf16*)alloc((size_t)T * DC_Q * 2);
  bf16*  qx    = (bf16*)alloc((size_t)T * NQX * 2);         // q gemm output
  bf16*  KcG   = (bf16*)alloc((size_t)T * 128 * 2);         // [rope64|c16|pad] per token
  bf16*  cTG   = (bf16*)alloc((size_t)B * 16 * S * 2);      // c_kv^T per batch
  bf16*  Qp    = (bf16*)alloc((size_t)B * H * S * 96 * 2);  // absorbed Q
  bf16*  OC    = (bf16*)alloc((size_t)T * H * 16 * 2);      // attention out in c-space
  float* cos_t = (float*)alloc((size_t)S * 32 * 4);
  float* sin_t = (float*)alloc((size_t)S * 32 * 4);

  rope_table_kernel<<<S * 32 / 64, 64, 0, stream>>>(cos_t, sin_t);
  cast_bf16_kernel<<<(T * D / 4 + 255) / 256, 256, 0, stream>>>(inputs, in_bf, T * D);
  zero_bf16_kernel<<<(NDNP * D / 8 + 255) / 256, 256, 0, stream>>>(WdT, NDNP * D);
  transpose_cast_kernel<<<dim3((DC_Q + 31) / 32, (D + 31) / 32), 256, 0, stream>>>(Wq_down, WdT, D, DC_Q, D);
  transpose_cast_kernel<<<dim3((80 + 31) / 32, (D + 31) / 32), 256, 0, stream>>>(Wkv_down, WdT + (size_t)DC_Q * D, D, 80, D);
  prep_w3_kernel<<<dim3(4, 16), 128, 0, stream>>>(Wq_up, Wkv_up, WqxT);
  prep_wrope_kernel<<<dim3(8, 16), 256, 0, stream>>>(Wq_up, WqxT);
  prep_w2_kernel<<<dim3(16, 16), 128, 0, stream>>>(Wkv_up, Wout, W2T);

  gemm_bt_kernel<float><<<dim3(NDNP / 128, T / 128), 256, 0, stream>>>(in_bf, WdT, cqkv, T, NDNP, D);
  rmsnorm_q_kernel<<<T / 4, 256, 0, stream>>>(cqkv, q_norm_w, cqn, NDNP);
  kv_prep_kernel<<<T, 64, 0, stream>>>(cqkv, kv_norm_w, pos_ids, cos_t, sin_t, KcG, cTG);
  gemm_bt_kernel<bf16><<<dim3(NQX / 128, T / 128), 256, 0, stream>>>(cqn, WqxT, qx, T, NQX, DC_Q);
  build_q_kernel<<<T, 256, 0, stream>>>(qx, pos_ids, cos_t, sin_t, Qp);
  attn_kernel<<<256, 512, 0, stream>>>(Qp, KcG, cTG, OC);
  gemm_bt_kernel<float><<<dim3(D / 128, T / 128), 256, 0, stream>>>(OC, W2T, out, T, D, 256);
}